// Round 1
// baseline (1203.589 us; speedup 1.0000x reference)
//
#include <hip/hip_runtime.h>
#include <hip/hip_bf16.h>
#include <math.h>

#define N_NODES 100000
#define N_EDGES 1600000
#define N_GRAPHS 64
#define HID 64
#define EPS 1e-5f

typedef unsigned int u32;

// ---------- weight prep: A' = A - B, B (per layer) ----------
__global__ void prep_w_k(const float* __restrict__ W1, const float* __restrict__ W2,
                         const float* __restrict__ W3, float* __restrict__ Wm) {
  int i = blockIdx.x * 256 + threadIdx.x;
  if (i >= 4096) return;
  const float* Ws[3] = {W1, W2, W3};
  for (int l = 0; l < 3; ++l) {
    float a = Ws[l][i];
    float b = Ws[l][4096 + i];
    Wm[l * 8192 + i] = a - b;          // A - B  (multiplies x[dst])
    Wm[l * 8192 + 4096 + i] = b;       // B      (multiplies x[src])
  }
}

// ---------- CSR build ----------
__global__ void hist_k(const int* __restrict__ dst, u32* __restrict__ cnt) {
  int e = blockIdx.x * 256 + threadIdx.x;
  if (e < N_EDGES) atomicAdd(&cnt[dst[e]], 1u);
}

__global__ void scan1_k(const u32* __restrict__ cnt, u32* __restrict__ incl,
                        u32* __restrict__ bsums, int n) {
  __shared__ u32 tmp[1024];
  int gid = blockIdx.x * 1024 + threadIdx.x;
  u32 v = (gid < n) ? cnt[gid] : 0u;
  tmp[threadIdx.x] = v;
  __syncthreads();
  for (int d = 1; d < 1024; d <<= 1) {
    u32 t = (threadIdx.x >= (u32)d) ? tmp[threadIdx.x - d] : 0u;
    __syncthreads();
    tmp[threadIdx.x] += t;
    __syncthreads();
  }
  if (gid < n) incl[gid] = tmp[threadIdx.x];
  if (threadIdx.x == 1023) bsums[blockIdx.x] = tmp[1023];
}

__global__ void scan2_k(u32* bsums, int nb) {
  __shared__ u32 t[128];
  u32 v = ((int)threadIdx.x < nb) ? bsums[threadIdx.x] : 0u;
  t[threadIdx.x] = v;
  __syncthreads();
  for (int d = 1; d < 128; d <<= 1) {
    u32 a = (threadIdx.x >= (u32)d) ? t[threadIdx.x - d] : 0u;
    __syncthreads();
    t[threadIdx.x] += a;
    __syncthreads();
  }
  if ((int)threadIdx.x < nb) bsums[threadIdx.x] = t[threadIdx.x] - v;  // exclusive
}

__global__ void scan3_k(const u32* __restrict__ incl, const u32* __restrict__ cnt,
                        const u32* __restrict__ bsums, u32* __restrict__ offs, int n) {
  int gid = blockIdx.x * 256 + threadIdx.x;
  if (gid < n) offs[gid] = incl[gid] - cnt[gid] + bsums[gid >> 10];
}

__global__ void scatter_k(const int* __restrict__ src, const int* __restrict__ dst,
                          const u32* __restrict__ offs, u32* __restrict__ cursor,
                          u32* __restrict__ edge_src) {
  int e = blockIdx.x * 256 + threadIdx.x;
  if (e < N_EDGES) {
    int d = dst[e];
    u32 p = atomicAdd(&cursor[d], 1u);
    edge_src[offs[d] + p] = (u32)src[e];
  }
}

// ---------- node GEMM: u = act(x)@(A-B), v = act(x)@B ----------
// act: 0 = identity (layer 1), 1 = relu(x*alpha + beta) (folded BN from prev layer)
__global__ __launch_bounds__(256, 2) void gemm_uv_k(
    const float* __restrict__ x, const float* __restrict__ Wm,
    const float* __restrict__ ab, int act,
    float* __restrict__ u, float* __restrict__ v) {
  int lane = threadIdx.x & 63;
  int wid = (blockIdx.x * blockDim.x + threadIdx.x) >> 6;
  int nw = (gridDim.x * blockDim.x) >> 6;
  float wa[64], wb[64];
#pragma unroll
  for (int k = 0; k < 64; ++k) {
    wa[k] = Wm[k * 64 + lane];
    wb[k] = Wm[4096 + k * 64 + lane];
  }
  float al = 1.f, bet = 0.f;
  if (act) { al = ab[lane]; bet = ab[64 + lane]; }
  for (int row = wid; row < N_NODES; row += nw) {
    float xr = x[row * 64 + lane];
    if (act) xr = fmaxf(fmaf(xr, al, bet), 0.f);
    float su = 0.f, sv = 0.f;
#pragma unroll
    for (int k = 0; k < 64; ++k) {
      float xv = __shfl(xr, k, 64);
      su = fmaf(xv, wa[k], su);
      sv = fmaf(xv, wb[k], sv);
    }
    u[row * 64 + lane] = su;
    v[row * 64 + lane] = sv;
  }
}

// ---------- per-node segment max over incoming edges + combine (in place over u) ----------
__global__ __launch_bounds__(256) void segmax_k(
    const float* __restrict__ v, const u32* __restrict__ offs,
    const u32* __restrict__ cnt, const u32* __restrict__ edge_src,
    const float* __restrict__ bias, float* uh) {
  int lane = threadIdx.x & 63;
  int node = blockIdx.x * 4 + (threadIdx.x >> 6);
  if (node >= N_NODES) return;
  u32 off = offs[node];
  u32 deg = cnt[node];
  float m = -INFINITY;
  for (u32 i = 0; i < deg; ++i) {
    int s = (int)edge_src[off + i];
    m = fmaxf(m, v[s * 64 + lane]);
  }
  float hv = uh[node * 64 + lane] + bias[lane] + m;
  uh[node * 64 + lane] = fmaxf(hv, 0.f);   // relu(-inf) = 0 covers deg==0
}

// ---------- BN stats -> per-channel affine (alpha, beta) ----------
#define BN_NB 256
__global__ void bn_part_k(const float* __restrict__ h, float* __restrict__ part) {
  int c = threadIdx.x & 63;
  float s1 = 0.f, s2 = 0.f;
  int stride = gridDim.x * blockDim.x;  // multiple of 64 -> fixed channel per thread
  for (int i = blockIdx.x * blockDim.x + threadIdx.x; i < N_NODES * 64; i += stride) {
    float x = h[i];
    s1 += x;
    s2 += x * x;
  }
  __shared__ float l1[256], l2[256];
  l1[threadIdx.x] = s1; l2[threadIdx.x] = s2;
  __syncthreads();
  if (threadIdx.x < 64) {
    s1 = l1[c] + l1[c + 64] + l1[c + 128] + l1[c + 192];
    s2 = l2[c] + l2[c + 64] + l2[c + 128] + l2[c + 192];
    part[blockIdx.x * 128 + c] = s1;
    part[blockIdx.x * 128 + 64 + c] = s2;
  }
}

__global__ void bn_final_k(const float* __restrict__ part, const float* __restrict__ g,
                           const float* __restrict__ be, float* __restrict__ ab) {
  int c = threadIdx.x;
  if (c >= 64) return;
  float s1 = 0.f, s2 = 0.f;
  for (int b = 0; b < BN_NB; ++b) {
    s1 += part[b * 128 + c];
    s2 += part[b * 128 + 64 + c];
  }
  float mu = s1 / (float)N_NODES;
  float var = s2 / (float)N_NODES - mu * mu;
  float al = g[c] / sqrtf(var + EPS);
  ab[c] = al;
  ab[64 + c] = be[c] - mu * al;
}

// ---------- graph boundaries (batch is sorted) ----------
__global__ void bounds_k(const int* __restrict__ batch, u32* __restrict__ bounds) {
  int t = threadIdx.x;
  if (t > 64) return;
  int lo = 0, hi = N_NODES;
  while (lo < hi) {
    int mid = (lo + hi) >> 1;
    if (batch[mid] < t) lo = mid + 1; else hi = mid;
  }
  bounds[t] = (u32)lo;
}

// ---------- mean pool per graph + BN3 affine ----------
__global__ void pool_k(const float* __restrict__ h3, const u32* __restrict__ bounds,
                       const float* __restrict__ ab3, float* __restrict__ pooled) {
  int g = blockIdx.x;
  int c = threadIdx.x;
  u32 s = bounds[g], e = bounds[g + 1];
  float acc = 0.f;
  for (u32 n = s; n < e; ++n) acc += h3[n * 64 + c];
  float cntf = fmaxf((float)(e - s), 1.f);
  pooled[g * 64 + c] = (acc / cntf) * ab3[c] + ab3[64 + c];
}

// ---------- linear head + softmax ----------
__global__ void head_k(const float* __restrict__ pooled, const float* __restrict__ Wo,
                       const float* __restrict__ bo, float* __restrict__ out) {
  int g = threadIdx.x;
  if (g >= 64) return;
  float lg[10];
#pragma unroll
  for (int j = 0; j < 10; ++j) lg[j] = bo[j];
  for (int c = 0; c < 64; ++c) {
    float p = pooled[g * 64 + c];
#pragma unroll
    for (int j = 0; j < 10; ++j) lg[j] = fmaf(p, Wo[c * 10 + j], lg[j]);
  }
  float mx = lg[0];
#pragma unroll
  for (int j = 1; j < 10; ++j) mx = fmaxf(mx, lg[j]);
  float s = 0.f, ex[10];
#pragma unroll
  for (int j = 0; j < 10; ++j) { ex[j] = expf(lg[j] - mx); s += ex[j]; }
#pragma unroll
  for (int j = 0; j < 10; ++j) out[g * 10 + j] = ex[j] / s;
}

extern "C" void kernel_launch(void* const* d_in, const int* in_sizes, int n_in,
                              void* d_out, int out_size, void* d_ws, size_t ws_size,
                              hipStream_t stream) {
  const float* x    = (const float*)d_in[0];
  const int*   ei   = (const int*)d_in[1];
  const int*   batch= (const int*)d_in[2];
  const float* W1 = (const float*)d_in[3];  const float* b1 = (const float*)d_in[4];
  const float* W2 = (const float*)d_in[5];  const float* b2 = (const float*)d_in[6];
  const float* W3 = (const float*)d_in[7];  const float* b3 = (const float*)d_in[8];
  const float* g1 = (const float*)d_in[9];  const float* be1= (const float*)d_in[10];
  const float* g2 = (const float*)d_in[11]; const float* be2= (const float*)d_in[12];
  const float* g3 = (const float*)d_in[13]; const float* be3= (const float*)d_in[14];
  const float* Wo = (const float*)d_in[15]; const float* bo = (const float*)d_in[16];
  float* out = (float*)d_out;

  char* p = (char*)d_ws;
  auto alloc = [&](size_t bytes) { void* r = (void*)p; p += (bytes + 255) & ~(size_t)255; return r; };
  float* Wm     = (float*)alloc(3 * 8192 * sizeof(float));
  float* ab     = (float*)alloc(3 * 128 * sizeof(float));
  u32*   bounds = (u32*)alloc(65 * sizeof(u32));
  u32*   cnt    = (u32*)alloc((size_t)N_NODES * sizeof(u32));
  u32*   offs   = (u32*)alloc((size_t)N_NODES * sizeof(u32));
  u32*   cursor = (u32*)alloc((size_t)N_NODES * sizeof(u32));  // doubles as incl-scan buf
  u32*   bsums  = (u32*)alloc(128 * sizeof(u32));
  float* part   = (float*)alloc((size_t)BN_NB * 128 * sizeof(float));
  float* pooled = (float*)alloc(64 * 64 * sizeof(float));
  u32*   esrc   = (u32*)alloc((size_t)N_EDGES * sizeof(u32));
  float* bufA   = (float*)alloc((size_t)N_NODES * 64 * sizeof(float));
  float* bufB   = (float*)alloc((size_t)N_NODES * 64 * sizeof(float));
  float* bufC   = (float*)alloc((size_t)N_NODES * 64 * sizeof(float));

  const int* src = ei;
  const int* dst = ei + N_EDGES;

  // weights prep + CSR build (edges identical for all 3 layers)
  prep_w_k<<<16, 256, 0, stream>>>(W1, W2, W3, Wm);
  hipMemsetAsync(cnt, 0, (size_t)N_NODES * sizeof(u32), stream);
  hist_k<<<(N_EDGES + 255) / 256, 256, 0, stream>>>(dst, cnt);
  scan1_k<<<(N_NODES + 1023) / 1024, 1024, 0, stream>>>(cnt, cursor, bsums, N_NODES);
  scan2_k<<<1, 128, 0, stream>>>(bsums, (N_NODES + 1023) / 1024);
  scan3_k<<<(N_NODES + 255) / 256, 256, 0, stream>>>(cursor, cnt, bsums, offs, N_NODES);
  hipMemsetAsync(cursor, 0, (size_t)N_NODES * sizeof(u32), stream);
  scatter_k<<<(N_EDGES + 255) / 256, 256, 0, stream>>>(src, dst, offs, cursor, esrc);
  bounds_k<<<1, 128, 0, stream>>>(batch, bounds);

  const int GEMM_GRID = 1024;
  const int SEG_GRID = N_NODES / 4;  // 4 nodes (waves) per 256-thread block

  // ---- layer 1: x -> bufA (h1), v in bufC ----
  gemm_uv_k<<<GEMM_GRID, 256, 0, stream>>>(x, Wm, nullptr, 0, bufA, bufC);
  segmax_k<<<SEG_GRID, 256, 0, stream>>>(bufC, offs, cnt, esrc, b1, bufA);
  bn_part_k<<<BN_NB, 256, 0, stream>>>(bufA, part);
  bn_final_k<<<1, 64, 0, stream>>>(part, g1, be1, ab);

  // ---- layer 2: bufA -> bufB (h2) ----
  gemm_uv_k<<<GEMM_GRID, 256, 0, stream>>>(bufA, Wm + 8192, ab, 1, bufB, bufC);
  segmax_k<<<SEG_GRID, 256, 0, stream>>>(bufC, offs, cnt, esrc, b2, bufB);
  bn_part_k<<<BN_NB, 256, 0, stream>>>(bufB, part);
  bn_final_k<<<1, 64, 0, stream>>>(part, g2, be2, ab + 128);

  // ---- layer 3: bufB -> bufA (h3) ----
  gemm_uv_k<<<GEMM_GRID, 256, 0, stream>>>(bufB, Wm + 16384, ab + 128, 1, bufA, bufC);
  segmax_k<<<SEG_GRID, 256, 0, stream>>>(bufC, offs, cnt, esrc, b3, bufA);
  bn_part_k<<<BN_NB, 256, 0, stream>>>(bufA, part);
  bn_final_k<<<1, 64, 0, stream>>>(part, g3, be3, ab + 256);

  // ---- pool (+BN3 affine) + head ----
  pool_k<<<N_GRAPHS, 64, 0, stream>>>(bufA, bounds, ab + 256, pooled);
  head_k<<<1, 64, 0, stream>>>(pooled, Wo, bo, out);
}

// Round 2
// 960.010 us; speedup vs baseline: 1.2537x; 1.2537x over previous
//
#include <hip/hip_runtime.h>
#include <hip/hip_bf16.h>
#include <math.h>

#define N_NODES 100000
#define N_EDGES 1600000
#define N_GRAPHS 64
#define HID 64
#define EPS 1e-5f

typedef unsigned int u32;

// ---------- weight prep: A' = A - B, B (per layer) ----------
__global__ void prep_w_k(const float* __restrict__ W1, const float* __restrict__ W2,
                         const float* __restrict__ W3, float* __restrict__ Wm) {
  int i = blockIdx.x * 256 + threadIdx.x;
  if (i >= 4096) return;
  const float* Ws[3] = {W1, W2, W3};
  for (int l = 0; l < 3; ++l) {
    float a = Ws[l][i];
    float b = Ws[l][4096 + i];
    Wm[l * 8192 + i] = a - b;          // A - B  (multiplies x[dst])
    Wm[l * 8192 + 4096 + i] = b;       // B      (multiplies x[src])
  }
}

// ---------- CSR build ----------
__global__ void hist_k(const int* __restrict__ dst, u32* __restrict__ cnt) {
  int e = blockIdx.x * 256 + threadIdx.x;
  if (e < N_EDGES) atomicAdd(&cnt[dst[e]], 1u);
}

__global__ void scan1_k(const u32* __restrict__ cnt, u32* __restrict__ incl,
                        u32* __restrict__ bsums, int n) {
  __shared__ u32 tmp[1024];
  int gid = blockIdx.x * 1024 + threadIdx.x;
  u32 v = (gid < n) ? cnt[gid] : 0u;
  tmp[threadIdx.x] = v;
  __syncthreads();
  for (int d = 1; d < 1024; d <<= 1) {
    u32 t = (threadIdx.x >= (u32)d) ? tmp[threadIdx.x - d] : 0u;
    __syncthreads();
    tmp[threadIdx.x] += t;
    __syncthreads();
  }
  if (gid < n) incl[gid] = tmp[threadIdx.x];
  if (threadIdx.x == 1023) bsums[blockIdx.x] = tmp[1023];
}

__global__ void scan2_k(u32* bsums, int nb) {
  __shared__ u32 t[128];
  u32 v = ((int)threadIdx.x < nb) ? bsums[threadIdx.x] : 0u;
  t[threadIdx.x] = v;
  __syncthreads();
  for (int d = 1; d < 128; d <<= 1) {
    u32 a = (threadIdx.x >= (u32)d) ? t[threadIdx.x - d] : 0u;
    __syncthreads();
    t[threadIdx.x] += a;
    __syncthreads();
  }
  if ((int)threadIdx.x < nb) bsums[threadIdx.x] = t[threadIdx.x] - v;  // exclusive
}

__global__ void scan3_k(const u32* __restrict__ incl, const u32* __restrict__ cnt,
                        const u32* __restrict__ bsums, u32* __restrict__ offs, int n) {
  int gid = blockIdx.x * 256 + threadIdx.x;
  if (gid < n) offs[gid] = incl[gid] - cnt[gid] + bsums[gid >> 10];
}

__global__ void scatter_k(const int* __restrict__ src, const int* __restrict__ dst,
                          const u32* __restrict__ offs, u32* __restrict__ cursor,
                          u32* __restrict__ edge_src) {
  int e = blockIdx.x * 256 + threadIdx.x;
  if (e < N_EDGES) {
    int d = dst[e];
    u32 p = atomicAdd(&cursor[d], 1u);
    edge_src[offs[d] + p] = (u32)src[e];
  }
}

// ---------- node GEMM half: out = act(x) @ W  (W is 64x64, col per lane) ----------
// act: 0 = identity, 1 = relu(x*alpha + beta) (folded BN+relu from prev layer)
__global__ __launch_bounds__(256) void gemm_half_k(
    const float* __restrict__ x, const float* __restrict__ W,
    const float* __restrict__ ab, int act,
    float* __restrict__ outp) {
  int lane = threadIdx.x & 63;
  int wid = (blockIdx.x * blockDim.x + threadIdx.x) >> 6;
  int nw = (gridDim.x * blockDim.x) >> 6;
  float w[64];
#pragma unroll
  for (int k = 0; k < 64; ++k) w[k] = W[k * 64 + lane];
  float al = 1.f, bet = 0.f;
  if (act) { al = ab[lane]; bet = ab[64 + lane]; }
  for (int row = wid; row < N_NODES; row += nw) {
    float xr = x[row * 64 + lane];
    if (act) xr = fmaxf(fmaf(xr, al, bet), 0.f);
    float s = 0.f;
#pragma unroll
    for (int k = 0; k < 64; ++k) s = fmaf(__shfl(xr, k, 64), w[k], s);
    outp[row * 64 + lane] = s;
  }
}

// ---------- per-node segment max over incoming edges + combine (in place over u) ----------
__global__ __launch_bounds__(256) void segmax_k(
    const float* __restrict__ v, const u32* __restrict__ offs,
    const u32* __restrict__ cnt, const u32* __restrict__ edge_src,
    const float* __restrict__ bias, float* __restrict__ uh) {
  int lane = threadIdx.x & 63;
  int node = blockIdx.x * 4 + (threadIdx.x >> 6);
  if (node >= N_NODES) return;
  u32 off = offs[node];
  u32 deg = cnt[node];
  const u32* ep = edge_src + off;
  float m0 = -INFINITY, m1 = -INFINITY, m2 = -INFINITY, m3 = -INFINITY;
  u32 i = 0;
  for (; i + 4 <= deg; i += 4) {
    u32 s0 = ep[i], s1 = ep[i + 1], s2 = ep[i + 2], s3 = ep[i + 3];
    float v0 = v[s0 * 64 + lane];
    float v1 = v[s1 * 64 + lane];
    float v2 = v[s2 * 64 + lane];
    float v3 = v[s3 * 64 + lane];
    m0 = fmaxf(m0, v0); m1 = fmaxf(m1, v1);
    m2 = fmaxf(m2, v2); m3 = fmaxf(m3, v3);
  }
  for (; i < deg; ++i) m0 = fmaxf(m0, v[ep[i] * 64 + lane]);
  float m = fmaxf(fmaxf(m0, m1), fmaxf(m2, m3));
  float hv = uh[node * 64 + lane] + bias[lane] + m;
  uh[node * 64 + lane] = fmaxf(hv, 0.f);   // relu(-inf) = 0 covers deg==0
}

// ---------- BN stats -> per-channel affine (alpha, beta) ----------
#define BN_NB 256
__global__ void bn_part_k(const float* __restrict__ h, float* __restrict__ part) {
  int c = threadIdx.x & 63;
  float s1 = 0.f, s2 = 0.f;
  int stride = gridDim.x * blockDim.x;  // multiple of 64 -> fixed channel per thread
  for (int i = blockIdx.x * blockDim.x + threadIdx.x; i < N_NODES * 64; i += stride) {
    float x = h[i];
    s1 += x;
    s2 += x * x;
  }
  __shared__ float l1[256], l2[256];
  l1[threadIdx.x] = s1; l2[threadIdx.x] = s2;
  __syncthreads();
  if (threadIdx.x < 64) {
    s1 = l1[c] + l1[c + 64] + l1[c + 128] + l1[c + 192];
    s2 = l2[c] + l2[c + 64] + l2[c + 128] + l2[c + 192];
    part[blockIdx.x * 128 + c] = s1;
    part[blockIdx.x * 128 + 64 + c] = s2;
  }
}

__global__ void bn_final_k(const float* __restrict__ part, const float* __restrict__ g,
                           const float* __restrict__ be, float* __restrict__ ab) {
  int c = threadIdx.x;
  if (c >= 64) return;
  float s1 = 0.f, s2 = 0.f;
  for (int b = 0; b < BN_NB; ++b) {
    s1 += part[b * 128 + c];
    s2 += part[b * 128 + 64 + c];
  }
  float mu = s1 / (float)N_NODES;
  float var = s2 / (float)N_NODES - mu * mu;
  float al = g[c] / sqrtf(var + EPS);
  ab[c] = al;
  ab[64 + c] = be[c] - mu * al;
}

// ---------- graph boundaries (batch is sorted) ----------
__global__ void bounds_k(const int* __restrict__ batch, u32* __restrict__ bounds) {
  int t = threadIdx.x;
  if (t > 64) return;
  int lo = 0, hi = N_NODES;
  while (lo < hi) {
    int mid = (lo + hi) >> 1;
    if (batch[mid] < t) lo = mid + 1; else hi = mid;
  }
  bounds[t] = (u32)lo;
}

// ---------- parallel mean pool: partial sums per graph ----------
__global__ void pool_part_k(const float* __restrict__ h3, const u32* __restrict__ bounds,
                            float* __restrict__ sums) {
  int g = blockIdx.y;
  u32 s = bounds[g], e = bounds[g + 1];
  int lane = threadIdx.x & 63;
  int wv = threadIdx.x >> 6;
  int nw = 4 * gridDim.x;
  u32 widx = blockIdx.x * 4 + wv;
  float acc = 0.f;
  for (u32 n = s + widx; n < e; n += nw) acc += h3[n * 64 + lane];
  __shared__ float l[256];
  l[threadIdx.x] = acc;
  __syncthreads();
  if (threadIdx.x < 64) {
    float t = l[lane] + l[lane + 64] + l[lane + 128] + l[lane + 192];
    atomicAdd(&sums[g * 64 + lane], t);
  }
}

// ---------- finalize pool (mean + BN3 affine) + linear head + softmax ----------
__global__ void head_k(const float* __restrict__ sums, const u32* __restrict__ bounds,
                       const float* __restrict__ ab3, const float* __restrict__ Wo,
                       const float* __restrict__ bo, float* __restrict__ out) {
  int g = threadIdx.x;
  if (g >= N_GRAPHS) return;
  u32 cntn = bounds[g + 1] - bounds[g];
  float inv = (cntn > 0) ? 1.f / (float)cntn : 0.f;
  float lg[10];
#pragma unroll
  for (int j = 0; j < 10; ++j) lg[j] = bo[j];
  for (int c = 0; c < 64; ++c) {
    float p = (cntn > 0) ? (sums[g * 64 + c] * inv * ab3[c] + ab3[64 + c]) : 0.f;
#pragma unroll
    for (int j = 0; j < 10; ++j) lg[j] = fmaf(p, Wo[c * 10 + j], lg[j]);
  }
  float mx = lg[0];
#pragma unroll
  for (int j = 1; j < 10; ++j) mx = fmaxf(mx, lg[j]);
  float s = 0.f, ex[10];
#pragma unroll
  for (int j = 0; j < 10; ++j) { ex[j] = expf(lg[j] - mx); s += ex[j]; }
#pragma unroll
  for (int j = 0; j < 10; ++j) out[g * 10 + j] = ex[j] / s;
}

extern "C" void kernel_launch(void* const* d_in, const int* in_sizes, int n_in,
                              void* d_out, int out_size, void* d_ws, size_t ws_size,
                              hipStream_t stream) {
  const float* x    = (const float*)d_in[0];
  const int*   ei   = (const int*)d_in[1];
  const int*   batch= (const int*)d_in[2];
  const float* W1 = (const float*)d_in[3];  const float* b1 = (const float*)d_in[4];
  const float* W2 = (const float*)d_in[5];  const float* b2 = (const float*)d_in[6];
  const float* W3 = (const float*)d_in[7];  const float* b3 = (const float*)d_in[8];
  const float* g1 = (const float*)d_in[9];  const float* be1= (const float*)d_in[10];
  const float* g2 = (const float*)d_in[11]; const float* be2= (const float*)d_in[12];
  const float* g3 = (const float*)d_in[13]; const float* be3= (const float*)d_in[14];
  const float* Wo = (const float*)d_in[15]; const float* bo = (const float*)d_in[16];
  float* out = (float*)d_out;

  char* p = (char*)d_ws;
  auto alloc = [&](size_t bytes) { void* r = (void*)p; p += (bytes + 255) & ~(size_t)255; return r; };
  float* Wm     = (float*)alloc(3 * 8192 * sizeof(float));
  float* ab     = (float*)alloc(3 * 128 * sizeof(float));
  u32*   bounds = (u32*)alloc(65 * sizeof(u32));
  u32*   cnt    = (u32*)alloc((size_t)N_NODES * sizeof(u32));
  u32*   offs   = (u32*)alloc((size_t)N_NODES * sizeof(u32));
  u32*   cursor = (u32*)alloc((size_t)N_NODES * sizeof(u32));  // doubles as incl-scan buf
  u32*   bsums  = (u32*)alloc(128 * sizeof(u32));
  float* part   = (float*)alloc((size_t)BN_NB * 128 * sizeof(float));
  float* sums   = (float*)alloc(64 * 64 * sizeof(float));
  u32*   esrc   = (u32*)alloc((size_t)N_EDGES * sizeof(u32));
  float* bufA   = (float*)alloc((size_t)N_NODES * 64 * sizeof(float));
  float* bufB   = (float*)alloc((size_t)N_NODES * 64 * sizeof(float));
  float* bufC   = (float*)alloc((size_t)N_NODES * 64 * sizeof(float));

  const int* src = ei;
  const int* dst = ei + N_EDGES;

  // weights prep + CSR build (edges identical for all 3 layers)
  prep_w_k<<<16, 256, 0, stream>>>(W1, W2, W3, Wm);
  hipMemsetAsync(cnt, 0, (size_t)N_NODES * sizeof(u32), stream);
  hist_k<<<(N_EDGES + 255) / 256, 256, 0, stream>>>(dst, cnt);
  scan1_k<<<(N_NODES + 1023) / 1024, 1024, 0, stream>>>(cnt, cursor, bsums, N_NODES);
  scan2_k<<<1, 128, 0, stream>>>(bsums, (N_NODES + 1023) / 1024);
  scan3_k<<<(N_NODES + 255) / 256, 256, 0, stream>>>(cursor, cnt, bsums, offs, N_NODES);
  hipMemsetAsync(cursor, 0, (size_t)N_NODES * sizeof(u32), stream);
  scatter_k<<<(N_EDGES + 255) / 256, 256, 0, stream>>>(src, dst, offs, cursor, esrc);
  bounds_k<<<1, 128, 0, stream>>>(batch, bounds);
  hipMemsetAsync(sums, 0, 64 * 64 * sizeof(float), stream);

  const int GEMM_GRID = 2048;
  const int SEG_GRID = N_NODES / 4;  // 4 nodes (waves) per 256-thread block

  // ---- layer 1: x -> bufA (h1), v in bufC ----
  gemm_half_k<<<GEMM_GRID, 256, 0, stream>>>(x, Wm, nullptr, 0, bufA);
  gemm_half_k<<<GEMM_GRID, 256, 0, stream>>>(x, Wm + 4096, nullptr, 0, bufC);
  segmax_k<<<SEG_GRID, 256, 0, stream>>>(bufC, offs, cnt, esrc, b1, bufA);
  bn_part_k<<<BN_NB, 256, 0, stream>>>(bufA, part);
  bn_final_k<<<1, 64, 0, stream>>>(part, g1, be1, ab);

  // ---- layer 2: bufA -> bufB (h2) ----
  gemm_half_k<<<GEMM_GRID, 256, 0, stream>>>(bufA, Wm + 8192, ab, 1, bufB);
  gemm_half_k<<<GEMM_GRID, 256, 0, stream>>>(bufA, Wm + 8192 + 4096, ab, 1, bufC);
  segmax_k<<<SEG_GRID, 256, 0, stream>>>(bufC, offs, cnt, esrc, b2, bufB);
  bn_part_k<<<BN_NB, 256, 0, stream>>>(bufB, part);
  bn_final_k<<<1, 64, 0, stream>>>(part, g2, be2, ab + 128);

  // ---- layer 3: bufB -> bufA (h3) ----
  gemm_half_k<<<GEMM_GRID, 256, 0, stream>>>(bufB, Wm + 16384, ab + 128, 1, bufA);
  gemm_half_k<<<GEMM_GRID, 256, 0, stream>>>(bufB, Wm + 16384 + 4096, ab + 128, 1, bufC);
  segmax_k<<<SEG_GRID, 256, 0, stream>>>(bufC, offs, cnt, esrc, b3, bufA);
  bn_part_k<<<BN_NB, 256, 0, stream>>>(bufA, part);
  bn_final_k<<<1, 64, 0, stream>>>(part, g3, be3, ab + 256);

  // ---- pool (+BN3 affine) + head ----
  pool_part_k<<<dim3(8, N_GRAPHS), 256, 0, stream>>>(bufA, bounds, sums);
  head_k<<<1, 64, 0, stream>>>(sums, bounds, ab + 256, Wo, bo, out);
}

// Round 3
// 738.371 us; speedup vs baseline: 1.6301x; 1.3002x over previous
//
#include <hip/hip_runtime.h>
#include <hip/hip_bf16.h>
#include <math.h>

#define N_NODES 100000
#define N_EDGES 1600000
#define N_GRAPHS 64
#define HID 64
#define EPS 1e-5f
#define NBUCK 391   // ceil(N_NODES / 256)

typedef unsigned int u32;

// ---------- weight prep: A' = A - B, B (per layer) ----------
__global__ void prep_w_k(const float* __restrict__ W1, const float* __restrict__ W2,
                         const float* __restrict__ W3, float* __restrict__ Wm) {
  int i = blockIdx.x * 256 + threadIdx.x;
  if (i >= 4096) return;
  const float* Ws[3] = {W1, W2, W3};
  for (int l = 0; l < 3; ++l) {
    float a = Ws[l][i];
    float b = Ws[l][4096 + i];
    Wm[l * 8192 + i] = a - b;          // A - B  (multiplies x[dst])
    Wm[l * 8192 + 4096 + i] = b;       // B      (multiplies x[src])
  }
}

// ---------- CSR build ----------
__global__ void hist_k(const int* __restrict__ dst, u32* __restrict__ cnt) {
  int e = blockIdx.x * 256 + threadIdx.x;
  if (e < N_EDGES) atomicAdd(&cnt[dst[e]], 1u);
}

__global__ void scan1_k(const u32* __restrict__ cnt, u32* __restrict__ incl,
                        u32* __restrict__ bsums, int n) {
  __shared__ u32 tmp[1024];
  int gid = blockIdx.x * 1024 + threadIdx.x;
  u32 v = (gid < n) ? cnt[gid] : 0u;
  tmp[threadIdx.x] = v;
  __syncthreads();
  for (int d = 1; d < 1024; d <<= 1) {
    u32 t = (threadIdx.x >= (u32)d) ? tmp[threadIdx.x - d] : 0u;
    __syncthreads();
    tmp[threadIdx.x] += t;
    __syncthreads();
  }
  if (gid < n) incl[gid] = tmp[threadIdx.x];
  if (threadIdx.x == 1023) bsums[blockIdx.x] = tmp[1023];
}

__global__ void scan2_k(u32* bsums, int nb) {
  __shared__ u32 t[128];
  u32 v = ((int)threadIdx.x < nb) ? bsums[threadIdx.x] : 0u;
  t[threadIdx.x] = v;
  __syncthreads();
  for (int d = 1; d < 128; d <<= 1) {
    u32 a = (threadIdx.x >= (u32)d) ? t[threadIdx.x - d] : 0u;
    __syncthreads();
    t[threadIdx.x] += a;
    __syncthreads();
  }
  if ((int)threadIdx.x < nb) bsums[threadIdx.x] = t[threadIdx.x] - v;  // exclusive
}

__global__ void scan3_k(const u32* __restrict__ incl, const u32* __restrict__ cnt,
                        const u32* __restrict__ bsums, u32* __restrict__ offs, int n) {
  int gid = blockIdx.x * 256 + threadIdx.x;
  if (gid < n) offs[gid] = incl[gid] - cnt[gid] + bsums[gid >> 10];
}

// ---------- bucketed edge scatter (bucket = dst>>8) ----------
__global__ void copycur_k(const u32* __restrict__ offs, u32* __restrict__ gcur) {
  int t = blockIdx.x * 256 + threadIdx.x;
  if (t < NBUCK) gcur[t] = offs[t * 256];
}

// pass C: edges -> bucket-grouped packed pairs ((dst&255)<<24 | src)
__global__ __launch_bounds__(256) void bscat_k(const int* __restrict__ src,
                                               const int* __restrict__ dst,
                                               u32* __restrict__ gcur,
                                               u32* __restrict__ pairs) {
  __shared__ u32 cnt[NBUCK];
  __shared__ u32 base[NBUCK];
  for (int i = threadIdx.x; i < NBUCK; i += 256) cnt[i] = 0;
  __syncthreads();
  u32 pk[8], bk[8];
  int be = blockIdx.x * 2048;
#pragma unroll
  for (int k = 0; k < 8; ++k) {
    int e = be + k * 256 + threadIdx.x;
    if (e < N_EDGES) {
      u32 d = (u32)dst[e], s = (u32)src[e];
      u32 b = d >> 8;
      pk[k] = ((d & 255u) << 24) | s;
      bk[k] = b;
      atomicAdd(&cnt[b], 1u);
    } else bk[k] = 0xFFFFFFFFu;
  }
  __syncthreads();
  for (int i = threadIdx.x; i < NBUCK; i += 256) {
    u32 c = cnt[i];
    base[i] = c ? atomicAdd(&gcur[i], c) : 0u;
    cnt[i] = 0;
  }
  __syncthreads();
#pragma unroll
  for (int k = 0; k < 8; ++k) {
    if (bk[k] != 0xFFFFFFFFu) {
      u32 p = base[bk[k]] + atomicAdd(&cnt[bk[k]], 1u);
      pairs[p] = pk[k];
    }
  }
}

// pass D: within-bucket placement into CSR esrc (bucket window ~16KB -> L2 resident)
__global__ __launch_bounds__(256) void fscat_k(const u32* __restrict__ offs,
                                               const u32* __restrict__ pairs,
                                               u32* __restrict__ esrc) {
  __shared__ u32 loffs[256];
  __shared__ u32 lcnt[256];
  int b = blockIdx.x;
  int nb0 = b << 8;
  int t = threadIdx.x;
  loffs[t] = (nb0 + t < N_NODES) ? offs[nb0 + t] : 0u;
  lcnt[t] = 0;
  __syncthreads();
  u32 start = loffs[0];
  u32 end = (b == NBUCK - 1) ? (u32)N_EDGES : offs[nb0 + 256];
  for (u32 p = start + t; p < end; p += 256) {
    u32 pk = pairs[p];
    u32 dl = pk >> 24;
    u32 s = pk & 0x00FFFFFFu;
    u32 l = atomicAdd(&lcnt[dl], 1u);
    esrc[loffs[dl] + l] = s;
  }
}

// ---------- fused node GEMM: u = act(x)@(A-B) + bias, v = act(x)@B ----------
// act: 0 = identity (layer 1), 1 = relu(x*alpha + beta) (folded BN from prev layer)
__global__ __launch_bounds__(256, 1) void gemm_uv_k(
    const float* __restrict__ x, const float* __restrict__ Wm,
    const float* __restrict__ ab, const float* __restrict__ bias, int act,
    float* __restrict__ u, float* __restrict__ v) {
  int lane = threadIdx.x & 63;
  int wid = (blockIdx.x * 256 + threadIdx.x) >> 6;
  int nw = (gridDim.x * 256) >> 6;
  float wa[64], wb[64];
#pragma unroll
  for (int k = 0; k < 64; ++k) {
    wa[k] = Wm[k * 64 + lane];
    wb[k] = Wm[4096 + k * 64 + lane];
  }
  float al = 1.f, bet = 0.f;
  if (act) { al = ab[lane]; bet = ab[64 + lane]; }
  float bs = bias[lane];
  for (int row = wid; row < N_NODES; row += nw) {
    float xr = x[row * 64 + lane];
    if (act) xr = fmaxf(fmaf(xr, al, bet), 0.f);
    float su = bs, sv = 0.f;
#pragma unroll
    for (int k = 0; k < 64; ++k) {
      float xv = __shfl(xr, k, 64);
      su = fmaf(xv, wa[k], su);
      sv = fmaf(xv, wb[k], sv);
    }
    u[row * 64 + lane] = su;
    v[row * 64 + lane] = sv;
  }
}

// ---------- per-node segment max over incoming edges + combine (in place over u) ----------
__global__ __launch_bounds__(256) void segmax_k(
    const float* __restrict__ v, const u32* __restrict__ offs,
    const u32* __restrict__ cnt, const u32* __restrict__ edge_src,
    float* __restrict__ uh) {
  int lane = threadIdx.x & 63;
  int node = blockIdx.x * 4 + (threadIdx.x >> 6);
  if (node >= N_NODES) return;
  u32 off = offs[node];
  u32 deg = cnt[node];
  const u32* ep = edge_src + off;
  float m0 = -INFINITY, m1 = -INFINITY, m2 = -INFINITY, m3 = -INFINITY;
  float m4 = -INFINITY, m5 = -INFINITY, m6 = -INFINITY, m7 = -INFINITY;
  u32 i = 0;
  for (; i + 8 <= deg; i += 8) {
    u32 s0 = ep[i], s1 = ep[i+1], s2 = ep[i+2], s3 = ep[i+3];
    u32 s4 = ep[i+4], s5 = ep[i+5], s6 = ep[i+6], s7 = ep[i+7];
    m0 = fmaxf(m0, v[s0 * 64 + lane]);
    m1 = fmaxf(m1, v[s1 * 64 + lane]);
    m2 = fmaxf(m2, v[s2 * 64 + lane]);
    m3 = fmaxf(m3, v[s3 * 64 + lane]);
    m4 = fmaxf(m4, v[s4 * 64 + lane]);
    m5 = fmaxf(m5, v[s5 * 64 + lane]);
    m6 = fmaxf(m6, v[s6 * 64 + lane]);
    m7 = fmaxf(m7, v[s7 * 64 + lane]);
  }
  for (; i < deg; ++i) m0 = fmaxf(m0, v[ep[i] * 64 + lane]);
  float m = fmaxf(fmaxf(fmaxf(m0, m1), fmaxf(m2, m3)),
                  fmaxf(fmaxf(m4, m5), fmaxf(m6, m7)));
  float hv = uh[node * 64 + lane] + m;   // bias already folded into u
  uh[node * 64 + lane] = fmaxf(hv, 0.f); // relu(-inf) = 0 covers deg==0
}

// ---------- BN stats -> per-channel affine (alpha, beta) ----------
#define BN_NB 256
__global__ void bn_part_k(const float* __restrict__ h, float* __restrict__ part) {
  int c = threadIdx.x & 63;
  float s1 = 0.f, s2 = 0.f;
  int stride = gridDim.x * blockDim.x;  // multiple of 64 -> fixed channel per thread
  for (int i = blockIdx.x * blockDim.x + threadIdx.x; i < N_NODES * 64; i += stride) {
    float x = h[i];
    s1 += x;
    s2 += x * x;
  }
  __shared__ float l1[256], l2[256];
  l1[threadIdx.x] = s1; l2[threadIdx.x] = s2;
  __syncthreads();
  if (threadIdx.x < 64) {
    s1 = l1[c] + l1[c + 64] + l1[c + 128] + l1[c + 192];
    s2 = l2[c] + l2[c + 64] + l2[c + 128] + l2[c + 192];
    part[blockIdx.x * 128 + c] = s1;
    part[blockIdx.x * 128 + 64 + c] = s2;
  }
}

__global__ void bn_final_k(const float* __restrict__ part, const float* __restrict__ g,
                           const float* __restrict__ be, float* __restrict__ ab) {
  int c = threadIdx.x;
  if (c >= 64) return;
  float s1 = 0.f, s2 = 0.f;
  for (int b = 0; b < BN_NB; ++b) {
    s1 += part[b * 128 + c];
    s2 += part[b * 128 + 64 + c];
  }
  float mu = s1 / (float)N_NODES;
  float var = s2 / (float)N_NODES - mu * mu;
  float al = g[c] / sqrtf(var + EPS);
  ab[c] = al;
  ab[64 + c] = be[c] - mu * al;
}

// ---------- graph boundaries (batch is sorted) ----------
__global__ void bounds_k(const int* __restrict__ batch, u32* __restrict__ bounds) {
  int t = threadIdx.x;
  if (t > 64) return;
  int lo = 0, hi = N_NODES;
  while (lo < hi) {
    int mid = (lo + hi) >> 1;
    if (batch[mid] < t) lo = mid + 1; else hi = mid;
  }
  bounds[t] = (u32)lo;
}

// ---------- parallel mean pool: partial sums per graph ----------
__global__ void pool_part_k(const float* __restrict__ h3, const u32* __restrict__ bounds,
                            float* __restrict__ sums) {
  int g = blockIdx.y;
  u32 s = bounds[g], e = bounds[g + 1];
  int lane = threadIdx.x & 63;
  int wv = threadIdx.x >> 6;
  int nw = 4 * gridDim.x;
  u32 widx = blockIdx.x * 4 + wv;
  float acc = 0.f;
  for (u32 n = s + widx; n < e; n += nw) acc += h3[n * 64 + lane];
  __shared__ float l[256];
  l[threadIdx.x] = acc;
  __syncthreads();
  if (threadIdx.x < 64) {
    float t = l[lane] + l[lane + 64] + l[lane + 128] + l[lane + 192];
    atomicAdd(&sums[g * 64 + lane], t);
  }
}

// ---------- finalize pool (mean + BN3 affine) + linear head + softmax ----------
__global__ void head_k(const float* __restrict__ sums, const u32* __restrict__ bounds,
                       const float* __restrict__ ab3, const float* __restrict__ Wo,
                       const float* __restrict__ bo, float* __restrict__ out) {
  int g = threadIdx.x;
  if (g >= N_GRAPHS) return;
  u32 cntn = bounds[g + 1] - bounds[g];
  float inv = (cntn > 0) ? 1.f / (float)cntn : 0.f;
  float lg[10];
#pragma unroll
  for (int j = 0; j < 10; ++j) lg[j] = bo[j];
  for (int c = 0; c < 64; ++c) {
    float p = (cntn > 0) ? (sums[g * 64 + c] * inv * ab3[c] + ab3[64 + c]) : 0.f;
#pragma unroll
    for (int j = 0; j < 10; ++j) lg[j] = fmaf(p, Wo[c * 10 + j], lg[j]);
  }
  float mx = lg[0];
#pragma unroll
  for (int j = 1; j < 10; ++j) mx = fmaxf(mx, lg[j]);
  float s = 0.f, ex[10];
#pragma unroll
  for (int j = 0; j < 10; ++j) { ex[j] = expf(lg[j] - mx); s += ex[j]; }
#pragma unroll
  for (int j = 0; j < 10; ++j) out[g * 10 + j] = ex[j] / s;
}

extern "C" void kernel_launch(void* const* d_in, const int* in_sizes, int n_in,
                              void* d_out, int out_size, void* d_ws, size_t ws_size,
                              hipStream_t stream) {
  const float* x    = (const float*)d_in[0];
  const int*   ei   = (const int*)d_in[1];
  const int*   batch= (const int*)d_in[2];
  const float* W1 = (const float*)d_in[3];  const float* b1 = (const float*)d_in[4];
  const float* W2 = (const float*)d_in[5];  const float* b2 = (const float*)d_in[6];
  const float* W3 = (const float*)d_in[7];  const float* b3 = (const float*)d_in[8];
  const float* g1 = (const float*)d_in[9];  const float* be1= (const float*)d_in[10];
  const float* g2 = (const float*)d_in[11]; const float* be2= (const float*)d_in[12];
  const float* g3 = (const float*)d_in[13]; const float* be3= (const float*)d_in[14];
  const float* Wo = (const float*)d_in[15]; const float* bo = (const float*)d_in[16];
  float* out = (float*)d_out;

  char* p = (char*)d_ws;
  auto alloc = [&](size_t bytes) { void* r = (void*)p; p += (bytes + 255) & ~(size_t)255; return r; };
  float* Wm     = (float*)alloc(3 * 8192 * sizeof(float));
  float* ab     = (float*)alloc(3 * 128 * sizeof(float));
  u32*   bounds = (u32*)alloc(65 * sizeof(u32));
  u32*   cnt    = (u32*)alloc((size_t)N_NODES * sizeof(u32));
  u32*   offs   = (u32*)alloc((size_t)N_NODES * sizeof(u32));
  u32*   cursor = (u32*)alloc((size_t)N_NODES * sizeof(u32));  // incl-scan buf, then bucket cursors
  u32*   bsums  = (u32*)alloc(128 * sizeof(u32));
  float* part   = (float*)alloc((size_t)BN_NB * 128 * sizeof(float));
  float* sums   = (float*)alloc(64 * 64 * sizeof(float));
  u32*   esrc   = (u32*)alloc((size_t)N_EDGES * sizeof(u32));
  u32*   pairs  = (u32*)alloc((size_t)N_EDGES * sizeof(u32));
  float* bufA   = (float*)alloc((size_t)N_NODES * 64 * sizeof(float));
  float* bufB   = (float*)alloc((size_t)N_NODES * 64 * sizeof(float));
  float* bufC   = (float*)alloc((size_t)N_NODES * 64 * sizeof(float));

  const int* src = ei;
  const int* dst = ei + N_EDGES;

  // weights prep + CSR build (edges identical for all 3 layers)
  prep_w_k<<<16, 256, 0, stream>>>(W1, W2, W3, Wm);
  hipMemsetAsync(cnt, 0, (size_t)N_NODES * sizeof(u32), stream);
  hist_k<<<(N_EDGES + 255) / 256, 256, 0, stream>>>(dst, cnt);
  scan1_k<<<(N_NODES + 1023) / 1024, 1024, 0, stream>>>(cnt, cursor, bsums, N_NODES);
  scan2_k<<<1, 128, 0, stream>>>(bsums, (N_NODES + 1023) / 1024);
  scan3_k<<<(N_NODES + 255) / 256, 256, 0, stream>>>(cursor, cnt, bsums, offs, N_NODES);
  copycur_k<<<2, 256, 0, stream>>>(offs, cursor);
  bscat_k<<<(N_EDGES + 2047) / 2048, 256, 0, stream>>>(src, dst, cursor, pairs);
  fscat_k<<<NBUCK, 256, 0, stream>>>(offs, pairs, esrc);
  bounds_k<<<1, 128, 0, stream>>>(batch, bounds);
  hipMemsetAsync(sums, 0, 64 * 64 * sizeof(float), stream);

  const int GEMM_GRID = 768;
  const int SEG_GRID = N_NODES / 4;  // 4 nodes (waves) per 256-thread block

  // ---- layer 1: x -> bufA (h1), v in bufC ----
  gemm_uv_k<<<GEMM_GRID, 256, 0, stream>>>(x, Wm, nullptr, b1, 0, bufA, bufC);
  segmax_k<<<SEG_GRID, 256, 0, stream>>>(bufC, offs, cnt, esrc, bufA);
  bn_part_k<<<BN_NB, 256, 0, stream>>>(bufA, part);
  bn_final_k<<<1, 64, 0, stream>>>(part, g1, be1, ab);

  // ---- layer 2: bufA -> bufB (h2) ----
  gemm_uv_k<<<GEMM_GRID, 256, 0, stream>>>(bufA, Wm + 8192, ab, b2, 1, bufB, bufC);
  segmax_k<<<SEG_GRID, 256, 0, stream>>>(bufC, offs, cnt, esrc, bufB);
  bn_part_k<<<BN_NB, 256, 0, stream>>>(bufB, part);
  bn_final_k<<<1, 64, 0, stream>>>(part, g2, be2, ab + 128);

  // ---- layer 3: bufB -> bufA (h3) ----
  gemm_uv_k<<<GEMM_GRID, 256, 0, stream>>>(bufB, Wm + 16384, ab + 128, b3, 1, bufA, bufC);
  segmax_k<<<SEG_GRID, 256, 0, stream>>>(bufC, offs, cnt, esrc, bufA);
  bn_part_k<<<BN_NB, 256, 0, stream>>>(bufA, part);
  bn_final_k<<<1, 64, 0, stream>>>(part, g3, be3, ab + 256);

  // ---- pool (+BN3 affine) + head ----
  pool_part_k<<<dim3(8, N_GRAPHS), 256, 0, stream>>>(bufA, bounds, sums);
  head_k<<<1, 64, 0, stream>>>(sums, bounds, ab + 256, Wo, bo, out);
}

// Round 4
// 710.787 us; speedup vs baseline: 1.6933x; 1.0388x over previous
//
#include <hip/hip_runtime.h>
#include <hip/hip_bf16.h>
#include <math.h>

#define N_NODES 100000
#define N_EDGES 1600000
#define N_GRAPHS 64
#define EPS 1e-5f
#define NBUCK 391     // ceil(N_NODES / 256)
#define SEG_NBLK 640  // segmax blocks (8 node-slots each)

typedef unsigned int u32;

static __device__ __forceinline__ ushort f2bf(float f) {
  u32 x = __float_as_uint(f);
  u32 r = (x + 0x7fffu + ((x >> 16) & 1u)) >> 16;  // RNE; inputs finite
  return (ushort)r;
}
static __device__ __forceinline__ float bflo(u32 w) { return __uint_as_float(w << 16); }
static __device__ __forceinline__ float bfhi(u32 w) { return __uint_as_float(w & 0xffff0000u); }

// ---------- weight prep: A' = A - B | B (per layer), f32 ----------
__global__ void prep_w_k(const float* __restrict__ W1, const float* __restrict__ W2,
                         const float* __restrict__ W3, float* __restrict__ Wm) {
  int i = blockIdx.x * 256 + threadIdx.x;
  if (i >= 4096) return;
  const float* Ws[3] = {W1, W2, W3};
  for (int l = 0; l < 3; ++l) {
    float a = Ws[l][i];
    float b = Ws[l][4096 + i];
    Wm[l * 8192 + i] = a - b;          // A - B  (multiplies x_i)
    Wm[l * 8192 + 4096 + i] = b;       // B      (multiplies x_j)
  }
}

// ---------- CSR build ----------
__global__ void hist_k(const int* __restrict__ dst, u32* __restrict__ cnt) {
  int e = blockIdx.x * 256 + threadIdx.x;
  if (e < N_EDGES) atomicAdd(&cnt[dst[e]], 1u);
}

__global__ void scan1_k(const u32* __restrict__ cnt, u32* __restrict__ incl,
                        u32* __restrict__ bsums, int n) {
  __shared__ u32 tmp[1024];
  int gid = blockIdx.x * 1024 + threadIdx.x;
  u32 v = (gid < n) ? cnt[gid] : 0u;
  tmp[threadIdx.x] = v;
  __syncthreads();
  for (int d = 1; d < 1024; d <<= 1) {
    u32 t = (threadIdx.x >= (u32)d) ? tmp[threadIdx.x - d] : 0u;
    __syncthreads();
    tmp[threadIdx.x] += t;
    __syncthreads();
  }
  if (gid < n) incl[gid] = tmp[threadIdx.x];
  if (threadIdx.x == 1023) bsums[blockIdx.x] = tmp[1023];
}

__global__ void scan2_k(u32* bsums, int nb) {
  __shared__ u32 t[128];
  u32 v = ((int)threadIdx.x < nb) ? bsums[threadIdx.x] : 0u;
  t[threadIdx.x] = v;
  __syncthreads();
  for (int d = 1; d < 128; d <<= 1) {
    u32 a = (threadIdx.x >= (u32)d) ? t[threadIdx.x - d] : 0u;
    __syncthreads();
    t[threadIdx.x] += a;
    __syncthreads();
  }
  if ((int)threadIdx.x < nb) bsums[threadIdx.x] = t[threadIdx.x] - v;  // exclusive
}

__global__ void scan3_k(const u32* __restrict__ incl, const u32* __restrict__ cnt,
                        const u32* __restrict__ bsums, u32* __restrict__ offs, int n) {
  int gid = blockIdx.x * 256 + threadIdx.x;
  if (gid < n) offs[gid] = incl[gid] - cnt[gid] + bsums[gid >> 10];
}

// ---------- bucketed edge scatter (bucket = dst>>8) ----------
__global__ void copycur_k(const u32* __restrict__ offs, u32* __restrict__ gcur) {
  int t = blockIdx.x * 256 + threadIdx.x;
  if (t < NBUCK) gcur[t] = offs[t * 256];
}

__global__ __launch_bounds__(256) void bscat_k(const int* __restrict__ src,
                                               const int* __restrict__ dst,
                                               u32* __restrict__ gcur,
                                               u32* __restrict__ pairs) {
  __shared__ u32 cnt[NBUCK];
  __shared__ u32 base[NBUCK];
  for (int i = threadIdx.x; i < NBUCK; i += 256) cnt[i] = 0;
  __syncthreads();
  u32 pk[8], bk[8];
  int be = blockIdx.x * 2048;
#pragma unroll
  for (int k = 0; k < 8; ++k) {
    int e = be + k * 256 + threadIdx.x;
    if (e < N_EDGES) {
      u32 d = (u32)dst[e], s = (u32)src[e];
      u32 b = d >> 8;
      pk[k] = ((d & 255u) << 24) | s;
      bk[k] = b;
      atomicAdd(&cnt[b], 1u);
    } else bk[k] = 0xFFFFFFFFu;
  }
  __syncthreads();
  for (int i = threadIdx.x; i < NBUCK; i += 256) {
    u32 c = cnt[i];
    base[i] = c ? atomicAdd(&gcur[i], c) : 0u;
    cnt[i] = 0;
  }
  __syncthreads();
#pragma unroll
  for (int k = 0; k < 8; ++k) {
    if (bk[k] != 0xFFFFFFFFu) {
      u32 p = base[bk[k]] + atomicAdd(&cnt[bk[k]], 1u);
      pairs[p] = pk[k];
    }
  }
}

__global__ __launch_bounds__(256) void fscat_k(const u32* __restrict__ offs,
                                               const u32* __restrict__ pairs,
                                               u32* __restrict__ esrc) {
  __shared__ u32 loffs[256];
  __shared__ u32 lcnt[256];
  int b = blockIdx.x;
  int nb0 = b << 8;
  int t = threadIdx.x;
  loffs[t] = (nb0 + t < N_NODES) ? offs[nb0 + t] : 0u;
  lcnt[t] = 0;
  __syncthreads();
  u32 start = loffs[0];
  u32 end = (b == NBUCK - 1) ? (u32)N_EDGES : offs[nb0 + 256];
  for (u32 p = start + t; p < end; p += 256) {
    u32 pk = pairs[p];
    u32 dl = pk >> 24;
    u32 s = pk & 0x00FFFFFFu;
    u32 l = atomicAdd(&lcnt[dl], 1u);
    esrc[loffs[dl] + l] = s;
  }
}

// ---------- LDS-tiled GEMM: [u | v] = act(X) @ [A-B | B] ----------
// X: f32 (layer 1) or bf16 (layers 2,3), [N][64]. act = relu(x*al+be) if ab != null.
// u: f32 [N][64] (+bias folded), v: bf16 [N][64].
// Block: 256 thr; tile 64 rows x 128 cols; thread = 8 rows x 4 cols.
__global__ __launch_bounds__(256) void gemm_uv_k(
    const void* __restrict__ xin, int xbf16,
    const float* __restrict__ Wm, const float* __restrict__ ab,
    const float* __restrict__ bias,
    float* __restrict__ u, ushort* __restrict__ vb) {
  __shared__ float Wl[64 * 128];
  __shared__ float Xl[64 * 64];
  int t = threadIdx.x;
  // stage weights once: Wl[k*128 + c]
  for (int rep = 0; rep < 32; ++rep) {
    int idx = rep * 256 + t;
    int k = idx >> 7, c = idx & 127;
    Wl[idx] = (c < 64) ? Wm[k * 64 + c] : Wm[4096 + k * 64 + (c - 64)];
  }
  int tcol = t & 31, trow = t >> 5;
  int c0 = tcol * 4;
  bool is_u = (c0 < 64);
  float binit[4];
#pragma unroll
  for (int j = 0; j < 4; ++j) binit[j] = is_u ? bias[c0 + j] : 0.f;
  // staging role: row srow, 16 cols at scol
  int srow = t >> 2, scol = (t & 3) * 16;
  float sal[16], sbe[16];
  if (ab) {
#pragma unroll
    for (int j = 0; j < 16; ++j) { sal[j] = ab[scol + j]; sbe[j] = ab[64 + scol + j]; }
  }
  for (int tile = blockIdx.x; tile * 64 < N_NODES; tile += gridDim.x) {
    int rb = tile * 64;
    __syncthreads();  // Xl reuse guard
    float xv[16];
    int gr = rb + srow;
    if (gr < N_NODES) {
      if (xbf16) {
        const uint4* xp = (const uint4*)((const ushort*)xin + (size_t)gr * 64 + scol);
        uint4 p0 = xp[0], p1 = xp[1];
        xv[0] = bflo(p0.x); xv[1] = bfhi(p0.x); xv[2] = bflo(p0.y); xv[3] = bfhi(p0.y);
        xv[4] = bflo(p0.z); xv[5] = bfhi(p0.z); xv[6] = bflo(p0.w); xv[7] = bfhi(p0.w);
        xv[8] = bflo(p1.x); xv[9] = bfhi(p1.x); xv[10] = bflo(p1.y); xv[11] = bfhi(p1.y);
        xv[12] = bflo(p1.z); xv[13] = bfhi(p1.z); xv[14] = bflo(p1.w); xv[15] = bfhi(p1.w);
      } else {
        const float4* xp = (const float4*)((const float*)xin + (size_t)gr * 64 + scol);
        float4 a0 = xp[0], a1 = xp[1], a2 = xp[2], a3 = xp[3];
        xv[0] = a0.x; xv[1] = a0.y; xv[2] = a0.z; xv[3] = a0.w;
        xv[4] = a1.x; xv[5] = a1.y; xv[6] = a1.z; xv[7] = a1.w;
        xv[8] = a2.x; xv[9] = a2.y; xv[10] = a2.z; xv[11] = a2.w;
        xv[12] = a3.x; xv[13] = a3.y; xv[14] = a3.z; xv[15] = a3.w;
      }
    } else {
#pragma unroll
      for (int j = 0; j < 16; ++j) xv[j] = 0.f;
    }
    if (ab) {
#pragma unroll
      for (int j = 0; j < 16; ++j) xv[j] = fmaxf(fmaf(xv[j], sal[j], sbe[j]), 0.f);
    }
#pragma unroll
    for (int j = 0; j < 16; ++j) Xl[srow * 64 + scol + j] = xv[j];
    __syncthreads();
    float acc[8][4];
#pragma unroll
    for (int i = 0; i < 8; ++i)
#pragma unroll
      for (int j = 0; j < 4; ++j) acc[i][j] = binit[j];
#pragma unroll 4
    for (int k = 0; k < 64; ++k) {
      float4 bv = *(const float4*)&Wl[k * 128 + c0];
#pragma unroll
      for (int i = 0; i < 8; ++i) {
        float a = Xl[(trow * 8 + i) * 64 + k];
        acc[i][0] = fmaf(a, bv.x, acc[i][0]);
        acc[i][1] = fmaf(a, bv.y, acc[i][1]);
        acc[i][2] = fmaf(a, bv.z, acc[i][2]);
        acc[i][3] = fmaf(a, bv.w, acc[i][3]);
      }
    }
    if (is_u) {
#pragma unroll
      for (int i = 0; i < 8; ++i) {
        int r = rb + trow * 8 + i;
        if (r < N_NODES) {
          float4 s = make_float4(acc[i][0], acc[i][1], acc[i][2], acc[i][3]);
          *(float4*)&u[(size_t)r * 64 + c0] = s;
        }
      }
    } else {
#pragma unroll
      for (int i = 0; i < 8; ++i) {
        int r = rb + trow * 8 + i;
        if (r < N_NODES) {
          u32 w0 = (u32)f2bf(acc[i][0]) | ((u32)f2bf(acc[i][1]) << 16);
          u32 w1 = (u32)f2bf(acc[i][2]) | ((u32)f2bf(acc[i][3]) << 16);
          uint2 s = make_uint2(w0, w1);
          *(uint2*)&vb[(size_t)r * 64 + (c0 - 64)] = s;
        }
      }
    }
  }
}

// ---------- segmax (bf16 v) + h = relu(u + max) -> bf16 h, + BN partials ----------
// wave: 2 nodes (32 lanes each), lane handles channel pair (2cp, 2cp+1) via one u32.
__global__ __launch_bounds__(256) void segmax_k(
    const ushort* __restrict__ v, const u32* __restrict__ offs,
    const u32* __restrict__ cnt, const u32* __restrict__ edge_src,
    const float* __restrict__ u, ushort* __restrict__ h,
    float* __restrict__ part) {
  int t = threadIdx.x;
  int lane = t & 63;
  int sub = lane >> 5;
  int cp = lane & 31;
  int wv = t >> 6;
  int slot = blockIdx.x * 8 + wv * 2 + sub;
  const int nslots = SEG_NBLK * 8;
  const u32* vw = (const u32*)v;
  float s1lo = 0.f, s1hi = 0.f, s2lo = 0.f, s2hi = 0.f;
  for (int node = slot; node < N_NODES; node += nslots) {
    u32 off = offs[node], deg = cnt[node];
    const u32* ep = edge_src + off;
    float l0 = -INFINITY, l1 = -INFINITY, l2 = -INFINITY, l3 = -INFINITY;
    float h0 = -INFINITY, h1 = -INFINITY, h2 = -INFINITY, h3 = -INFINITY;
    u32 i = 0;
    for (; i + 8 <= deg; i += 8) {
      u32 s0 = ep[i], s1_ = ep[i+1], s2_ = ep[i+2], s3_ = ep[i+3];
      u32 s4 = ep[i+4], s5 = ep[i+5], s6 = ep[i+6], s7 = ep[i+7];
      u32 w0 = vw[(size_t)s0 * 32 + cp];
      u32 w1 = vw[(size_t)s1_ * 32 + cp];
      u32 w2 = vw[(size_t)s2_ * 32 + cp];
      u32 w3 = vw[(size_t)s3_ * 32 + cp];
      u32 w4 = vw[(size_t)s4 * 32 + cp];
      u32 w5 = vw[(size_t)s5 * 32 + cp];
      u32 w6 = vw[(size_t)s6 * 32 + cp];
      u32 w7 = vw[(size_t)s7 * 32 + cp];
      l0 = fmaxf(l0, bflo(w0)); h0 = fmaxf(h0, bfhi(w0));
      l1 = fmaxf(l1, bflo(w1)); h1 = fmaxf(h1, bfhi(w1));
      l2 = fmaxf(l2, bflo(w2)); h2 = fmaxf(h2, bfhi(w2));
      l3 = fmaxf(l3, bflo(w3)); h3 = fmaxf(h3, bfhi(w3));
      l0 = fmaxf(l0, bflo(w4)); h0 = fmaxf(h0, bfhi(w4));
      l1 = fmaxf(l1, bflo(w5)); h1 = fmaxf(h1, bfhi(w5));
      l2 = fmaxf(l2, bflo(w6)); h2 = fmaxf(h2, bfhi(w6));
      l3 = fmaxf(l3, bflo(w7)); h3 = fmaxf(h3, bfhi(w7));
    }
    for (; i < deg; ++i) {
      u32 w = vw[(size_t)ep[i] * 32 + cp];
      l0 = fmaxf(l0, bflo(w)); h0 = fmaxf(h0, bfhi(w));
    }
    float mlo = fmaxf(fmaxf(l0, l1), fmaxf(l2, l3));
    float mhi = fmaxf(fmaxf(h0, h1), fmaxf(h2, h3));
    float2 uv = *(const float2*)&u[(size_t)node * 64 + 2 * cp];
    float hlo = fmaxf(uv.x + mlo, 0.f);  // relu(-inf)=0 covers deg==0
    float hhi = fmaxf(uv.y + mhi, 0.f);
    ((u32*)h)[(size_t)node * 32 + cp] = (u32)f2bf(hlo) | ((u32)f2bf(hhi) << 16);
    s1lo += hlo; s2lo += hlo * hlo;
    s1hi += hhi; s2hi += hhi * hhi;
  }
  __shared__ float4 red[256];
  red[t] = make_float4(s1lo, s1hi, s2lo, s2hi);
  __syncthreads();
  if (t < 32) {
    float4 a = red[t];
#pragma unroll
    for (int j = 1; j < 8; ++j) {
      float4 b = red[t + 32 * j];
      a.x += b.x; a.y += b.y; a.z += b.z; a.w += b.w;
    }
    part[blockIdx.x * 128 + 2 * t]      = a.x;
    part[blockIdx.x * 128 + 2 * t + 1]  = a.y;
    part[blockIdx.x * 128 + 64 + 2 * t]     = a.z;
    part[blockIdx.x * 128 + 64 + 2 * t + 1] = a.w;
  }
}

// ---------- BN finalize: reduce partials -> per-channel affine ----------
__global__ void bn_final_k(const float* __restrict__ part, const float* __restrict__ g,
                           const float* __restrict__ be, float* __restrict__ ab) {
  int t = threadIdx.x;       // 256
  int c = t & 63, q = t >> 6;
  float s1 = 0.f, s2 = 0.f;
  for (int b = q; b < SEG_NBLK; b += 4) {
    s1 += part[b * 128 + c];
    s2 += part[b * 128 + 64 + c];
  }
  __shared__ float r1[256], r2[256];
  r1[t] = s1; r2[t] = s2;
  __syncthreads();
  if (t < 64) {
    s1 = r1[t] + r1[t + 64] + r1[t + 128] + r1[t + 192];
    s2 = r2[t] + r2[t + 64] + r2[t + 128] + r2[t + 192];
    float mu = s1 / (float)N_NODES;
    float var = s2 / (float)N_NODES - mu * mu;
    float al = g[t] / sqrtf(var + EPS);
    ab[t] = al;
    ab[64 + t] = be[t] - mu * al;
  }
}

// ---------- graph boundaries (batch is sorted) ----------
__global__ void bounds_k(const int* __restrict__ batch, u32* __restrict__ bounds) {
  int t = threadIdx.x;
  if (t > 64) return;
  int lo = 0, hi = N_NODES;
  while (lo < hi) {
    int mid = (lo + hi) >> 1;
    if (batch[mid] < t) lo = mid + 1; else hi = mid;
  }
  bounds[t] = (u32)lo;
}

// ---------- parallel mean pool over bf16 h3 ----------
__global__ void pool_part_k(const ushort* __restrict__ h3, const u32* __restrict__ bounds,
                            float* __restrict__ sums) {
  int g = blockIdx.y;
  u32 s = bounds[g], e = bounds[g + 1];
  int t = threadIdx.x;
  int lane = t & 63, wv = t >> 6, sub = lane >> 5, cp = lane & 31;
  int slot = blockIdx.x * 8 + wv * 2 + sub;
  int nsl = gridDim.x * 8;
  const u32* hw = (const u32*)h3;
  float alo = 0.f, ahi = 0.f;
  for (u32 n = s + slot; n < e; n += nsl) {
    u32 w = hw[(size_t)n * 32 + cp];
    alo += bflo(w);
    ahi += bfhi(w);
  }
  __shared__ float2 red[256];
  red[t] = make_float2(alo, ahi);
  __syncthreads();
  if (t < 32) {
    float2 a = red[t];
#pragma unroll
    for (int j = 1; j < 8; ++j) {
      float2 b = red[t + 32 * j];
      a.x += b.x; a.y += b.y;
    }
    atomicAdd(&sums[g * 64 + 2 * t], a.x);
    atomicAdd(&sums[g * 64 + 2 * t + 1], a.y);
  }
}

// ---------- finalize pool (mean + BN3 affine) + linear head + softmax ----------
__global__ void head_k(const float* __restrict__ sums, const u32* __restrict__ bounds,
                       const float* __restrict__ ab3, const float* __restrict__ Wo,
                       const float* __restrict__ bo, float* __restrict__ out) {
  int g = threadIdx.x;
  if (g >= N_GRAPHS) return;
  u32 cntn = bounds[g + 1] - bounds[g];
  float inv = (cntn > 0) ? 1.f / (float)cntn : 0.f;
  float lg[10];
#pragma unroll
  for (int j = 0; j < 10; ++j) lg[j] = bo[j];
  for (int c = 0; c < 64; ++c) {
    float p = (cntn > 0) ? (sums[g * 64 + c] * inv * ab3[c] + ab3[64 + c]) : 0.f;
#pragma unroll
    for (int j = 0; j < 10; ++j) lg[j] = fmaf(p, Wo[c * 10 + j], lg[j]);
  }
  float mx = lg[0];
#pragma unroll
  for (int j = 1; j < 10; ++j) mx = fmaxf(mx, lg[j]);
  float s = 0.f, ex[10];
#pragma unroll
  for (int j = 0; j < 10; ++j) { ex[j] = expf(lg[j] - mx); s += ex[j]; }
#pragma unroll
  for (int j = 0; j < 10; ++j) out[g * 10 + j] = ex[j] / s;
}

extern "C" void kernel_launch(void* const* d_in, const int* in_sizes, int n_in,
                              void* d_out, int out_size, void* d_ws, size_t ws_size,
                              hipStream_t stream) {
  const float* x    = (const float*)d_in[0];
  const int*   ei   = (const int*)d_in[1];
  const int*   batch= (const int*)d_in[2];
  const float* W1 = (const float*)d_in[3];  const float* b1 = (const float*)d_in[4];
  const float* W2 = (const float*)d_in[5];  const float* b2 = (const float*)d_in[6];
  const float* W3 = (const float*)d_in[7];  const float* b3 = (const float*)d_in[8];
  const float* g1 = (const float*)d_in[9];  const float* be1= (const float*)d_in[10];
  const float* g2 = (const float*)d_in[11]; const float* be2= (const float*)d_in[12];
  const float* g3 = (const float*)d_in[13]; const float* be3= (const float*)d_in[14];
  const float* Wo = (const float*)d_in[15]; const float* bo = (const float*)d_in[16];
  float* out = (float*)d_out;

  char* p = (char*)d_ws;
  auto alloc = [&](size_t bytes) { void* r = (void*)p; p += (bytes + 255) & ~(size_t)255; return r; };
  float* Wm     = (float*)alloc(3 * 8192 * sizeof(float));
  float* ab     = (float*)alloc(3 * 128 * sizeof(float));
  u32*   bounds = (u32*)alloc(65 * sizeof(u32));
  u32*   cnt    = (u32*)alloc((size_t)N_NODES * sizeof(u32));
  u32*   offs   = (u32*)alloc((size_t)N_NODES * sizeof(u32));
  u32*   cursor = (u32*)alloc((size_t)N_NODES * sizeof(u32));
  u32*   bsums  = (u32*)alloc(128 * sizeof(u32));
  float* part   = (float*)alloc((size_t)SEG_NBLK * 128 * sizeof(float));
  float* sums   = (float*)alloc(64 * 64 * sizeof(float));
  u32*   esrc   = (u32*)alloc((size_t)N_EDGES * sizeof(u32));
  u32*   pairs  = (u32*)alloc((size_t)N_EDGES * sizeof(u32));
  float* bufU   = (float*)alloc((size_t)N_NODES * 64 * sizeof(float));
  ushort* vb    = (ushort*)alloc((size_t)N_NODES * 64 * sizeof(ushort));
  ushort* hb    = (ushort*)alloc((size_t)N_NODES * 64 * sizeof(ushort));

  const int* src = ei;
  const int* dst = ei + N_EDGES;

  // weights prep + CSR build (edges identical for all 3 layers)
  prep_w_k<<<16, 256, 0, stream>>>(W1, W2, W3, Wm);
  hipMemsetAsync(cnt, 0, (size_t)N_NODES * sizeof(u32), stream);
  hist_k<<<(N_EDGES + 255) / 256, 256, 0, stream>>>(dst, cnt);
  scan1_k<<<(N_NODES + 1023) / 1024, 1024, 0, stream>>>(cnt, cursor, bsums, N_NODES);
  scan2_k<<<1, 128, 0, stream>>>(bsums, (N_NODES + 1023) / 1024);
  scan3_k<<<(N_NODES + 255) / 256, 256, 0, stream>>>(cursor, cnt, bsums, offs, N_NODES);
  copycur_k<<<2, 256, 0, stream>>>(offs, cursor);
  bscat_k<<<(N_EDGES + 2047) / 2048, 256, 0, stream>>>(src, dst, cursor, pairs);
  fscat_k<<<NBUCK, 256, 0, stream>>>(offs, pairs, esrc);
  bounds_k<<<1, 128, 0, stream>>>(batch, bounds);
  hipMemsetAsync(sums, 0, 64 * 64 * sizeof(float), stream);

  const int GEMM_GRID = 1024;

  // ---- layer 1 ----
  gemm_uv_k<<<GEMM_GRID, 256, 0, stream>>>(x, 0, Wm, nullptr, b1, bufU, vb);
  segmax_k<<<SEG_NBLK, 256, 0, stream>>>(vb, offs, cnt, esrc, bufU, hb, part);
  bn_final_k<<<1, 256, 0, stream>>>(part, g1, be1, ab);

  // ---- layer 2 ----
  gemm_uv_k<<<GEMM_GRID, 256, 0, stream>>>(hb, 1, Wm + 8192, ab, b2, bufU, vb);
  segmax_k<<<SEG_NBLK, 256, 0, stream>>>(vb, offs, cnt, esrc, bufU, hb, part);
  bn_final_k<<<1, 256, 0, stream>>>(part, g2, be2, ab + 128);

  // ---- layer 3 ----
  gemm_uv_k<<<GEMM_GRID, 256, 0, stream>>>(hb, 1, Wm + 16384, ab + 128, b3, bufU, vb);
  segmax_k<<<SEG_NBLK, 256, 0, stream>>>(vb, offs, cnt, esrc, bufU, hb, part);
  bn_final_k<<<1, 256, 0, stream>>>(part, g3, be3, ab + 256);

  // ---- pool (+BN3 affine) + head ----
  pool_part_k<<<dim3(4, N_GRAPHS), 256, 0, stream>>>(hb, bounds, sums);
  head_k<<<1, 64, 0, stream>>>(sums, bounds, ab + 256, Wo, bo, out);
}

// Round 5
// 466.160 us; speedup vs baseline: 2.5819x; 1.5248x over previous
//
#include <hip/hip_runtime.h>
#include <hip/hip_bf16.h>
#include <math.h>

#define N_NODES 100000
#define N_EDGES 1600000
#define N_GRAPHS 64
#define EPS 1e-5f
#define NBUCK 391     // ceil(N_NODES / 256)
#define SEG_NBLK 2560 // segmax blocks (8 node-slots each)

typedef unsigned int u32;

static __device__ __forceinline__ ushort f2bf(float f) {
  u32 x = __float_as_uint(f);
  u32 r = (x + 0x7fffu + ((x >> 16) & 1u)) >> 16;  // RNE; inputs finite
  return (ushort)r;
}
static __device__ __forceinline__ float bflo(u32 w) { return __uint_as_float(w << 16); }
static __device__ __forceinline__ float bfhi(u32 w) { return __uint_as_float(w & 0xffff0000u); }

// ---------- weight prep: A' = A - B | B (per layer), f32 ----------
__global__ void prep_w_k(const float* __restrict__ W1, const float* __restrict__ W2,
                         const float* __restrict__ W3, float* __restrict__ Wm) {
  int i = blockIdx.x * 256 + threadIdx.x;
  if (i >= 4096) return;
  const float* Ws[3] = {W1, W2, W3};
  for (int l = 0; l < 3; ++l) {
    float a = Ws[l][i];
    float b = Ws[l][4096 + i];
    Wm[l * 8192 + i] = a - b;          // A - B  (multiplies x_i)
    Wm[l * 8192 + 4096 + i] = b;       // B      (multiplies x_j)
  }
}

// ---------- CSR build ----------
__global__ void hist_k(const int* __restrict__ dst, u32* __restrict__ cnt) {
  int e = blockIdx.x * 256 + threadIdx.x;
  if (e < N_EDGES) atomicAdd(&cnt[dst[e]], 1u);
}

__global__ void scan1_k(const u32* __restrict__ cnt, u32* __restrict__ incl,
                        u32* __restrict__ bsums, int n) {
  __shared__ u32 tmp[1024];
  int gid = blockIdx.x * 1024 + threadIdx.x;
  u32 v = (gid < n) ? cnt[gid] : 0u;
  tmp[threadIdx.x] = v;
  __syncthreads();
  for (int d = 1; d < 1024; d <<= 1) {
    u32 t = (threadIdx.x >= (u32)d) ? tmp[threadIdx.x - d] : 0u;
    __syncthreads();
    tmp[threadIdx.x] += t;
    __syncthreads();
  }
  if (gid < n) incl[gid] = tmp[threadIdx.x];
  if (threadIdx.x == 1023) bsums[blockIdx.x] = tmp[1023];
}

__global__ void scan2_k(u32* bsums, int nb) {
  __shared__ u32 t[128];
  u32 v = ((int)threadIdx.x < nb) ? bsums[threadIdx.x] : 0u;
  t[threadIdx.x] = v;
  __syncthreads();
  for (int d = 1; d < 128; d <<= 1) {
    u32 a = (threadIdx.x >= (u32)d) ? t[threadIdx.x - d] : 0u;
    __syncthreads();
    t[threadIdx.x] += a;
    __syncthreads();
  }
  if ((int)threadIdx.x < nb) bsums[threadIdx.x] = t[threadIdx.x] - v;  // exclusive
}

__global__ void scan3_k(const u32* __restrict__ incl, const u32* __restrict__ cnt,
                        const u32* __restrict__ bsums, u32* __restrict__ offs, int n) {
  int gid = blockIdx.x * 256 + threadIdx.x;
  if (gid < n) offs[gid] = incl[gid] - cnt[gid] + bsums[gid >> 10];
}

// ---------- bucketed edge scatter (bucket = dst>>8) ----------
__global__ void copycur_k(const u32* __restrict__ offs, u32* __restrict__ gcur) {
  int t = blockIdx.x * 256 + threadIdx.x;
  if (t < NBUCK) gcur[t] = offs[t * 256];
}

__global__ __launch_bounds__(256) void bscat_k(const int* __restrict__ src,
                                               const int* __restrict__ dst,
                                               u32* __restrict__ gcur,
                                               u32* __restrict__ pairs) {
  __shared__ u32 cnt[NBUCK];
  __shared__ u32 base[NBUCK];
  for (int i = threadIdx.x; i < NBUCK; i += 256) cnt[i] = 0;
  __syncthreads();
  u32 pk[8], bk[8];
  int be = blockIdx.x * 2048;
#pragma unroll
  for (int k = 0; k < 8; ++k) {
    int e = be + k * 256 + threadIdx.x;
    if (e < N_EDGES) {
      u32 d = (u32)dst[e], s = (u32)src[e];
      u32 b = d >> 8;
      pk[k] = ((d & 255u) << 24) | s;
      bk[k] = b;
      atomicAdd(&cnt[b], 1u);
    } else bk[k] = 0xFFFFFFFFu;
  }
  __syncthreads();
  for (int i = threadIdx.x; i < NBUCK; i += 256) {
    u32 c = cnt[i];
    base[i] = c ? atomicAdd(&gcur[i], c) : 0u;
    cnt[i] = 0;
  }
  __syncthreads();
#pragma unroll
  for (int k = 0; k < 8; ++k) {
    if (bk[k] != 0xFFFFFFFFu) {
      u32 p = base[bk[k]] + atomicAdd(&cnt[bk[k]], 1u);
      pairs[p] = pk[k];
    }
  }
}

__global__ __launch_bounds__(256) void fscat_k(const u32* __restrict__ offs,
                                               const u32* __restrict__ pairs,
                                               u32* __restrict__ esrc) {
  __shared__ u32 loffs[256];
  __shared__ u32 lcnt[256];
  int b = blockIdx.x;
  int nb0 = b << 8;
  int t = threadIdx.x;
  loffs[t] = (nb0 + t < N_NODES) ? offs[nb0 + t] : 0u;
  lcnt[t] = 0;
  __syncthreads();
  u32 start = loffs[0];
  u32 end = (b == NBUCK - 1) ? (u32)N_EDGES : offs[nb0 + 256];
  for (u32 p = start + t; p < end; p += 256) {
    u32 pk = pairs[p];
    u32 dl = pk >> 24;
    u32 s = pk & 0x00FFFFFFu;
    u32 l = atomicAdd(&lcnt[dl], 1u);
    esrc[loffs[dl] + l] = s;
  }
}

// ---------- LDS-tiled GEMM: [u | v] = act(X) @ [A-B | B] ----------
// X: f32 (layer 1) or bf16 (layers 2,3), [N][64]. act = relu(x*al+be) if ab != null.
// u: f32 [N][64] (+bias folded), v: bf16 [N][64].
// Block: 256 thr; tile 64 rows x 128 cols; thread = 8 rows x 4 cols.
__global__ __launch_bounds__(256) void gemm_uv_k(
    const void* __restrict__ xin, int xbf16,
    const float* __restrict__ Wm, const float* __restrict__ ab,
    const float* __restrict__ bias,
    float* __restrict__ u, ushort* __restrict__ vb) {
  __shared__ float Wl[64 * 128];
  __shared__ float Xl[64 * 64];
  int t = threadIdx.x;
  // stage weights once: Wl[k*128 + c]
  for (int rep = 0; rep < 32; ++rep) {
    int idx = rep * 256 + t;
    int k = idx >> 7, c = idx & 127;
    Wl[idx] = (c < 64) ? Wm[k * 64 + c] : Wm[4096 + k * 64 + (c - 64)];
  }
  int tcol = t & 31, trow = t >> 5;
  int c0 = tcol * 4;
  bool is_u = (c0 < 64);
  float binit[4];
#pragma unroll
  for (int j = 0; j < 4; ++j) binit[j] = is_u ? bias[c0 + j] : 0.f;
  // staging role: row srow, 16 cols at scol
  int srow = t >> 2, scol = (t & 3) * 16;
  float sal[16], sbe[16];
  if (ab) {
#pragma unroll
    for (int j = 0; j < 16; ++j) { sal[j] = ab[scol + j]; sbe[j] = ab[64 + scol + j]; }
  }
  for (int tile = blockIdx.x; tile * 64 < N_NODES; tile += gridDim.x) {
    int rb = tile * 64;
    __syncthreads();  // Xl reuse guard
    float xv[16];
    int gr = rb + srow;
    if (gr < N_NODES) {
      if (xbf16) {
        const uint4* xp = (const uint4*)((const ushort*)xin + (size_t)gr * 64 + scol);
        uint4 p0 = xp[0], p1 = xp[1];
        xv[0] = bflo(p0.x); xv[1] = bfhi(p0.x); xv[2] = bflo(p0.y); xv[3] = bfhi(p0.y);
        xv[4] = bflo(p0.z); xv[5] = bfhi(p0.z); xv[6] = bflo(p0.w); xv[7] = bfhi(p0.w);
        xv[8] = bflo(p1.x); xv[9] = bfhi(p1.x); xv[10] = bflo(p1.y); xv[11] = bfhi(p1.y);
        xv[12] = bflo(p1.z); xv[13] = bfhi(p1.z); xv[14] = bflo(p1.w); xv[15] = bfhi(p1.w);
      } else {
        const float4* xp = (const float4*)((const float*)xin + (size_t)gr * 64 + scol);
        float4 a0 = xp[0], a1 = xp[1], a2 = xp[2], a3 = xp[3];
        xv[0] = a0.x; xv[1] = a0.y; xv[2] = a0.z; xv[3] = a0.w;
        xv[4] = a1.x; xv[5] = a1.y; xv[6] = a1.z; xv[7] = a1.w;
        xv[8] = a2.x; xv[9] = a2.y; xv[10] = a2.z; xv[11] = a2.w;
        xv[12] = a3.x; xv[13] = a3.y; xv[14] = a3.z; xv[15] = a3.w;
      }
    } else {
#pragma unroll
      for (int j = 0; j < 16; ++j) xv[j] = 0.f;
    }
    if (ab) {
#pragma unroll
      for (int j = 0; j < 16; ++j) xv[j] = fmaxf(fmaf(xv[j], sal[j], sbe[j]), 0.f);
    }
#pragma unroll
    for (int j = 0; j < 16; ++j) Xl[srow * 64 + scol + j] = xv[j];
    __syncthreads();
    float acc[8][4];
#pragma unroll
    for (int i = 0; i < 8; ++i)
#pragma unroll
      for (int j = 0; j < 4; ++j) acc[i][j] = binit[j];
#pragma unroll 4
    for (int k = 0; k < 64; ++k) {
      float4 bv = *(const float4*)&Wl[k * 128 + c0];
#pragma unroll
      for (int i = 0; i < 8; ++i) {
        float a = Xl[(trow * 8 + i) * 64 + k];
        acc[i][0] = fmaf(a, bv.x, acc[i][0]);
        acc[i][1] = fmaf(a, bv.y, acc[i][1]);
        acc[i][2] = fmaf(a, bv.z, acc[i][2]);
        acc[i][3] = fmaf(a, bv.w, acc[i][3]);
      }
    }
    if (is_u) {
#pragma unroll
      for (int i = 0; i < 8; ++i) {
        int r = rb + trow * 8 + i;
        if (r < N_NODES) {
          float4 s = make_float4(acc[i][0], acc[i][1], acc[i][2], acc[i][3]);
          *(float4*)&u[(size_t)r * 64 + c0] = s;
        }
      }
    } else {
#pragma unroll
      for (int i = 0; i < 8; ++i) {
        int r = rb + trow * 8 + i;
        if (r < N_NODES) {
          u32 w0 = (u32)f2bf(acc[i][0]) | ((u32)f2bf(acc[i][1]) << 16);
          u32 w1 = (u32)f2bf(acc[i][2]) | ((u32)f2bf(acc[i][3]) << 16);
          uint2 s = make_uint2(w0, w1);
          *(uint2*)&vb[(size_t)r * 64 + (c0 - 64)] = s;
        }
      }
    }
  }
}

// ---------- segmax (bf16 v) + h = relu(u + max) -> bf16 h, + BN partials ----------
// wave: 2 nodes (32 lanes each), lane handles channel pair (2cp, 2cp+1) via one u32.
__global__ __launch_bounds__(256) void segmax_k(
    const ushort* __restrict__ v, const u32* __restrict__ offs,
    const u32* __restrict__ cnt, const u32* __restrict__ edge_src,
    const float* __restrict__ u, ushort* __restrict__ h,
    float* __restrict__ part) {
  int t = threadIdx.x;
  int lane = t & 63;
  int sub = lane >> 5;
  int cp = lane & 31;
  int wv = t >> 6;
  int slot = blockIdx.x * 8 + wv * 2 + sub;
  const int nslots = SEG_NBLK * 8;
  const u32* vw = (const u32*)v;
  float s1lo = 0.f, s1hi = 0.f, s2lo = 0.f, s2hi = 0.f;
  for (int node = slot; node < N_NODES; node += nslots) {
    u32 off = offs[node], deg = cnt[node];
    const u32* ep = edge_src + off;
    float l0 = -INFINITY, l1 = -INFINITY, l2 = -INFINITY, l3 = -INFINITY;
    float h0 = -INFINITY, h1 = -INFINITY, h2 = -INFINITY, h3 = -INFINITY;
    u32 i = 0;
    for (; i + 8 <= deg; i += 8) {
      u32 s0 = ep[i], s1_ = ep[i+1], s2_ = ep[i+2], s3_ = ep[i+3];
      u32 s4 = ep[i+4], s5 = ep[i+5], s6 = ep[i+6], s7 = ep[i+7];
      u32 w0 = vw[(size_t)s0 * 32 + cp];
      u32 w1 = vw[(size_t)s1_ * 32 + cp];
      u32 w2 = vw[(size_t)s2_ * 32 + cp];
      u32 w3 = vw[(size_t)s3_ * 32 + cp];
      u32 w4 = vw[(size_t)s4 * 32 + cp];
      u32 w5 = vw[(size_t)s5 * 32 + cp];
      u32 w6 = vw[(size_t)s6 * 32 + cp];
      u32 w7 = vw[(size_t)s7 * 32 + cp];
      l0 = fmaxf(l0, bflo(w0)); h0 = fmaxf(h0, bfhi(w0));
      l1 = fmaxf(l1, bflo(w1)); h1 = fmaxf(h1, bfhi(w1));
      l2 = fmaxf(l2, bflo(w2)); h2 = fmaxf(h2, bfhi(w2));
      l3 = fmaxf(l3, bflo(w3)); h3 = fmaxf(h3, bfhi(w3));
      l0 = fmaxf(l0, bflo(w4)); h0 = fmaxf(h0, bfhi(w4));
      l1 = fmaxf(l1, bflo(w5)); h1 = fmaxf(h1, bfhi(w5));
      l2 = fmaxf(l2, bflo(w6)); h2 = fmaxf(h2, bfhi(w6));
      l3 = fmaxf(l3, bflo(w7)); h3 = fmaxf(h3, bfhi(w7));
    }
    for (; i < deg; ++i) {
      u32 w = vw[(size_t)ep[i] * 32 + cp];
      l0 = fmaxf(l0, bflo(w)); h0 = fmaxf(h0, bfhi(w));
    }
    float mlo = fmaxf(fmaxf(l0, l1), fmaxf(l2, l3));
    float mhi = fmaxf(fmaxf(h0, h1), fmaxf(h2, h3));
    float2 uv = *(const float2*)&u[(size_t)node * 64 + 2 * cp];
    float hlo = fmaxf(uv.x + mlo, 0.f);  // relu(-inf)=0 covers deg==0
    float hhi = fmaxf(uv.y + mhi, 0.f);
    ((u32*)h)[(size_t)node * 32 + cp] = (u32)f2bf(hlo) | ((u32)f2bf(hhi) << 16);
    s1lo += hlo; s2lo += hlo * hlo;
    s1hi += hhi; s2hi += hhi * hhi;
  }
  __shared__ float4 red[256];
  red[t] = make_float4(s1lo, s1hi, s2lo, s2hi);
  __syncthreads();
  if (t < 32) {
    float4 a = red[t];
#pragma unroll
    for (int j = 1; j < 8; ++j) {
      float4 b = red[t + 32 * j];
      a.x += b.x; a.y += b.y; a.z += b.z; a.w += b.w;
    }
    part[blockIdx.x * 128 + 2 * t]      = a.x;
    part[blockIdx.x * 128 + 2 * t + 1]  = a.y;
    part[blockIdx.x * 128 + 64 + 2 * t]     = a.z;
    part[blockIdx.x * 128 + 64 + 2 * t + 1] = a.w;
  }
}

// ---------- BN finalize: one block per channel ----------
__global__ void bn_final_k(const float* __restrict__ part, const float* __restrict__ g,
                           const float* __restrict__ be, float* __restrict__ ab) {
  int c = blockIdx.x;        // 64 channels
  int t = threadIdx.x;       // 256
  float s1 = 0.f, s2 = 0.f;
  for (int b = t; b < SEG_NBLK; b += 256) {
    s1 += part[b * 128 + c];
    s2 += part[b * 128 + 64 + c];
  }
  __shared__ float r1[256], r2[256];
  r1[t] = s1; r2[t] = s2;
  __syncthreads();
  for (int d = 128; d > 0; d >>= 1) {
    if (t < d) { r1[t] += r1[t + d]; r2[t] += r2[t + d]; }
    __syncthreads();
  }
  if (t == 0) {
    float mu = r1[0] / (float)N_NODES;
    float var = r2[0] / (float)N_NODES - mu * mu;
    float al = g[c] / sqrtf(var + EPS);
    ab[c] = al;
    ab[64 + c] = be[c] - mu * al;
  }
}

// ---------- graph boundaries (batch is sorted) ----------
__global__ void bounds_k(const int* __restrict__ batch, u32* __restrict__ bounds) {
  int t = threadIdx.x;
  if (t > 64) return;
  int lo = 0, hi = N_NODES;
  while (lo < hi) {
    int mid = (lo + hi) >> 1;
    if (batch[mid] < t) lo = mid + 1; else hi = mid;
  }
  bounds[t] = (u32)lo;
}

// ---------- parallel mean pool over bf16 h3 ----------
__global__ void pool_part_k(const ushort* __restrict__ h3, const u32* __restrict__ bounds,
                            float* __restrict__ sums) {
  int g = blockIdx.y;
  u32 s = bounds[g], e = bounds[g + 1];
  int t = threadIdx.x;
  int lane = t & 63, wv = t >> 6, sub = lane >> 5, cp = lane & 31;
  int slot = blockIdx.x * 8 + wv * 2 + sub;
  int nsl = gridDim.x * 8;
  const u32* hw = (const u32*)h3;
  float alo = 0.f, ahi = 0.f;
  for (u32 n = s + slot; n < e; n += nsl) {
    u32 w = hw[(size_t)n * 32 + cp];
    alo += bflo(w);
    ahi += bfhi(w);
  }
  __shared__ float2 red[256];
  red[t] = make_float2(alo, ahi);
  __syncthreads();
  if (t < 32) {
    float2 a = red[t];
#pragma unroll
    for (int j = 1; j < 8; ++j) {
      float2 b = red[t + 32 * j];
      a.x += b.x; a.y += b.y;
    }
    atomicAdd(&sums[g * 64 + 2 * t], a.x);
    atomicAdd(&sums[g * 64 + 2 * t + 1], a.y);
  }
}

// ---------- finalize pool (mean + BN3 affine) + linear head + softmax ----------
__global__ void head_k(const float* __restrict__ sums, const u32* __restrict__ bounds,
                       const float* __restrict__ ab3, const float* __restrict__ Wo,
                       const float* __restrict__ bo, float* __restrict__ out) {
  int g = threadIdx.x;
  if (g >= N_GRAPHS) return;
  u32 cntn = bounds[g + 1] - bounds[g];
  float inv = (cntn > 0) ? 1.f / (float)cntn : 0.f;
  float lg[10];
#pragma unroll
  for (int j = 0; j < 10; ++j) lg[j] = bo[j];
  for (int c = 0; c < 64; ++c) {
    float p = (cntn > 0) ? (sums[g * 64 + c] * inv * ab3[c] + ab3[64 + c]) : 0.f;
#pragma unroll
    for (int j = 0; j < 10; ++j) lg[j] = fmaf(p, Wo[c * 10 + j], lg[j]);
  }
  float mx = lg[0];
#pragma unroll
  for (int j = 1; j < 10; ++j) mx = fmaxf(mx, lg[j]);
  float s = 0.f, ex[10];
#pragma unroll
  for (int j = 0; j < 10; ++j) { ex[j] = expf(lg[j] - mx); s += ex[j]; }
#pragma unroll
  for (int j = 0; j < 10; ++j) out[g * 10 + j] = ex[j] / s;
}

extern "C" void kernel_launch(void* const* d_in, const int* in_sizes, int n_in,
                              void* d_out, int out_size, void* d_ws, size_t ws_size,
                              hipStream_t stream) {
  const float* x    = (const float*)d_in[0];
  const int*   ei   = (const int*)d_in[1];
  const int*   batch= (const int*)d_in[2];
  const float* W1 = (const float*)d_in[3];  const float* b1 = (const float*)d_in[4];
  const float* W2 = (const float*)d_in[5];  const float* b2 = (const float*)d_in[6];
  const float* W3 = (const float*)d_in[7];  const float* b3 = (const float*)d_in[8];
  const float* g1 = (const float*)d_in[9];  const float* be1= (const float*)d_in[10];
  const float* g2 = (const float*)d_in[11]; const float* be2= (const float*)d_in[12];
  const float* g3 = (const float*)d_in[13]; const float* be3= (const float*)d_in[14];
  const float* Wo = (const float*)d_in[15]; const float* bo = (const float*)d_in[16];
  float* out = (float*)d_out;

  char* p = (char*)d_ws;
  auto alloc = [&](size_t bytes) { void* r = (void*)p; p += (bytes + 255) & ~(size_t)255; return r; };
  float* Wm     = (float*)alloc(3 * 8192 * sizeof(float));
  float* ab     = (float*)alloc(3 * 128 * sizeof(float));
  u32*   bounds = (u32*)alloc(65 * sizeof(u32));
  u32*   cnt    = (u32*)alloc((size_t)N_NODES * sizeof(u32));
  u32*   offs   = (u32*)alloc((size_t)N_NODES * sizeof(u32));
  u32*   cursor = (u32*)alloc((size_t)N_NODES * sizeof(u32));
  u32*   bsums  = (u32*)alloc(128 * sizeof(u32));
  float* part   = (float*)alloc((size_t)SEG_NBLK * 128 * sizeof(float));
  float* sums   = (float*)alloc(64 * 64 * sizeof(float));
  u32*   esrc   = (u32*)alloc((size_t)N_EDGES * sizeof(u32));
  u32*   pairs  = (u32*)alloc((size_t)N_EDGES * sizeof(u32));
  float* bufU   = (float*)alloc((size_t)N_NODES * 64 * sizeof(float));
  ushort* vb    = (ushort*)alloc((size_t)N_NODES * 64 * sizeof(ushort));
  ushort* hb    = (ushort*)alloc((size_t)N_NODES * 64 * sizeof(ushort));

  const int* src = ei;
  const int* dst = ei + N_EDGES;

  // weights prep + CSR build (edges identical for all 3 layers)
  prep_w_k<<<16, 256, 0, stream>>>(W1, W2, W3, Wm);
  hipMemsetAsync(cnt, 0, (size_t)N_NODES * sizeof(u32), stream);
  hist_k<<<(N_EDGES + 255) / 256, 256, 0, stream>>>(dst, cnt);
  scan1_k<<<(N_NODES + 1023) / 1024, 1024, 0, stream>>>(cnt, cursor, bsums, N_NODES);
  scan2_k<<<1, 128, 0, stream>>>(bsums, (N_NODES + 1023) / 1024);
  scan3_k<<<(N_NODES + 255) / 256, 256, 0, stream>>>(cursor, cnt, bsums, offs, N_NODES);
  copycur_k<<<2, 256, 0, stream>>>(offs, cursor);
  bscat_k<<<(N_EDGES + 2047) / 2048, 256, 0, stream>>>(src, dst, cursor, pairs);
  fscat_k<<<NBUCK, 256, 0, stream>>>(offs, pairs, esrc);
  bounds_k<<<1, 128, 0, stream>>>(batch, bounds);
  hipMemsetAsync(sums, 0, 64 * 64 * sizeof(float), stream);

  const int GEMM_GRID = 1024;

  // ---- layer 1 ----
  gemm_uv_k<<<GEMM_GRID, 256, 0, stream>>>(x, 0, Wm, nullptr, b1, bufU, vb);
  segmax_k<<<SEG_NBLK, 256, 0, stream>>>(vb, offs, cnt, esrc, bufU, hb, part);
  bn_final_k<<<64, 256, 0, stream>>>(part, g1, be1, ab);

  // ---- layer 2 ----
  gemm_uv_k<<<GEMM_GRID, 256, 0, stream>>>(hb, 1, Wm + 8192, ab, b2, bufU, vb);
  segmax_k<<<SEG_NBLK, 256, 0, stream>>>(vb, offs, cnt, esrc, bufU, hb, part);
  bn_final_k<<<64, 256, 0, stream>>>(part, g2, be2, ab + 128);

  // ---- layer 3 ----
  gemm_uv_k<<<GEMM_GRID, 256, 0, stream>>>(hb, 1, Wm + 16384, ab + 128, b3, bufU, vb);
  segmax_k<<<SEG_NBLK, 256, 0, stream>>>(vb, offs, cnt, esrc, bufU, hb, part);
  bn_final_k<<<64, 256, 0, stream>>>(part, g3, be3, ab + 256);

  // ---- pool (+BN3 affine) + head ----
  pool_part_k<<<dim3(8, N_GRAPHS), 256, 0, stream>>>(hb, bounds, sums);
  head_k<<<1, 64, 0, stream>>>(sums, bounds, ab + 256, Wo, bo, out);
}

// Round 6
// 367.804 us; speedup vs baseline: 3.2724x; 1.2674x over previous
//
#include <hip/hip_runtime.h>
#include <hip/hip_bf16.h>
#include <math.h>

#define N_NODES 100000
#define N_EDGES 1600000
#define N_GRAPHS 64
#define EPS 1e-5f
#define NBUCK 391     // ceil(N_NODES / 256)
#define SEG_NBLK 2048 // segmax blocks (16 node-slots each)

typedef unsigned int u32;

static __device__ __forceinline__ ushort f2bf(float f) {
  u32 x = __float_as_uint(f);
  u32 r = (x + 0x7fffu + ((x >> 16) & 1u)) >> 16;  // RNE; inputs finite
  return (ushort)r;
}
static __device__ __forceinline__ float bflo(u32 w) { return __uint_as_float(w << 16); }
static __device__ __forceinline__ float bfhi(u32 w) { return __uint_as_float(w & 0xffff0000u); }

// ---------- weight prep: A' = A - B | B (per layer), f32 ----------
__global__ void prep_w_k(const float* __restrict__ W1, const float* __restrict__ W2,
                         const float* __restrict__ W3, float* __restrict__ Wm) {
  int i = blockIdx.x * 256 + threadIdx.x;
  if (i >= 4096) return;
  const float* Ws[3] = {W1, W2, W3};
  for (int l = 0; l < 3; ++l) {
    float a = Ws[l][i];
    float b = Ws[l][4096 + i];
    Wm[l * 8192 + i] = a - b;          // A - B  (multiplies x_i)
    Wm[l * 8192 + 4096 + i] = b;       // B      (multiplies x_j)
  }
}

// ---------- bucket-level histogram (bucket = dst>>8): LDS-aggregated ----------
__global__ __launch_bounds__(256) void bhist_k(const int* __restrict__ dst,
                                               u32* __restrict__ bcnt) {
  __shared__ u32 c[NBUCK];
  for (int i = threadIdx.x; i < NBUCK; i += 256) c[i] = 0;
  __syncthreads();
  int base = blockIdx.x * 2048;
#pragma unroll
  for (int k = 0; k < 8; ++k) {
    int e = base + k * 256 + threadIdx.x;
    if (e < N_EDGES) atomicAdd(&c[(u32)dst[e] >> 8], 1u);
  }
  __syncthreads();
  for (int i = threadIdx.x; i < NBUCK; i += 256) {
    u32 cc = c[i];
    if (cc) atomicAdd(&bcnt[i], cc);
  }
}

// ---------- bucket scan -> boffs (exclusive, +total), bcur ----------
__global__ void bscan_k(const u32* __restrict__ bcnt, u32* __restrict__ boffs,
                        u32* __restrict__ bcur) {
  __shared__ u32 s[512];
  int t = threadIdx.x;
  u32 v = (t < NBUCK) ? bcnt[t] : 0u;
  s[t] = v;
  __syncthreads();
  for (int d = 1; d < 512; d <<= 1) {
    u32 a = (t >= d) ? s[t - d] : 0u;
    __syncthreads();
    s[t] += a;
    __syncthreads();
  }
  if (t < NBUCK) { boffs[t] = s[t] - v; bcur[t] = s[t] - v; }
  if (t == NBUCK - 1) boffs[NBUCK] = s[t];
}

// ---------- pass C: edges -> bucket-grouped packed pairs ((dst&255)<<24 | src) ----------
__global__ __launch_bounds__(256) void bscat_k(const int* __restrict__ src,
                                               const int* __restrict__ dst,
                                               u32* __restrict__ gcur,
                                               u32* __restrict__ pairs) {
  __shared__ u32 cnt[NBUCK];
  __shared__ u32 base[NBUCK];
  for (int i = threadIdx.x; i < NBUCK; i += 256) cnt[i] = 0;
  __syncthreads();
  u32 pk[8], bk[8];
  int be = blockIdx.x * 2048;
#pragma unroll
  for (int k = 0; k < 8; ++k) {
    int e = be + k * 256 + threadIdx.x;
    if (e < N_EDGES) {
      u32 d = (u32)dst[e], s = (u32)src[e];
      u32 b = d >> 8;
      pk[k] = ((d & 255u) << 24) | s;
      bk[k] = b;
      atomicAdd(&cnt[b], 1u);
    } else bk[k] = 0xFFFFFFFFu;
  }
  __syncthreads();
  for (int i = threadIdx.x; i < NBUCK; i += 256) {
    u32 c = cnt[i];
    base[i] = c ? atomicAdd(&gcur[i], c) : 0u;
    cnt[i] = 0;
  }
  __syncthreads();
#pragma unroll
  for (int k = 0; k < 8; ++k) {
    if (bk[k] != 0xFFFFFFFFu) {
      u32 p = base[bk[k]] + atomicAdd(&cnt[bk[k]], 1u);
      pairs[p] = pk[k];
    }
  }
}

// ---------- pass D: per-bucket node CSR (LDS hist+scan, coalesced offs/cnt) + place ----------
__global__ __launch_bounds__(256) void fscat2_k(const u32* __restrict__ boffs,
                                                const u32* __restrict__ pairs,
                                                u32* __restrict__ esrc,
                                                u32* __restrict__ offs_g,
                                                u32* __restrict__ cnt_g) {
  __shared__ u32 lcnt[256], lexc[256], lcur[256];
  int b = blockIdx.x, t = threadIdx.x;
  u32 s0 = boffs[b], e0 = boffs[b + 1];
  lcnt[t] = 0;
  __syncthreads();
  for (u32 p = s0 + t; p < e0; p += 256) atomicAdd(&lcnt[pairs[p] >> 24], 1u);
  __syncthreads();
  u32 v = lcnt[t];
  lexc[t] = v;
  __syncthreads();
  for (int d = 1; d < 256; d <<= 1) {
    u32 a = (t >= d) ? lexc[t - d] : 0u;
    __syncthreads();
    lexc[t] += a;
    __syncthreads();
  }
  u32 excl = lexc[t] - v;
  int node = (b << 8) + t;
  if (node < N_NODES) { offs_g[node] = s0 + excl; cnt_g[node] = v; }
  lcur[t] = 0;
  lexc[t] = excl;
  __syncthreads();
  for (u32 p = s0 + t; p < e0; p += 256) {
    u32 pk = pairs[p];
    u32 dl = pk >> 24;
    u32 l = atomicAdd(&lcur[dl], 1u);
    esrc[s0 + lexc[dl] + l] = pk & 0x00FFFFFFu;
  }
}

// ---------- LDS-tiled GEMM: [u | v] = act(X) @ [A-B | B] ----------
// X: f32 (layer 1) or bf16 (layers 2,3), [N][64]. act = relu(x*al+be) if ab != null.
// u: f32 [N][64] (+bias folded), v: bf16 [N][64].
// Block: 256 thr; tile 64 rows x 128 cols; thread = 8 rows x 4 cols.
__global__ __launch_bounds__(256) void gemm_uv_k(
    const void* __restrict__ xin, int xbf16,
    const float* __restrict__ Wm, const float* __restrict__ ab,
    const float* __restrict__ bias,
    float* __restrict__ u, ushort* __restrict__ vb) {
  __shared__ float Wl[64 * 128];
  __shared__ float Xl[64 * 64];
  int t = threadIdx.x;
  for (int rep = 0; rep < 32; ++rep) {
    int idx = rep * 256 + t;
    int k = idx >> 7, c = idx & 127;
    Wl[idx] = (c < 64) ? Wm[k * 64 + c] : Wm[4096 + k * 64 + (c - 64)];
  }
  int tcol = t & 31, trow = t >> 5;
  int c0 = tcol * 4;
  bool is_u = (c0 < 64);
  float binit[4];
#pragma unroll
  for (int j = 0; j < 4; ++j) binit[j] = is_u ? bias[c0 + j] : 0.f;
  int srow = t >> 2, scol = (t & 3) * 16;
  float sal[16], sbe[16];
  if (ab) {
#pragma unroll
    for (int j = 0; j < 16; ++j) { sal[j] = ab[scol + j]; sbe[j] = ab[64 + scol + j]; }
  }
  for (int tile = blockIdx.x; tile * 64 < N_NODES; tile += gridDim.x) {
    int rb = tile * 64;
    __syncthreads();  // Xl reuse guard
    float xv[16];
    int gr = rb + srow;
    if (gr < N_NODES) {
      if (xbf16) {
        const uint4* xp = (const uint4*)((const ushort*)xin + (size_t)gr * 64 + scol);
        uint4 p0 = xp[0], p1 = xp[1];
        xv[0] = bflo(p0.x); xv[1] = bfhi(p0.x); xv[2] = bflo(p0.y); xv[3] = bfhi(p0.y);
        xv[4] = bflo(p0.z); xv[5] = bfhi(p0.z); xv[6] = bflo(p0.w); xv[7] = bfhi(p0.w);
        xv[8] = bflo(p1.x); xv[9] = bfhi(p1.x); xv[10] = bflo(p1.y); xv[11] = bfhi(p1.y);
        xv[12] = bflo(p1.z); xv[13] = bfhi(p1.z); xv[14] = bflo(p1.w); xv[15] = bfhi(p1.w);
      } else {
        const float4* xp = (const float4*)((const float*)xin + (size_t)gr * 64 + scol);
        float4 a0 = xp[0], a1 = xp[1], a2 = xp[2], a3 = xp[3];
        xv[0] = a0.x; xv[1] = a0.y; xv[2] = a0.z; xv[3] = a0.w;
        xv[4] = a1.x; xv[5] = a1.y; xv[6] = a1.z; xv[7] = a1.w;
        xv[8] = a2.x; xv[9] = a2.y; xv[10] = a2.z; xv[11] = a2.w;
        xv[12] = a3.x; xv[13] = a3.y; xv[14] = a3.z; xv[15] = a3.w;
      }
    } else {
#pragma unroll
      for (int j = 0; j < 16; ++j) xv[j] = 0.f;
    }
    if (ab) {
#pragma unroll
      for (int j = 0; j < 16; ++j) xv[j] = fmaxf(fmaf(xv[j], sal[j], sbe[j]), 0.f);
    }
#pragma unroll
    for (int j = 0; j < 16; ++j) Xl[srow * 64 + scol + j] = xv[j];
    __syncthreads();
    float acc[8][4];
#pragma unroll
    for (int i = 0; i < 8; ++i)
#pragma unroll
      for (int j = 0; j < 4; ++j) acc[i][j] = binit[j];
#pragma unroll 4
    for (int k = 0; k < 64; ++k) {
      float4 bv = *(const float4*)&Wl[k * 128 + c0];
#pragma unroll
      for (int i = 0; i < 8; ++i) {
        float a = Xl[(trow * 8 + i) * 64 + k];
        acc[i][0] = fmaf(a, bv.x, acc[i][0]);
        acc[i][1] = fmaf(a, bv.y, acc[i][1]);
        acc[i][2] = fmaf(a, bv.z, acc[i][2]);
        acc[i][3] = fmaf(a, bv.w, acc[i][3]);
      }
    }
    if (is_u) {
#pragma unroll
      for (int i = 0; i < 8; ++i) {
        int r = rb + trow * 8 + i;
        if (r < N_NODES) {
          float4 s = make_float4(acc[i][0], acc[i][1], acc[i][2], acc[i][3]);
          *(float4*)&u[(size_t)r * 64 + c0] = s;
        }
      }
    } else {
#pragma unroll
      for (int i = 0; i < 8; ++i) {
        int r = rb + trow * 8 + i;
        if (r < N_NODES) {
          u32 w0 = (u32)f2bf(acc[i][0]) | ((u32)f2bf(acc[i][1]) << 16);
          u32 w1 = (u32)f2bf(acc[i][2]) | ((u32)f2bf(acc[i][3]) << 16);
          uint2 s = make_uint2(w0, w1);
          *(uint2*)&vb[(size_t)r * 64 + (c0 - 64)] = s;
        }
      }
    }
  }
}

// ---------- segmax (bf16 v) + h = relu(u + max) -> bf16 h, + BN partials ----------
// wave: 4 nodes (16 lanes each), lane handles 4 channels (4qp..4qp+3) via one uint2.
__global__ __launch_bounds__(256) void segmax_k(
    const ushort* __restrict__ v, const u32* __restrict__ offs,
    const u32* __restrict__ cnt, const u32* __restrict__ edge_src,
    const float* __restrict__ u, ushort* __restrict__ h,
    float* __restrict__ part) {
  int t = threadIdx.x;
  int lane = t & 63;
  int sub = lane >> 4;
  int qp = lane & 15;
  int wv = t >> 6;
  int slot = blockIdx.x * 16 + wv * 4 + sub;
  const int nslots = SEG_NBLK * 16;
  const uint2* vw = (const uint2*)v;
  float s1[4] = {0.f, 0.f, 0.f, 0.f}, s2[4] = {0.f, 0.f, 0.f, 0.f};
  for (int node = slot; node < N_NODES; node += nslots) {
    u32 off = offs[node], deg = cnt[node];
    const u32* ep = edge_src + off;
    float m[4][4];
#pragma unroll
    for (int a = 0; a < 4; ++a)
#pragma unroll
      for (int c = 0; c < 4; ++c) m[a][c] = -INFINITY;
    u32 i = 0;
    for (; i + 4 <= deg; i += 4) {
      u32 sA = ep[i], sB = ep[i + 1], sC = ep[i + 2], sD = ep[i + 3];
      uint2 wA = vw[(size_t)sA * 16 + qp];
      uint2 wB = vw[(size_t)sB * 16 + qp];
      uint2 wC = vw[(size_t)sC * 16 + qp];
      uint2 wD = vw[(size_t)sD * 16 + qp];
      m[0][0] = fmaxf(m[0][0], bflo(wA.x)); m[0][1] = fmaxf(m[0][1], bfhi(wA.x));
      m[0][2] = fmaxf(m[0][2], bflo(wA.y)); m[0][3] = fmaxf(m[0][3], bfhi(wA.y));
      m[1][0] = fmaxf(m[1][0], bflo(wB.x)); m[1][1] = fmaxf(m[1][1], bfhi(wB.x));
      m[1][2] = fmaxf(m[1][2], bflo(wB.y)); m[1][3] = fmaxf(m[1][3], bfhi(wB.y));
      m[2][0] = fmaxf(m[2][0], bflo(wC.x)); m[2][1] = fmaxf(m[2][1], bfhi(wC.x));
      m[2][2] = fmaxf(m[2][2], bflo(wC.y)); m[2][3] = fmaxf(m[2][3], bfhi(wC.y));
      m[3][0] = fmaxf(m[3][0], bflo(wD.x)); m[3][1] = fmaxf(m[3][1], bfhi(wD.x));
      m[3][2] = fmaxf(m[3][2], bflo(wD.y)); m[3][3] = fmaxf(m[3][3], bfhi(wD.y));
    }
    for (; i < deg; ++i) {
      uint2 w = vw[(size_t)ep[i] * 16 + qp];
      m[0][0] = fmaxf(m[0][0], bflo(w.x)); m[0][1] = fmaxf(m[0][1], bfhi(w.x));
      m[0][2] = fmaxf(m[0][2], bflo(w.y)); m[0][3] = fmaxf(m[0][3], bfhi(w.y));
    }
    float mm[4];
#pragma unroll
    for (int c = 0; c < 4; ++c)
      mm[c] = fmaxf(fmaxf(m[0][c], m[1][c]), fmaxf(m[2][c], m[3][c]));
    float4 uv = *(const float4*)&u[(size_t)node * 64 + 4 * qp];
    float h0 = fmaxf(uv.x + mm[0], 0.f);  // relu(-inf)=0 covers deg==0
    float h1 = fmaxf(uv.y + mm[1], 0.f);
    float h2 = fmaxf(uv.z + mm[2], 0.f);
    float h3 = fmaxf(uv.w + mm[3], 0.f);
    u32 w0 = (u32)f2bf(h0) | ((u32)f2bf(h1) << 16);
    u32 w1 = (u32)f2bf(h2) | ((u32)f2bf(h3) << 16);
    ((uint2*)h)[(size_t)node * 16 + qp] = make_uint2(w0, w1);
    s1[0] += h0; s2[0] += h0 * h0;
    s1[1] += h1; s2[1] += h1 * h1;
    s1[2] += h2; s2[2] += h2 * h2;
    s1[3] += h3; s2[3] += h3 * h3;
  }
  __shared__ float4 r1[256], r2[256];
  r1[t] = make_float4(s1[0], s1[1], s1[2], s1[3]);
  r2[t] = make_float4(s2[0], s2[1], s2[2], s2[3]);
  __syncthreads();
  if (t < 16) {
    float4 a1 = r1[t], a2 = r2[t];
#pragma unroll
    for (int j = 1; j < 16; ++j) {
      float4 b1 = r1[j * 16 + t], b2 = r2[j * 16 + t];
      a1.x += b1.x; a1.y += b1.y; a1.z += b1.z; a1.w += b1.w;
      a2.x += b2.x; a2.y += b2.y; a2.z += b2.z; a2.w += b2.w;
    }
    part[blockIdx.x * 128 + 4 * t]     = a1.x;
    part[blockIdx.x * 128 + 4 * t + 1] = a1.y;
    part[blockIdx.x * 128 + 4 * t + 2] = a1.z;
    part[blockIdx.x * 128 + 4 * t + 3] = a1.w;
    part[blockIdx.x * 128 + 64 + 4 * t]     = a2.x;
    part[blockIdx.x * 128 + 64 + 4 * t + 1] = a2.y;
    part[blockIdx.x * 128 + 64 + 4 * t + 2] = a2.z;
    part[blockIdx.x * 128 + 64 + 4 * t + 3] = a2.w;
  }
}

// ---------- BN finalize: one block per channel ----------
__global__ void bn_final_k(const float* __restrict__ part, const float* __restrict__ g,
                           const float* __restrict__ be, float* __restrict__ ab) {
  int c = blockIdx.x;        // 64 channels
  int t = threadIdx.x;       // 256
  float s1 = 0.f, s2 = 0.f;
  for (int b = t; b < SEG_NBLK; b += 256) {
    s1 += part[b * 128 + c];
    s2 += part[b * 128 + 64 + c];
  }
  __shared__ float r1[256], r2[256];
  r1[t] = s1; r2[t] = s2;
  __syncthreads();
  for (int d = 128; d > 0; d >>= 1) {
    if (t < d) { r1[t] += r1[t + d]; r2[t] += r2[t + d]; }
    __syncthreads();
  }
  if (t == 0) {
    float mu = r1[0] / (float)N_NODES;
    float var = r2[0] / (float)N_NODES - mu * mu;
    float al = g[c] / sqrtf(var + EPS);
    ab[c] = al;
    ab[64 + c] = be[c] - mu * al;
  }
}

// ---------- graph boundaries (batch is sorted) ----------
__global__ void bounds_k(const int* __restrict__ batch, u32* __restrict__ bounds) {
  int t = threadIdx.x;
  if (t > 64) return;
  int lo = 0, hi = N_NODES;
  while (lo < hi) {
    int mid = (lo + hi) >> 1;
    if (batch[mid] < t) lo = mid + 1; else hi = mid;
  }
  bounds[t] = (u32)lo;
}

// ---------- parallel mean pool over bf16 h3 ----------
__global__ void pool_part_k(const ushort* __restrict__ h3, const u32* __restrict__ bounds,
                            float* __restrict__ sums) {
  int g = blockIdx.y;
  u32 s = bounds[g], e = bounds[g + 1];
  int t = threadIdx.x;
  int lane = t & 63, wv = t >> 6, sub = lane >> 5, cp = lane & 31;
  int slot = blockIdx.x * 8 + wv * 2 + sub;
  int nsl = gridDim.x * 8;
  const u32* hw = (const u32*)h3;
  float alo = 0.f, ahi = 0.f;
  for (u32 n = s + slot; n < e; n += nsl) {
    u32 w = hw[(size_t)n * 32 + cp];
    alo += bflo(w);
    ahi += bfhi(w);
  }
  __shared__ float2 red[256];
  red[t] = make_float2(alo, ahi);
  __syncthreads();
  if (t < 32) {
    float2 a = red[t];
#pragma unroll
    for (int j = 1; j < 8; ++j) {
      float2 b = red[t + 32 * j];
      a.x += b.x; a.y += b.y;
    }
    atomicAdd(&sums[g * 64 + 2 * t], a.x);
    atomicAdd(&sums[g * 64 + 2 * t + 1], a.y);
  }
}

// ---------- finalize pool (mean + BN3 affine) + linear head + softmax ----------
__global__ void head_k(const float* __restrict__ sums, const u32* __restrict__ bounds,
                       const float* __restrict__ ab3, const float* __restrict__ Wo,
                       const float* __restrict__ bo, float* __restrict__ out) {
  int g = threadIdx.x;
  if (g >= N_GRAPHS) return;
  u32 cntn = bounds[g + 1] - bounds[g];
  float inv = (cntn > 0) ? 1.f / (float)cntn : 0.f;
  float lg[10];
#pragma unroll
  for (int j = 0; j < 10; ++j) lg[j] = bo[j];
  for (int c = 0; c < 64; ++c) {
    float p = (cntn > 0) ? (sums[g * 64 + c] * inv * ab3[c] + ab3[64 + c]) : 0.f;
#pragma unroll
    for (int j = 0; j < 10; ++j) lg[j] = fmaf(p, Wo[c * 10 + j], lg[j]);
  }
  float mx = lg[0];
#pragma unroll
  for (int j = 1; j < 10; ++j) mx = fmaxf(mx, lg[j]);
  float s = 0.f, ex[10];
#pragma unroll
  for (int j = 0; j < 10; ++j) { ex[j] = expf(lg[j] - mx); s += ex[j]; }
#pragma unroll
  for (int j = 0; j < 10; ++j) out[g * 10 + j] = ex[j] / s;
}

extern "C" void kernel_launch(void* const* d_in, const int* in_sizes, int n_in,
                              void* d_out, int out_size, void* d_ws, size_t ws_size,
                              hipStream_t stream) {
  const float* x    = (const float*)d_in[0];
  const int*   ei   = (const int*)d_in[1];
  const int*   batch= (const int*)d_in[2];
  const float* W1 = (const float*)d_in[3];  const float* b1 = (const float*)d_in[4];
  const float* W2 = (const float*)d_in[5];  const float* b2 = (const float*)d_in[6];
  const float* W3 = (const float*)d_in[7];  const float* b3 = (const float*)d_in[8];
  const float* g1 = (const float*)d_in[9];  const float* be1= (const float*)d_in[10];
  const float* g2 = (const float*)d_in[11]; const float* be2= (const float*)d_in[12];
  const float* g3 = (const float*)d_in[13]; const float* be3= (const float*)d_in[14];
  const float* Wo = (const float*)d_in[15]; const float* bo = (const float*)d_in[16];
  float* out = (float*)d_out;

  char* p = (char*)d_ws;
  auto alloc = [&](size_t bytes) { void* r = (void*)p; p += (bytes + 255) & ~(size_t)255; return r; };
  float* Wm     = (float*)alloc(3 * 8192 * sizeof(float));
  float* ab     = (float*)alloc(3 * 128 * sizeof(float));
  u32*   bounds = (u32*)alloc(65 * sizeof(u32));
  u32*   bcnt   = (u32*)alloc(NBUCK * sizeof(u32));
  u32*   boffs  = (u32*)alloc((NBUCK + 1) * sizeof(u32));
  u32*   bcur   = (u32*)alloc(NBUCK * sizeof(u32));
  u32*   cnt    = (u32*)alloc((size_t)N_NODES * sizeof(u32));
  u32*   offs   = (u32*)alloc((size_t)N_NODES * sizeof(u32));
  float* part   = (float*)alloc((size_t)SEG_NBLK * 128 * sizeof(float));
  float* sums   = (float*)alloc(64 * 64 * sizeof(float));
  u32*   esrc   = (u32*)alloc((size_t)N_EDGES * sizeof(u32));
  u32*   pairs  = (u32*)alloc((size_t)N_EDGES * sizeof(u32));
  float* bufU   = (float*)alloc((size_t)N_NODES * 64 * sizeof(float));
  ushort* vb    = (ushort*)alloc((size_t)N_NODES * 64 * sizeof(ushort));
  ushort* hb    = (ushort*)alloc((size_t)N_NODES * 64 * sizeof(ushort));

  const int* src = ei;
  const int* dst = ei + N_EDGES;

  // weights prep + CSR build (edges identical for all 3 layers)
  prep_w_k<<<16, 256, 0, stream>>>(W1, W2, W3, Wm);
  hipMemsetAsync(bcnt, 0, NBUCK * sizeof(u32), stream);
  bhist_k<<<(N_EDGES + 2047) / 2048, 256, 0, stream>>>(dst, bcnt);
  bscan_k<<<1, 512, 0, stream>>>(bcnt, boffs, bcur);
  bscat_k<<<(N_EDGES + 2047) / 2048, 256, 0, stream>>>(src, dst, bcur, pairs);
  fscat2_k<<<NBUCK, 256, 0, stream>>>(boffs, pairs, esrc, offs, cnt);
  bounds_k<<<1, 128, 0, stream>>>(batch, bounds);
  hipMemsetAsync(sums, 0, 64 * 64 * sizeof(float), stream);

  const int GEMM_GRID = 521;  // 1563 tiles = exactly 3 per block

  // ---- layer 1 ----
  gemm_uv_k<<<GEMM_GRID, 256, 0, stream>>>(x, 0, Wm, nullptr, b1, bufU, vb);
  segmax_k<<<SEG_NBLK, 256, 0, stream>>>(vb, offs, cnt, esrc, bufU, hb, part);
  bn_final_k<<<64, 256, 0, stream>>>(part, g1, be1, ab);

  // ---- layer 2 ----
  gemm_uv_k<<<GEMM_GRID, 256, 0, stream>>>(hb, 1, Wm + 8192, ab, b2, bufU, vb);
  segmax_k<<<SEG_NBLK, 256, 0, stream>>>(vb, offs, cnt, esrc, bufU, hb, part);
  bn_final_k<<<64, 256, 0, stream>>>(part, g2, be2, ab + 128);

  // ---- layer 3 ----
  gemm_uv_k<<<GEMM_GRID, 256, 0, stream>>>(hb, 1, Wm + 16384, ab + 128, b3, bufU, vb);
  segmax_k<<<SEG_NBLK, 256, 0, stream>>>(vb, offs, cnt, esrc, bufU, hb, part);
  bn_final_k<<<64, 256, 0, stream>>>(part, g3, be3, ab + 256);

  // ---- pool (+BN3 affine) + head ----
  pool_part_k<<<dim3(8, N_GRAPHS), 256, 0, stream>>>(hb, bounds, sums);
  head_k<<<1, 64, 0, stream>>>(sums, bounds, ab + 256, Wo, bo, out);
}

// Round 7
// 282.841 us; speedup vs baseline: 4.2554x; 1.3004x over previous
//
#include <hip/hip_runtime.h>
#include <hip/hip_bf16.h>
#include <math.h>

#define N_NODES 100000
#define N_EDGES 1600000
#define N_GRAPHS 64
#define EPS 1e-5f
#define NBUCK 391     // ceil(N_NODES / 256)
#define SEG_NBLK 2048 // segmax blocks (16 node-slots each)

typedef unsigned int u32;
typedef __attribute__((ext_vector_type(8))) short short8;
typedef __attribute__((ext_vector_type(4))) float f32x4;

static __device__ __forceinline__ ushort f2bf(float f) {
  u32 x = __float_as_uint(f);
  u32 r = (x + 0x7fffu + ((x >> 16) & 1u)) >> 16;  // RNE; inputs finite
  return (ushort)r;
}
static __device__ __forceinline__ float bflo(u32 w) { return __uint_as_float(w << 16); }
static __device__ __forceinline__ float bfhi(u32 w) { return __uint_as_float(w & 0xffff0000u); }

// ---------- weight prep: pack [A-B | B] into bf16 MFMA B-fragment order ----------
// Wb[layer][kh(2)][ct(8)][lane(64)] = uint4 (8 bf16): lane l, elem j ->
//   Wc[kh*32 + (l>>4)*8 + j][ct*16 + (l&15)], Wc = [A-B | B] (64 x 128)
__global__ void prep_wb_k(const float* __restrict__ W1, const float* __restrict__ W2,
                          const float* __restrict__ W3, uint4* __restrict__ Wb) {
  int g = blockIdx.x * 256 + threadIdx.x;
  if (g >= 3072) return;
  int layer = g >> 10, rem = g & 1023;
  int kh = rem >> 9, ct = (rem >> 6) & 7, l = rem & 63;
  const float* W = (layer == 0) ? W1 : (layer == 1) ? W2 : W3;
  int c = ct * 16 + (l & 15);
  u32 w[4];
#pragma unroll
  for (int jj = 0; jj < 4; ++jj) {
    int k0 = kh * 32 + (l >> 4) * 8 + 2 * jj;
    float v0, v1;
    if (c < 64) {
      v0 = W[k0 * 64 + c] - W[(64 + k0) * 64 + c];
      v1 = W[(k0 + 1) * 64 + c] - W[(65 + k0) * 64 + c];
    } else {
      v0 = W[(64 + k0) * 64 + (c - 64)];
      v1 = W[(65 + k0) * 64 + (c - 64)];
    }
    w[jj] = (u32)f2bf(v0) | ((u32)f2bf(v1) << 16);
  }
  Wb[g] = make_uint4(w[0], w[1], w[2], w[3]);
}

// ---------- bucket-level histogram (bucket = dst>>8): LDS-aggregated ----------
__global__ __launch_bounds__(256) void bhist_k(const int* __restrict__ dst,
                                               u32* __restrict__ bcnt) {
  __shared__ u32 c[NBUCK];
  for (int i = threadIdx.x; i < NBUCK; i += 256) c[i] = 0;
  __syncthreads();
  int base = blockIdx.x * 2048;
#pragma unroll
  for (int k = 0; k < 8; ++k) {
    int e = base + k * 256 + threadIdx.x;
    if (e < N_EDGES) atomicAdd(&c[(u32)dst[e] >> 8], 1u);
  }
  __syncthreads();
  for (int i = threadIdx.x; i < NBUCK; i += 256) {
    u32 cc = c[i];
    if (cc) atomicAdd(&bcnt[i], cc);
  }
}

// ---------- bucket scan -> boffs (exclusive, +total), bcur ----------
__global__ void bscan_k(const u32* __restrict__ bcnt, u32* __restrict__ boffs,
                        u32* __restrict__ bcur) {
  __shared__ u32 s[512];
  int t = threadIdx.x;
  u32 v = (t < NBUCK) ? bcnt[t] : 0u;
  s[t] = v;
  __syncthreads();
  for (int d = 1; d < 512; d <<= 1) {
    u32 a = (t >= d) ? s[t - d] : 0u;
    __syncthreads();
    s[t] += a;
    __syncthreads();
  }
  if (t < NBUCK) { boffs[t] = s[t] - v; bcur[t] = s[t] - v; }
  if (t == NBUCK - 1) boffs[NBUCK] = s[t];
}

// ---------- pass C: edges -> bucket-grouped packed pairs ((dst&255)<<24 | src) ----------
__global__ __launch_bounds__(256) void bscat_k(const int* __restrict__ src,
                                               const int* __restrict__ dst,
                                               u32* __restrict__ gcur,
                                               u32* __restrict__ pairs) {
  __shared__ u32 cnt[NBUCK];
  __shared__ u32 base[NBUCK];
  for (int i = threadIdx.x; i < NBUCK; i += 256) cnt[i] = 0;
  __syncthreads();
  u32 pk[8], bk[8];
  int be = blockIdx.x * 2048;
#pragma unroll
  for (int k = 0; k < 8; ++k) {
    int e = be + k * 256 + threadIdx.x;
    if (e < N_EDGES) {
      u32 d = (u32)dst[e], s = (u32)src[e];
      u32 b = d >> 8;
      pk[k] = ((d & 255u) << 24) | s;
      bk[k] = b;
      atomicAdd(&cnt[b], 1u);
    } else bk[k] = 0xFFFFFFFFu;
  }
  __syncthreads();
  for (int i = threadIdx.x; i < NBUCK; i += 256) {
    u32 c = cnt[i];
    base[i] = c ? atomicAdd(&gcur[i], c) : 0u;
    cnt[i] = 0;
  }
  __syncthreads();
#pragma unroll
  for (int k = 0; k < 8; ++k) {
    if (bk[k] != 0xFFFFFFFFu) {
      u32 p = base[bk[k]] + atomicAdd(&cnt[bk[k]], 1u);
      pairs[p] = pk[k];
    }
  }
}

// ---------- pass D: per-bucket node CSR (LDS hist+scan) + place ----------
__global__ __launch_bounds__(256) void fscat2_k(const u32* __restrict__ boffs,
                                                const u32* __restrict__ pairs,
                                                u32* __restrict__ esrc,
                                                u32* __restrict__ offs_g,
                                                u32* __restrict__ cnt_g) {
  __shared__ u32 lcnt[256], lexc[256], lcur[256];
  int b = blockIdx.x, t = threadIdx.x;
  u32 s0 = boffs[b], e0 = boffs[b + 1];
  lcnt[t] = 0;
  __syncthreads();
  for (u32 p = s0 + t; p < e0; p += 256) atomicAdd(&lcnt[pairs[p] >> 24], 1u);
  __syncthreads();
  u32 v = lcnt[t];
  lexc[t] = v;
  __syncthreads();
  for (int d = 1; d < 256; d <<= 1) {
    u32 a = (t >= d) ? lexc[t - d] : 0u;
    __syncthreads();
    lexc[t] += a;
    __syncthreads();
  }
  u32 excl = lexc[t] - v;
  int node = (b << 8) + t;
  if (node < N_NODES) { offs_g[node] = s0 + excl; cnt_g[node] = v; }
  lcur[t] = 0;
  lexc[t] = excl;
  __syncthreads();
  for (u32 p = s0 + t; p < e0; p += 256) {
    u32 pk = pairs[p];
    u32 dl = pk >> 24;
    u32 l = atomicAdd(&lcur[dl], 1u);
    esrc[s0 + lexc[dl] + l] = pk & 0x00FFFFFFu;
  }
}

// ---------- MFMA GEMM: [u | v] = act(X) @ [A-B | B] (bf16 in, f32 acc) ----------
// One 64-row tile per block; 4 waves, wave w = rows [w*16, w*16+16).
// Xl: 64 rows x 64 bf16, XOR-swizzled (byte^=(row&7)<<4) to kill bank conflicts.
__global__ __launch_bounds__(256) void gemm_mfma_k(
    const void* __restrict__ xin, int xbf16, const uint4* __restrict__ Wb,
    const float* __restrict__ ab, const float* __restrict__ bias,
    float* __restrict__ u, ushort* __restrict__ vb) {
  __shared__ u32 Xl[64 * 32];  // 8KB
  int t = threadIdx.x;
  int l = t & 63, wv = t >> 6;

  // B fragments: all waves load full [A-B|B] (16 frags x 16B per lane, L2-hot)
  short8 bs[2][8];
#pragma unroll
  for (int kh = 0; kh < 2; ++kh)
#pragma unroll
    for (int ct = 0; ct < 8; ++ct) {
      uint4 tmp = Wb[(kh * 8 + ct) * 64 + l];
      __builtin_memcpy(&bs[kh][ct], &tmp, 16);
    }

  // stage X tile (row srow, 16 cols at scol), act fused, bf16 packed
  int srow = t >> 2, scol = (t & 3) * 16;
  int rb = blockIdx.x * 64;
  int gr = rb + srow;
  u32 xb[8];
  if (gr < N_NODES) {
    if (xbf16) {
      const uint4* xp = (const uint4*)((const ushort*)xin + (size_t)gr * 64 + scol);
      uint4 p0 = xp[0], p1 = xp[1];
      u32 raw[8] = {p0.x, p0.y, p0.z, p0.w, p1.x, p1.y, p1.z, p1.w};
#pragma unroll
      for (int q = 0; q < 8; ++q) {
        int c = scol + 2 * q;
        float lo = fmaxf(fmaf(bflo(raw[q]), ab[c], ab[64 + c]), 0.f);
        float hi = fmaxf(fmaf(bfhi(raw[q]), ab[c + 1], ab[64 + c + 1]), 0.f);
        xb[q] = (u32)f2bf(lo) | ((u32)f2bf(hi) << 16);
      }
    } else {
      const float4* xp = (const float4*)((const float*)xin + (size_t)gr * 64 + scol);
#pragma unroll
      for (int q = 0; q < 4; ++q) {
        float4 a = xp[q];
        xb[2 * q]     = (u32)f2bf(a.x) | ((u32)f2bf(a.y) << 16);
        xb[2 * q + 1] = (u32)f2bf(a.z) | ((u32)f2bf(a.w) << 16);
      }
    }
  } else {
#pragma unroll
    for (int q = 0; q < 8; ++q) xb[q] = 0u;
  }
  int byte0 = srow * 128 + ((scol * 2) ^ ((srow & 7) << 4));
  int byte1 = srow * 128 + ((scol * 2 + 16) ^ ((srow & 7) << 4));
  *(uint4*)((char*)Xl + byte0) = make_uint4(xb[0], xb[1], xb[2], xb[3]);
  *(uint4*)((char*)Xl + byte1) = make_uint4(xb[4], xb[5], xb[6], xb[7]);
  __syncthreads();

  // accumulate: acc[ct] covers rows wv*16+4*(l>>4)+r, col ct*16+(l&15)
  f32x4 acc[8];
#pragma unroll
  for (int ct = 0; ct < 8; ++ct) {
    float b0 = (ct < 4) ? bias[ct * 16 + (l & 15)] : 0.f;
    acc[ct] = (f32x4){b0, b0, b0, b0};
  }
  int arow = wv * 16 + (l & 15);
#pragma unroll
  for (int kh = 0; kh < 2; ++kh) {
    int abyte = arow * 128 + ((kh * 64 + ((l >> 4) * 16)) ^ ((arow & 7) << 4));
    short8 af = *(const short8*)((const char*)Xl + abyte);
#pragma unroll
    for (int ct = 0; ct < 8; ++ct)
      acc[ct] = __builtin_amdgcn_mfma_f32_16x16x32_bf16(af, bs[kh][ct], acc[ct], 0, 0, 0);
  }

  // write out: C layout col=l&15, row=4*(l>>4)+reg (m89-verified)
  int rloc = rb + wv * 16 + 4 * (l >> 4);
#pragma unroll
  for (int ct = 0; ct < 4; ++ct) {
    int col = ct * 16 + (l & 15);
#pragma unroll
    for (int r = 0; r < 4; ++r) {
      int row = rloc + r;
      if (row < N_NODES) u[(size_t)row * 64 + col] = acc[ct][r];
    }
  }
#pragma unroll
  for (int ct = 4; ct < 8; ++ct) {
    int col = ct * 16 + (l & 15) - 64;
#pragma unroll
    for (int r = 0; r < 4; ++r) {
      int row = rloc + r;
      if (row < N_NODES) vb[(size_t)row * 64 + col] = f2bf(acc[ct][r]);
    }
  }
}

// ---------- segmax (bf16 v) + h = relu(u + max) -> bf16 h, + BN partials ----------
// wave: 4 nodes (16 lanes each), lane handles 4 channels (4qp..4qp+3) via one uint2.
__global__ __launch_bounds__(256) void segmax_k(
    const ushort* __restrict__ v, const u32* __restrict__ offs,
    const u32* __restrict__ cnt, const u32* __restrict__ edge_src,
    const float* __restrict__ u, ushort* __restrict__ h,
    float* __restrict__ part) {
  int t = threadIdx.x;
  int lane = t & 63;
  int sub = lane >> 4;
  int qp = lane & 15;
  int wv = t >> 6;
  int slot = blockIdx.x * 16 + wv * 4 + sub;
  const int nslots = SEG_NBLK * 16;
  const uint2* vw = (const uint2*)v;
  float s1[4] = {0.f, 0.f, 0.f, 0.f}, s2[4] = {0.f, 0.f, 0.f, 0.f};
  for (int node = slot; node < N_NODES; node += nslots) {
    u32 off = offs[node], deg = cnt[node];
    const u32* ep = edge_src + off;
    float m[4][4];
#pragma unroll
    for (int a = 0; a < 4; ++a)
#pragma unroll
      for (int c = 0; c < 4; ++c) m[a][c] = -INFINITY;
    u32 i = 0;
    for (; i + 4 <= deg; i += 4) {
      u32 sA = ep[i], sB = ep[i + 1], sC = ep[i + 2], sD = ep[i + 3];
      uint2 wA = vw[(size_t)sA * 16 + qp];
      uint2 wB = vw[(size_t)sB * 16 + qp];
      uint2 wC = vw[(size_t)sC * 16 + qp];
      uint2 wD = vw[(size_t)sD * 16 + qp];
      m[0][0] = fmaxf(m[0][0], bflo(wA.x)); m[0][1] = fmaxf(m[0][1], bfhi(wA.x));
      m[0][2] = fmaxf(m[0][2], bflo(wA.y)); m[0][3] = fmaxf(m[0][3], bfhi(wA.y));
      m[1][0] = fmaxf(m[1][0], bflo(wB.x)); m[1][1] = fmaxf(m[1][1], bfhi(wB.x));
      m[1][2] = fmaxf(m[1][2], bflo(wB.y)); m[1][3] = fmaxf(m[1][3], bfhi(wB.y));
      m[2][0] = fmaxf(m[2][0], bflo(wC.x)); m[2][1] = fmaxf(m[2][1], bfhi(wC.x));
      m[2][2] = fmaxf(m[2][2], bflo(wC.y)); m[2][3] = fmaxf(m[2][3], bfhi(wC.y));
      m[3][0] = fmaxf(m[3][0], bflo(wD.x)); m[3][1] = fmaxf(m[3][1], bfhi(wD.x));
      m[3][2] = fmaxf(m[3][2], bflo(wD.y)); m[3][3] = fmaxf(m[3][3], bfhi(wD.y));
    }
    for (; i < deg; ++i) {
      uint2 w = vw[(size_t)ep[i] * 16 + qp];
      m[0][0] = fmaxf(m[0][0], bflo(w.x)); m[0][1] = fmaxf(m[0][1], bfhi(w.x));
      m[0][2] = fmaxf(m[0][2], bflo(w.y)); m[0][3] = fmaxf(m[0][3], bfhi(w.y));
    }
    float mm[4];
#pragma unroll
    for (int c = 0; c < 4; ++c)
      mm[c] = fmaxf(fmaxf(m[0][c], m[1][c]), fmaxf(m[2][c], m[3][c]));
    float4 uv = *(const float4*)&u[(size_t)node * 64 + 4 * qp];
    float h0 = fmaxf(uv.x + mm[0], 0.f);  // relu(-inf)=0 covers deg==0
    float h1 = fmaxf(uv.y + mm[1], 0.f);
    float h2 = fmaxf(uv.z + mm[2], 0.f);
    float h3 = fmaxf(uv.w + mm[3], 0.f);
    u32 w0 = (u32)f2bf(h0) | ((u32)f2bf(h1) << 16);
    u32 w1 = (u32)f2bf(h2) | ((u32)f2bf(h3) << 16);
    ((uint2*)h)[(size_t)node * 16 + qp] = make_uint2(w0, w1);
    s1[0] += h0; s2[0] += h0 * h0;
    s1[1] += h1; s2[1] += h1 * h1;
    s1[2] += h2; s2[2] += h2 * h2;
    s1[3] += h3; s2[3] += h3 * h3;
  }
  __shared__ float4 r1[256], r2[256];
  r1[t] = make_float4(s1[0], s1[1], s1[2], s1[3]);
  r2[t] = make_float4(s2[0], s2[1], s2[2], s2[3]);
  __syncthreads();
  if (t < 16) {
    float4 a1 = r1[t], a2 = r2[t];
#pragma unroll
    for (int j = 1; j < 16; ++j) {
      float4 b1 = r1[j * 16 + t], b2 = r2[j * 16 + t];
      a1.x += b1.x; a1.y += b1.y; a1.z += b1.z; a1.w += b1.w;
      a2.x += b2.x; a2.y += b2.y; a2.z += b2.z; a2.w += b2.w;
    }
    part[blockIdx.x * 128 + 4 * t]     = a1.x;
    part[blockIdx.x * 128 + 4 * t + 1] = a1.y;
    part[blockIdx.x * 128 + 4 * t + 2] = a1.z;
    part[blockIdx.x * 128 + 4 * t + 3] = a1.w;
    part[blockIdx.x * 128 + 64 + 4 * t]     = a2.x;
    part[blockIdx.x * 128 + 64 + 4 * t + 1] = a2.y;
    part[blockIdx.x * 128 + 64 + 4 * t + 2] = a2.z;
    part[blockIdx.x * 128 + 64 + 4 * t + 3] = a2.w;
  }
}

// ---------- BN finalize: one block per channel ----------
__global__ void bn_final_k(const float* __restrict__ part, const float* __restrict__ g,
                           const float* __restrict__ be, float* __restrict__ ab) {
  int c = blockIdx.x;        // 64 channels
  int t = threadIdx.x;       // 256
  float s1 = 0.f, s2 = 0.f;
  for (int b = t; b < SEG_NBLK; b += 256) {
    s1 += part[b * 128 + c];
    s2 += part[b * 128 + 64 + c];
  }
  __shared__ float r1[256], r2[256];
  r1[t] = s1; r2[t] = s2;
  __syncthreads();
  for (int d = 128; d > 0; d >>= 1) {
    if (t < d) { r1[t] += r1[t + d]; r2[t] += r2[t + d]; }
    __syncthreads();
  }
  if (t == 0) {
    float mu = r1[0] / (float)N_NODES;
    float var = r2[0] / (float)N_NODES - mu * mu;
    float al = g[c] / sqrtf(var + EPS);
    ab[c] = al;
    ab[64 + c] = be[c] - mu * al;
  }
}

// ---------- graph boundaries (batch is sorted) ----------
__global__ void bounds_k(const int* __restrict__ batch, u32* __restrict__ bounds) {
  int t = threadIdx.x;
  if (t > 64) return;
  int lo = 0, hi = N_NODES;
  while (lo < hi) {
    int mid = (lo + hi) >> 1;
    if (batch[mid] < t) lo = mid + 1; else hi = mid;
  }
  bounds[t] = (u32)lo;
}

// ---------- parallel mean pool over bf16 h3 ----------
__global__ void pool_part_k(const ushort* __restrict__ h3, const u32* __restrict__ bounds,
                            float* __restrict__ sums) {
  int g = blockIdx.y;
  u32 s = bounds[g], e = bounds[g + 1];
  int t = threadIdx.x;
  int lane = t & 63, wv = t >> 6, sub = lane >> 5, cp = lane & 31;
  int slot = blockIdx.x * 8 + wv * 2 + sub;
  int nsl = gridDim.x * 8;
  const u32* hw = (const u32*)h3;
  float alo = 0.f, ahi = 0.f;
  for (u32 n = s + slot; n < e; n += nsl) {
    u32 w = hw[(size_t)n * 32 + cp];
    alo += bflo(w);
    ahi += bfhi(w);
  }
  __shared__ float2 red[256];
  red[t] = make_float2(alo, ahi);
  __syncthreads();
  if (t < 32) {
    float2 a = red[t];
#pragma unroll
    for (int j = 1; j < 8; ++j) {
      float2 b = red[t + 32 * j];
      a.x += b.x; a.y += b.y;
    }
    atomicAdd(&sums[g * 64 + 2 * t], a.x);
    atomicAdd(&sums[g * 64 + 2 * t + 1], a.y);
  }
}

// ---------- finalize pool (mean + BN3 affine) + linear head + softmax ----------
__global__ void head_k(const float* __restrict__ sums, const u32* __restrict__ bounds,
                       const float* __restrict__ ab3, const float* __restrict__ Wo,
                       const float* __restrict__ bo, float* __restrict__ out) {
  int g = threadIdx.x;
  if (g >= N_GRAPHS) return;
  u32 cntn = bounds[g + 1] - bounds[g];
  float inv = (cntn > 0) ? 1.f / (float)cntn : 0.f;
  float lg[10];
#pragma unroll
  for (int j = 0; j < 10; ++j) lg[j] = bo[j];
  for (int c = 0; c < 64; ++c) {
    float p = (cntn > 0) ? (sums[g * 64 + c] * inv * ab3[c] + ab3[64 + c]) : 0.f;
#pragma unroll
    for (int j = 0; j < 10; ++j) lg[j] = fmaf(p, Wo[c * 10 + j], lg[j]);
  }
  float mx = lg[0];
#pragma unroll
  for (int j = 1; j < 10; ++j) mx = fmaxf(mx, lg[j]);
  float s = 0.f, ex[10];
#pragma unroll
  for (int j = 0; j < 10; ++j) { ex[j] = expf(lg[j] - mx); s += ex[j]; }
#pragma unroll
  for (int j = 0; j < 10; ++j) out[g * 10 + j] = ex[j] / s;
}

extern "C" void kernel_launch(void* const* d_in, const int* in_sizes, int n_in,
                              void* d_out, int out_size, void* d_ws, size_t ws_size,
                              hipStream_t stream) {
  const float* x    = (const float*)d_in[0];
  const int*   ei   = (const int*)d_in[1];
  const int*   batch= (const int*)d_in[2];
  const float* W1 = (const float*)d_in[3];  const float* b1 = (const float*)d_in[4];
  const float* W2 = (const float*)d_in[5];  const float* b2 = (const float*)d_in[6];
  const float* W3 = (const float*)d_in[7];  const float* b3 = (const float*)d_in[8];
  const float* g1 = (const float*)d_in[9];  const float* be1= (const float*)d_in[10];
  const float* g2 = (const float*)d_in[11]; const float* be2= (const float*)d_in[12];
  const float* g3 = (const float*)d_in[13]; const float* be3= (const float*)d_in[14];
  const float* Wo = (const float*)d_in[15]; const float* bo = (const float*)d_in[16];
  float* out = (float*)d_out;

  char* p = (char*)d_ws;
  auto alloc = [&](size_t bytes) { void* r = (void*)p; p += (bytes + 255) & ~(size_t)255; return r; };
  uint4* Wb     = (uint4*)alloc(3072 * sizeof(uint4));
  float* ab     = (float*)alloc(3 * 128 * sizeof(float));
  u32*   bounds = (u32*)alloc(65 * sizeof(u32));
  u32*   bcnt   = (u32*)alloc(NBUCK * sizeof(u32));
  u32*   boffs  = (u32*)alloc((NBUCK + 1) * sizeof(u32));
  u32*   bcur   = (u32*)alloc(NBUCK * sizeof(u32));
  u32*   cnt    = (u32*)alloc((size_t)N_NODES * sizeof(u32));
  u32*   offs   = (u32*)alloc((size_t)N_NODES * sizeof(u32));
  float* part   = (float*)alloc((size_t)SEG_NBLK * 128 * sizeof(float));
  float* sums   = (float*)alloc(64 * 64 * sizeof(float));
  u32*   esrc   = (u32*)alloc((size_t)N_EDGES * sizeof(u32));
  u32*   pairs  = (u32*)alloc((size_t)N_EDGES * sizeof(u32));
  float* bufU   = (float*)alloc((size_t)N_NODES * 64 * sizeof(float));
  ushort* vb    = (ushort*)alloc((size_t)N_NODES * 64 * sizeof(ushort));
  ushort* hb    = (ushort*)alloc((size_t)N_NODES * 64 * sizeof(ushort));

  const int* src = ei;
  const int* dst = ei + N_EDGES;

  // weights prep + CSR build (edges identical for all 3 layers)
  prep_wb_k<<<12, 256, 0, stream>>>(W1, W2, W3, Wb);
  hipMemsetAsync(bcnt, 0, NBUCK * sizeof(u32), stream);
  bhist_k<<<(N_EDGES + 2047) / 2048, 256, 0, stream>>>(dst, bcnt);
  bscan_k<<<1, 512, 0, stream>>>(bcnt, boffs, bcur);
  bscat_k<<<(N_EDGES + 2047) / 2048, 256, 0, stream>>>(src, dst, bcur, pairs);
  fscat2_k<<<NBUCK, 256, 0, stream>>>(boffs, pairs, esrc, offs, cnt);
  bounds_k<<<1, 128, 0, stream>>>(batch, bounds);
  hipMemsetAsync(sums, 0, 64 * 64 * sizeof(float), stream);

  const int GEMM_GRID = (N_NODES + 63) / 64;  // 1563 tiles, one per block

  // ---- layer 1 ----
  gemm_mfma_k<<<GEMM_GRID, 256, 0, stream>>>(x, 0, Wb, nullptr, b1, bufU, vb);
  segmax_k<<<SEG_NBLK, 256, 0, stream>>>(vb, offs, cnt, esrc, bufU, hb, part);
  bn_final_k<<<64, 256, 0, stream>>>(part, g1, be1, ab);

  // ---- layer 2 ----
  gemm_mfma_k<<<GEMM_GRID, 256, 0, stream>>>(hb, 1, Wb + 1024, ab, b2, bufU, vb);
  segmax_k<<<SEG_NBLK, 256, 0, stream>>>(vb, offs, cnt, esrc, bufU, hb, part);
  bn_final_k<<<64, 256, 0, stream>>>(part, g2, be2, ab + 128);

  // ---- layer 3 ----
  gemm_mfma_k<<<GEMM_GRID, 256, 0, stream>>>(hb, 1, Wb + 2048, ab + 128, b3, bufU, vb);
  segmax_k<<<SEG_NBLK, 256, 0, stream>>>(vb, offs, cnt, esrc, bufU, hb, part);
  bn_final_k<<<64, 256, 0, stream>>>(part, g3, be3, ab + 256);

  // ---- pool (+BN3 affine) + head ----
  pool_part_k<<<dim3(8, N_GRAPHS), 256, 0, stream>>>(hb, bounds, sums);
  head_k<<<1, 64, 0, stream>>>(sums, bounds, ab + 256, Wo, bo, out);
}

// Round 8
// 265.661 us; speedup vs baseline: 4.5305x; 1.0647x over previous
//
#include <hip/hip_runtime.h>
#include <hip/hip_bf16.h>
#include <math.h>

#define N_NODES 100000
#define N_EDGES 1600000
#define N_GRAPHS 64
#define EPS 1e-5f
#define NBUCK 391     // ceil(N_NODES / 256)
#define EBLK 782      // ceil(N_EDGES / 2048)
#define SEG_NBLK 2048 // segmax blocks (32 node-slots each)
#define GEMM_TILES 1563  // ceil(N_NODES / 64)

typedef unsigned int u32;
typedef __attribute__((ext_vector_type(8))) short short8;
typedef __attribute__((ext_vector_type(4))) float f32x4;

static __device__ __forceinline__ ushort f2bf(float f) {
  u32 x = __float_as_uint(f);
  u32 r = (x + 0x7fffu + ((x >> 16) & 1u)) >> 16;  // RNE; inputs finite
  return (ushort)r;
}
static __device__ __forceinline__ float bflo(u32 w) { return __uint_as_float(w << 16); }
static __device__ __forceinline__ float bfhi(u32 w) { return __uint_as_float(w & 0xffff0000u); }
static __device__ __forceinline__ void decode8(uint4 w, float* f) {
  f[0] = bflo(w.x); f[1] = bfhi(w.x); f[2] = bflo(w.y); f[3] = bfhi(w.y);
  f[4] = bflo(w.z); f[5] = bfhi(w.z); f[6] = bflo(w.w); f[7] = bfhi(w.w);
}

// ---------- setup: bhist (bucket=dst>>8) + weight pack + graph bounds ----------
// Wb[layer][kh(2)][ct(8)][lane(64)] = uint4 (8 bf16): lane l, elem j ->
//   Wc[kh*32 + (l>>4)*8 + j][ct*16 + (l&15)], Wc = [A-B | B] (64 x 128)
__global__ __launch_bounds__(256) void setup_k(
    const int* __restrict__ dst, u32* __restrict__ bcnt,
    const float* __restrict__ W1, const float* __restrict__ W2,
    const float* __restrict__ W3, uint4* __restrict__ Wb,
    const int* __restrict__ batch, u32* __restrict__ bounds) {
  __shared__ u32 csh[NBUCK];
  int bid = blockIdx.x, t = threadIdx.x;
  if (bid < EBLK) {
    for (int i = t; i < NBUCK; i += 256) csh[i] = 0;
    __syncthreads();
    int base = bid * 2048;
#pragma unroll
    for (int k = 0; k < 8; ++k) {
      int e = base + k * 256 + t;
      if (e < N_EDGES) atomicAdd(&csh[(u32)dst[e] >> 8], 1u);
    }
    __syncthreads();
    for (int i = t; i < NBUCK; i += 256) {
      u32 cc = csh[i];
      if (cc) atomicAdd(&bcnt[i], cc);
    }
  } else if (bid < EBLK + 12) {
    int g = (bid - EBLK) * 256 + t;
    if (g >= 3072) return;
    int layer = g >> 10, rem = g & 1023;
    int kh = rem >> 9, ct = (rem >> 6) & 7, l = rem & 63;
    const float* W = (layer == 0) ? W1 : (layer == 1) ? W2 : W3;
    int c = ct * 16 + (l & 15);
    u32 w[4];
#pragma unroll
    for (int jj = 0; jj < 4; ++jj) {
      int k0 = kh * 32 + (l >> 4) * 8 + 2 * jj;
      float v0, v1;
      if (c < 64) {
        v0 = W[k0 * 64 + c] - W[(64 + k0) * 64 + c];
        v1 = W[(k0 + 1) * 64 + c] - W[(65 + k0) * 64 + c];
      } else {
        v0 = W[(64 + k0) * 64 + (c - 64)];
        v1 = W[(65 + k0) * 64 + (c - 64)];
      }
      w[jj] = (u32)f2bf(v0) | ((u32)f2bf(v1) << 16);
    }
    Wb[g] = make_uint4(w[0], w[1], w[2], w[3]);
  } else {
    if (t > 64) return;
    int lo = 0, hi = N_NODES;
    while (lo < hi) {
      int mid = (lo + hi) >> 1;
      if (batch[mid] < t) lo = mid + 1; else hi = mid;
    }
    bounds[t] = (u32)lo;
  }
}

// ---------- bucket scan -> boffs (exclusive, +total), bcur ----------
__global__ void bscan_k(const u32* __restrict__ bcnt, u32* __restrict__ boffs,
                        u32* __restrict__ bcur) {
  __shared__ u32 s[512];
  int t = threadIdx.x;
  u32 v = (t < NBUCK) ? bcnt[t] : 0u;
  s[t] = v;
  __syncthreads();
  for (int d = 1; d < 512; d <<= 1) {
    u32 a = (t >= d) ? s[t - d] : 0u;
    __syncthreads();
    s[t] += a;
    __syncthreads();
  }
  if (t < NBUCK) { boffs[t] = s[t] - v; bcur[t] = s[t] - v; }
  if (t == NBUCK - 1) boffs[NBUCK] = s[t];
}

// ---------- pass C: edges -> bucket-grouped packed pairs ((dst&255)<<24 | src) ----------
__global__ __launch_bounds__(256) void bscat_k(const int* __restrict__ src,
                                               const int* __restrict__ dst,
                                               u32* __restrict__ gcur,
                                               u32* __restrict__ pairs) {
  __shared__ u32 cnt[NBUCK];
  __shared__ u32 base[NBUCK];
  for (int i = threadIdx.x; i < NBUCK; i += 256) cnt[i] = 0;
  __syncthreads();
  u32 pk[8], bk[8];
  int be = blockIdx.x * 2048;
#pragma unroll
  for (int k = 0; k < 8; ++k) {
    int e = be + k * 256 + threadIdx.x;
    if (e < N_EDGES) {
      u32 d = (u32)dst[e], s = (u32)src[e];
      u32 b = d >> 8;
      pk[k] = ((d & 255u) << 24) | s;
      bk[k] = b;
      atomicAdd(&cnt[b], 1u);
    } else bk[k] = 0xFFFFFFFFu;
  }
  __syncthreads();
  for (int i = threadIdx.x; i < NBUCK; i += 256) {
    u32 c = cnt[i];
    base[i] = c ? atomicAdd(&gcur[i], c) : 0u;
    cnt[i] = 0;
  }
  __syncthreads();
#pragma unroll
  for (int k = 0; k < 8; ++k) {
    if (bk[k] != 0xFFFFFFFFu) {
      u32 p = base[bk[k]] + atomicAdd(&cnt[bk[k]], 1u);
      pairs[p] = pk[k];
    }
  }
}

// ---------- fscat2 body: per-bucket node CSR (LDS hist+scan) + place ----------
static __device__ __forceinline__ void fscat2_body(
    int b, u32* SH, const u32* __restrict__ boffs, const u32* __restrict__ pairs,
    u32* __restrict__ esrc, u32* __restrict__ offs_g, u32* __restrict__ cnt_g) {
  u32* lcnt = SH; u32* lexc = SH + 256; u32* lcur = SH + 512;
  int t = threadIdx.x;
  u32 s0 = boffs[b], e0 = boffs[b + 1];
  lcnt[t] = 0;
  __syncthreads();
  for (u32 p = s0 + t; p < e0; p += 256) atomicAdd(&lcnt[pairs[p] >> 24], 1u);
  __syncthreads();
  u32 v = lcnt[t];
  lexc[t] = v;
  __syncthreads();
  for (int d = 1; d < 256; d <<= 1) {
    u32 a = (t >= d) ? lexc[t - d] : 0u;
    __syncthreads();
    lexc[t] += a;
    __syncthreads();
  }
  u32 excl = lexc[t] - v;
  int node = (b << 8) + t;
  if (node < N_NODES) { offs_g[node] = s0 + excl; cnt_g[node] = v; }
  lcur[t] = 0;
  lexc[t] = excl;
  __syncthreads();
  for (u32 p = s0 + t; p < e0; p += 256) {
    u32 pk = pairs[p];
    u32 dl = pk >> 24;
    u32 l = atomicAdd(&lcur[dl], 1u);
    esrc[s0 + lexc[dl] + l] = pk & 0x00FFFFFFu;
  }
}

// ---------- MFMA GEMM body: [u | v] = act(X) @ [A-B | B], u/v bf16 out ----------
// One 64-row tile; 4 waves; Xl XOR-swizzled (byte^=(row&7)<<4).
static __device__ __forceinline__ void gemm_body(
    int tile, u32* Xl,
    const void* __restrict__ xin, int xbf16, const uint4* __restrict__ Wb,
    const float* __restrict__ ab, const float* __restrict__ bias,
    ushort* __restrict__ ub, ushort* __restrict__ vb) {
  int t = threadIdx.x;
  int l = t & 63, wv = t >> 6;
  short8 bs[2][8];
#pragma unroll
  for (int kh = 0; kh < 2; ++kh)
#pragma unroll
    for (int ct = 0; ct < 8; ++ct) {
      uint4 tmp = Wb[(kh * 8 + ct) * 64 + l];
      __builtin_memcpy(&bs[kh][ct], &tmp, 16);
    }
  int srow = t >> 2, scol = (t & 3) * 16;
  int rb = tile * 64;
  int gr = rb + srow;
  u32 xb[8];
  if (gr < N_NODES) {
    if (xbf16) {
      const uint4* xp = (const uint4*)((const ushort*)xin + (size_t)gr * 64 + scol);
      uint4 p0 = xp[0], p1 = xp[1];
      u32 raw[8] = {p0.x, p0.y, p0.z, p0.w, p1.x, p1.y, p1.z, p1.w};
#pragma unroll
      for (int q = 0; q < 8; ++q) {
        int c = scol + 2 * q;
        float lo = fmaxf(fmaf(bflo(raw[q]), ab[c], ab[64 + c]), 0.f);
        float hi = fmaxf(fmaf(bfhi(raw[q]), ab[c + 1], ab[64 + c + 1]), 0.f);
        xb[q] = (u32)f2bf(lo) | ((u32)f2bf(hi) << 16);
      }
    } else {
      const float4* xp = (const float4*)((const float*)xin + (size_t)gr * 64 + scol);
#pragma unroll
      for (int q = 0; q < 4; ++q) {
        float4 a = xp[q];
        xb[2 * q]     = (u32)f2bf(a.x) | ((u32)f2bf(a.y) << 16);
        xb[2 * q + 1] = (u32)f2bf(a.z) | ((u32)f2bf(a.w) << 16);
      }
    }
  } else {
#pragma unroll
    for (int q = 0; q < 8; ++q) xb[q] = 0u;
  }
  int byte0 = srow * 128 + ((scol * 2) ^ ((srow & 7) << 4));
  int byte1 = srow * 128 + ((scol * 2 + 16) ^ ((srow & 7) << 4));
  *(uint4*)((char*)Xl + byte0) = make_uint4(xb[0], xb[1], xb[2], xb[3]);
  *(uint4*)((char*)Xl + byte1) = make_uint4(xb[4], xb[5], xb[6], xb[7]);
  __syncthreads();
  f32x4 acc[8];
#pragma unroll
  for (int ct = 0; ct < 8; ++ct) {
    float b0 = (ct < 4) ? bias[ct * 16 + (l & 15)] : 0.f;
    acc[ct] = (f32x4){b0, b0, b0, b0};
  }
  int arow = wv * 16 + (l & 15);
#pragma unroll
  for (int kh = 0; kh < 2; ++kh) {
    int abyte = arow * 128 + ((kh * 64 + ((l >> 4) * 16)) ^ ((arow & 7) << 4));
    short8 af = *(const short8*)((const char*)Xl + abyte);
#pragma unroll
    for (int ct = 0; ct < 8; ++ct)
      acc[ct] = __builtin_amdgcn_mfma_f32_16x16x32_bf16(af, bs[kh][ct], acc[ct], 0, 0, 0);
  }
  // C layout: col = l&15, row = 4*(l>>4)+reg (m89-verified)
  int rloc = rb + wv * 16 + 4 * (l >> 4);
#pragma unroll
  for (int ct = 0; ct < 4; ++ct) {
    int col = ct * 16 + (l & 15);
#pragma unroll
    for (int r = 0; r < 4; ++r) {
      int row = rloc + r;
      if (row < N_NODES) ub[(size_t)row * 64 + col] = f2bf(acc[ct][r]);
    }
  }
#pragma unroll
  for (int ct = 4; ct < 8; ++ct) {
    int col = ct * 16 + (l & 15) - 64;
#pragma unroll
    for (int r = 0; r < 4; ++r) {
      int row = rloc + r;
      if (row < N_NODES) vb[(size_t)row * 64 + col] = f2bf(acc[ct][r]);
    }
  }
}

// ---------- fused: fscat2 (391 blocks) || layer-1 GEMM (1563 blocks) ----------
__global__ __launch_bounds__(256) void fused_fg_k(
    const u32* __restrict__ boffs, const u32* __restrict__ pairs,
    u32* __restrict__ esrc, u32* __restrict__ offs_g, u32* __restrict__ cnt_g,
    const float* __restrict__ x, const uint4* __restrict__ Wb,
    const float* __restrict__ bias, ushort* __restrict__ ub, ushort* __restrict__ vb) {
  __shared__ u32 SH[2048];  // 8KB: fscat2 uses 3KB, gemm uses all
  int bid = blockIdx.x;
  if (bid < NBUCK) fscat2_body(bid, SH, boffs, pairs, esrc, offs_g, cnt_g);
  else gemm_body(bid - NBUCK, SH, x, 0, Wb, nullptr, bias, ub, vb);
}

// ---------- standalone GEMM (layers 2,3; bf16 input + BN affine) ----------
__global__ __launch_bounds__(256) void gemm_k(
    const ushort* __restrict__ xin, const uint4* __restrict__ Wb,
    const float* __restrict__ ab, const float* __restrict__ bias,
    ushort* __restrict__ ub, ushort* __restrict__ vb) {
  __shared__ u32 Xl[2048];
  gemm_body(blockIdx.x, Xl, xin, 1, Wb, ab, bias, ub, vb);
}

// ---------- segmax: 8 lanes/node, uint4 gathers; h=relu(u+max) bf16; BN partials ----------
__global__ __launch_bounds__(256) void segmax_k(
    const ushort* __restrict__ v, const u32* __restrict__ offs,
    const u32* __restrict__ cnt, const u32* __restrict__ esrc,
    const ushort* __restrict__ ub, ushort* __restrict__ hb,
    float* __restrict__ part) {
  int t = threadIdx.x;
  int lane = t & 63;
  int op = lane & 7;        // uint4 index within row (8 channels)
  int sub = lane >> 3;      // node sub-group within wave (8 nodes/wave)
  int wv = t >> 6;
  int slot = blockIdx.x * 32 + wv * 8 + sub;
  const int nslots = SEG_NBLK * 32;
  const uint4* v4 = (const uint4*)v;
  const uint4* u4 = (const uint4*)ub;
  uint4* h4 = (uint4*)hb;
  float s1[8], s2[8];
#pragma unroll
  for (int j = 0; j < 8; ++j) { s1[j] = 0.f; s2[j] = 0.f; }
  for (int node = slot; node < N_NODES; node += nslots) {
    u32 off = offs[node], deg = cnt[node];
    const u32* ep = esrc + off;
    float m[8];
#pragma unroll
    for (int j = 0; j < 8; ++j) m[j] = -INFINITY;
    u32 i = 0;
    for (; i + 2 <= deg; i += 2) {
      u32 sA = ep[i], sB = ep[i + 1];
      uint4 wA = v4[(size_t)sA * 8 + op];
      uint4 wB = v4[(size_t)sB * 8 + op];
      float fA[8], fB[8];
      decode8(wA, fA); decode8(wB, fB);
#pragma unroll
      for (int j = 0; j < 8; ++j) m[j] = fmaxf(m[j], fmaxf(fA[j], fB[j]));
    }
    if (i < deg) {
      uint4 w = v4[(size_t)ep[i] * 8 + op];
      float f[8]; decode8(w, f);
#pragma unroll
      for (int j = 0; j < 8; ++j) m[j] = fmaxf(m[j], f[j]);
    }
    uint4 uu = u4[(size_t)node * 8 + op];
    float uf[8]; decode8(uu, uf);
    float h[8];
#pragma unroll
    for (int j = 0; j < 8; ++j) {
      h[j] = fmaxf(uf[j] + m[j], 0.f);   // relu(-inf)=0 covers deg==0
      s1[j] += h[j]; s2[j] += h[j] * h[j];
    }
    uint4 hw;
    hw.x = (u32)f2bf(h[0]) | ((u32)f2bf(h[1]) << 16);
    hw.y = (u32)f2bf(h[2]) | ((u32)f2bf(h[3]) << 16);
    hw.z = (u32)f2bf(h[4]) | ((u32)f2bf(h[5]) << 16);
    hw.w = (u32)f2bf(h[6]) | ((u32)f2bf(h[7]) << 16);
    h4[(size_t)node * 8 + op] = hw;
  }
  // BN partial reduce: channel c = op*8 + j
  __shared__ float red[256 * 8];
#pragma unroll
  for (int j = 0; j < 8; ++j) red[t * 8 + j] = s1[j];
  __syncthreads();
  float o1 = 0.f, o2 = 0.f;
  if (t < 64) {
    int cop = t >> 3, cj = t & 7;
    for (int q = 0; q < 32; ++q) o1 += red[(q * 8 + cop) * 8 + cj];
  }
  __syncthreads();
#pragma unroll
  for (int j = 0; j < 8; ++j) red[t * 8 + j] = s2[j];
  __syncthreads();
  if (t < 64) {
    int cop = t >> 3, cj = t & 7;
    for (int q = 0; q < 32; ++q) o2 += red[(q * 8 + cop) * 8 + cj];
    part[blockIdx.x * 128 + t] = o1;
    part[blockIdx.x * 128 + 64 + t] = o2;
  }
}

// ---------- BN finalize: one block per channel ----------
__global__ void bn_final_k(const float* __restrict__ part, const float* __restrict__ g,
                           const float* __restrict__ be, float* __restrict__ ab) {
  int c = blockIdx.x;
  int t = threadIdx.x;
  float s1 = 0.f, s2 = 0.f;
  for (int b = t; b < SEG_NBLK; b += 256) {
    s1 += part[b * 128 + c];
    s2 += part[b * 128 + 64 + c];
  }
  __shared__ float r1[256], r2[256];
  r1[t] = s1; r2[t] = s2;
  __syncthreads();
  for (int d = 128; d > 0; d >>= 1) {
    if (t < d) { r1[t] += r1[t + d]; r2[t] += r2[t + d]; }
    __syncthreads();
  }
  if (t == 0) {
    float mu = r1[0] / (float)N_NODES;
    float var = r2[0] / (float)N_NODES - mu * mu;
    float al = g[c] / sqrtf(var + EPS);
    ab[c] = al;
    ab[64 + c] = be[c] - mu * al;
  }
}

// ---------- parallel mean pool over bf16 h3 ----------
__global__ void pool_part_k(const ushort* __restrict__ h3, const u32* __restrict__ bounds,
                            float* __restrict__ sums) {
  int g = blockIdx.y;
  u32 s = bounds[g], e = bounds[g + 1];
  int t = threadIdx.x;
  int lane = t & 63, wv = t >> 6, sub = lane >> 5, cp = lane & 31;
  int slot = blockIdx.x * 8 + wv * 2 + sub;
  int nsl = gridDim.x * 8;
  const u32* hw = (const u32*)h3;
  float alo = 0.f, ahi = 0.f;
  for (u32 n = s + slot; n < e; n += nsl) {
    u32 w = hw[(size_t)n * 32 + cp];
    alo += bflo(w);
    ahi += bfhi(w);
  }
  __shared__ float2 red[256];
  red[t] = make_float2(alo, ahi);
  __syncthreads();
  if (t < 32) {
    float2 a = red[t];
#pragma unroll
    for (int j = 1; j < 8; ++j) {
      float2 b = red[t + 32 * j];
      a.x += b.x; a.y += b.y;
    }
    atomicAdd(&sums[g * 64 + 2 * t], a.x);
    atomicAdd(&sums[g * 64 + 2 * t + 1], a.y);
  }
}

// ---------- finalize pool (mean + BN3 affine) + linear head + softmax ----------
__global__ void head_k(const float* __restrict__ sums, const u32* __restrict__ bounds,
                       const float* __restrict__ ab3, const float* __restrict__ Wo,
                       const float* __restrict__ bo, float* __restrict__ out) {
  int g = threadIdx.x;
  if (g >= N_GRAPHS) return;
  u32 cntn = bounds[g + 1] - bounds[g];
  float inv = (cntn > 0) ? 1.f / (float)cntn : 0.f;
  float lg[10];
#pragma unroll
  for (int j = 0; j < 10; ++j) lg[j] = bo[j];
  for (int c = 0; c < 64; ++c) {
    float p = (cntn > 0) ? (sums[g * 64 + c] * inv * ab3[c] + ab3[64 + c]) : 0.f;
#pragma unroll
    for (int j = 0; j < 10; ++j) lg[j] = fmaf(p, Wo[c * 10 + j], lg[j]);
  }
  float mx = lg[0];
#pragma unroll
  for (int j = 1; j < 10; ++j) mx = fmaxf(mx, lg[j]);
  float s = 0.f, ex[10];
#pragma unroll
  for (int j = 0; j < 10; ++j) { ex[j] = expf(lg[j] - mx); s += ex[j]; }
#pragma unroll
  for (int j = 0; j < 10; ++j) out[g * 10 + j] = ex[j] / s;
}

extern "C" void kernel_launch(void* const* d_in, const int* in_sizes, int n_in,
                              void* d_out, int out_size, void* d_ws, size_t ws_size,
                              hipStream_t stream) {
  const float* x    = (const float*)d_in[0];
  const int*   ei   = (const int*)d_in[1];
  const int*   batch= (const int*)d_in[2];
  const float* W1 = (const float*)d_in[3];  const float* b1 = (const float*)d_in[4];
  const float* W2 = (const float*)d_in[5];  const float* b2 = (const float*)d_in[6];
  const float* W3 = (const float*)d_in[7];  const float* b3 = (const float*)d_in[8];
  const float* g1 = (const float*)d_in[9];  const float* be1= (const float*)d_in[10];
  const float* g2 = (const float*)d_in[11]; const float* be2= (const float*)d_in[12];
  const float* g3 = (const float*)d_in[13]; const float* be3= (const float*)d_in[14];
  const float* Wo = (const float*)d_in[15]; const float* bo = (const float*)d_in[16];
  float* out = (float*)d_out;

  char* p = (char*)d_ws;
  auto alloc = [&](size_t bytes) { void* r = (void*)p; p += (bytes + 255) & ~(size_t)255; return r; };
  uint4* Wb     = (uint4*)alloc(3072 * sizeof(uint4));
  float* ab     = (float*)alloc(3 * 128 * sizeof(float));
  u32*   bounds = (u32*)alloc(65 * sizeof(u32));
  u32*   bcnt   = (u32*)alloc(NBUCK * sizeof(u32));
  u32*   boffs  = (u32*)alloc((NBUCK + 1) * sizeof(u32));
  u32*   bcur   = (u32*)alloc(NBUCK * sizeof(u32));
  u32*   cnt    = (u32*)alloc((size_t)N_NODES * sizeof(u32));
  u32*   offs   = (u32*)alloc((size_t)N_NODES * sizeof(u32));
  float* part   = (float*)alloc((size_t)SEG_NBLK * 128 * sizeof(float));
  float* sums   = (float*)alloc(64 * 64 * sizeof(float));
  u32*   esrc   = (u32*)alloc((size_t)N_EDGES * sizeof(u32));
  u32*   pairs  = (u32*)alloc((size_t)N_EDGES * sizeof(u32));
  ushort* ub    = (ushort*)alloc((size_t)N_NODES * 64 * sizeof(ushort));
  ushort* vb    = (ushort*)alloc((size_t)N_NODES * 64 * sizeof(ushort));
  ushort* hb    = (ushort*)alloc((size_t)N_NODES * 64 * sizeof(ushort));

  const int* src = ei;
  const int* dst = ei + N_EDGES;

  hipMemsetAsync(bcnt, 0, NBUCK * sizeof(u32), stream);
  hipMemsetAsync(sums, 0, 64 * 64 * sizeof(float), stream);
  // setup: bhist (782) + weight pack (12) + bounds (1)
  setup_k<<<EBLK + 13, 256, 0, stream>>>(dst, bcnt, W1, W2, W3, Wb, batch, bounds);
  bscan_k<<<1, 512, 0, stream>>>(bcnt, boffs, bcur);
  bscat_k<<<EBLK, 256, 0, stream>>>(src, dst, bcur, pairs);

  // fscat2 || layer-1 GEMM
  fused_fg_k<<<NBUCK + GEMM_TILES, 256, 0, stream>>>(boffs, pairs, esrc, offs, cnt,
                                                     x, Wb, b1, ub, vb);
  segmax_k<<<SEG_NBLK, 256, 0, stream>>>(vb, offs, cnt, esrc, ub, hb, part);
  bn_final_k<<<64, 256, 0, stream>>>(part, g1, be1, ab);

  // ---- layer 2 ----
  gemm_k<<<GEMM_TILES, 256, 0, stream>>>(hb, Wb + 1024, ab, b2, ub, vb);
  segmax_k<<<SEG_NBLK, 256, 0, stream>>>(vb, offs, cnt, esrc, ub, hb, part);
  bn_final_k<<<64, 256, 0, stream>>>(part, g2, be2, ab + 128);

  // ---- layer 3 ----
  gemm_k<<<GEMM_TILES, 256, 0, stream>>>(hb, Wb + 2048, ab + 128, b3, ub, vb);
  segmax_k<<<SEG_NBLK, 256, 0, stream>>>(vb, offs, cnt, esrc, ub, hb, part);
  bn_final_k<<<64, 256, 0, stream>>>(part, g3, be3, ab + 256);

  // ---- pool (+BN3 affine) + head ----
  pool_part_k<<<dim3(8, N_GRAPHS), 256, 0, stream>>>(hb, bounds, sums);
  head_k<<<1, 64, 0, stream>>>(sums, bounds, ab + 256, Wo, bo, out);
}

// Round 9
// 264.127 us; speedup vs baseline: 4.5569x; 1.0058x over previous
//
#include <hip/hip_runtime.h>
#include <hip/hip_bf16.h>
#include <math.h>

#define N_NODES 100000
#define N_EDGES 1600000
#define N_GRAPHS 64
#define EPS 1e-5f
#define NBUCK 391       // ceil(N_NODES / 256)
#define EBLK 782        // ceil(N_EDGES / 2048)  (setup bhist blocks)
#define BSCAT_GRID 196  // ceil(N_EDGES / 8192)
#define SEG_NBLK 3125   // 3125 * 32 = 100000 node slots (exact)
#define GEMM_TILES 1563 // ceil(N_NODES / 64)

typedef unsigned int u32;
typedef __attribute__((ext_vector_type(8))) short short8;
typedef __attribute__((ext_vector_type(4))) float f32x4;

static __device__ __forceinline__ ushort f2bf(float f) {
  u32 x = __float_as_uint(f);
  u32 r = (x + 0x7fffu + ((x >> 16) & 1u)) >> 16;  // RNE; inputs finite
  return (ushort)r;
}
static __device__ __forceinline__ float bflo(u32 w) { return __uint_as_float(w << 16); }
static __device__ __forceinline__ float bfhi(u32 w) { return __uint_as_float(w & 0xffff0000u); }
static __device__ __forceinline__ void decode8(uint4 w, float* f) {
  f[0] = bflo(w.x); f[1] = bfhi(w.x); f[2] = bflo(w.y); f[3] = bfhi(w.y);
  f[4] = bflo(w.z); f[5] = bfhi(w.z); f[6] = bflo(w.w); f[7] = bfhi(w.w);
}

// ---------- setup: bhist + weight pack + graph bounds + zero accumulators ----------
// Wb[layer][kh(2)][ct(8)][lane(64)] = uint4 (8 bf16): lane l, elem j ->
//   Wc[kh*32 + (l>>4)*8 + j][ct*16 + (l&15)], Wc = [A-B | B] (64 x 128)
__global__ __launch_bounds__(256) void setup_k(
    const int* __restrict__ dst, u32* __restrict__ bcnt,
    const float* __restrict__ W1, const float* __restrict__ W2,
    const float* __restrict__ W3, uint4* __restrict__ Wb,
    const int* __restrict__ batch, u32* __restrict__ bounds,
    u32* __restrict__ zbase) {
  __shared__ u32 csh[NBUCK];
  int bid = blockIdx.x, t = threadIdx.x;
  if (bid < EBLK) {
    for (int i = t; i < NBUCK; i += 256) csh[i] = 0;
    __syncthreads();
    int base = bid * 2048;
#pragma unroll
    for (int k = 0; k < 8; ++k) {
      int e = base + k * 256 + t;
      if (e < N_EDGES) atomicAdd(&csh[(u32)dst[e] >> 8], 1u);
    }
    __syncthreads();
    for (int i = t; i < NBUCK; i += 256) {
      u32 cc = csh[i];
      if (cc) atomicAdd(&bcnt[i], cc);
    }
  } else if (bid < EBLK + 12) {
    int g = (bid - EBLK) * 256 + t;
    if (g >= 3072) return;
    int layer = g >> 10, rem = g & 1023;
    int kh = rem >> 9, ct = (rem >> 6) & 7, l = rem & 63;
    const float* W = (layer == 0) ? W1 : (layer == 1) ? W2 : W3;
    int c = ct * 16 + (l & 15);
    u32 w[4];
#pragma unroll
    for (int jj = 0; jj < 4; ++jj) {
      int k0 = kh * 32 + (l >> 4) * 8 + 2 * jj;
      float v0, v1;
      if (c < 64) {
        v0 = W[k0 * 64 + c] - W[(64 + k0) * 64 + c];
        v1 = W[(k0 + 1) * 64 + c] - W[(65 + k0) * 64 + c];
      } else {
        v0 = W[(64 + k0) * 64 + (c - 64)];
        v1 = W[(65 + k0) * 64 + (c - 64)];
      }
      w[jj] = (u32)f2bf(v0) | ((u32)f2bf(v1) << 16);
    }
    Wb[g] = make_uint4(w[0], w[1], w[2], w[3]);
  } else if (bid == EBLK + 12) {
    if (t > 64) return;
    int lo = 0, hi = N_NODES;
    while (lo < hi) {
      int mid = (lo + hi) >> 1;
      if (batch[mid] < t) lo = mid + 1; else hi = mid;
    }
    bounds[t] = (u32)lo;
  } else {
    // zero sums (4096) + bnacc (12288) + counter region (64)
    for (int i = t; i < 16448; i += 256) zbase[i] = 0u;
  }
}

// ---------- bucket scan -> boffs (exclusive, +total), bcur ----------
__global__ void bscan_k(const u32* __restrict__ bcnt, u32* __restrict__ boffs,
                        u32* __restrict__ bcur) {
  __shared__ u32 s[512];
  int t = threadIdx.x;
  u32 v = (t < NBUCK) ? bcnt[t] : 0u;
  s[t] = v;
  __syncthreads();
  for (int d = 1; d < 512; d <<= 1) {
    u32 a = (t >= d) ? s[t - d] : 0u;
    __syncthreads();
    s[t] += a;
    __syncthreads();
  }
  if (t < NBUCK) { boffs[t] = s[t] - v; bcur[t] = s[t] - v; }
  if (t == NBUCK - 1) boffs[NBUCK] = s[t];
}

// ---------- pass C: edges -> bucket-grouped packed pairs ((dst&255)<<24 | src) ----------
// 8192 edges/block (32/thread in registers) for write-combining on bucket fronts.
__global__ __launch_bounds__(256) void bscat_k(const int* __restrict__ src,
                                               const int* __restrict__ dst,
                                               u32* __restrict__ gcur,
                                               u32* __restrict__ pairs) {
  __shared__ u32 cnt[NBUCK];
  __shared__ u32 base[NBUCK];
  int t = threadIdx.x;
  for (int i = t; i < NBUCK; i += 256) cnt[i] = 0;
  __syncthreads();
  u32 pk[32], bk[32];
  int be = blockIdx.x * 8192;
#pragma unroll
  for (int k = 0; k < 32; ++k) {
    int e = be + k * 256 + t;
    if (e < N_EDGES) {
      u32 d = (u32)dst[e], s = (u32)src[e];
      u32 b = d >> 8;
      pk[k] = ((d & 255u) << 24) | s;
      bk[k] = b;
      atomicAdd(&cnt[b], 1u);
    } else bk[k] = 0xFFFFFFFFu;
  }
  __syncthreads();
  for (int i = t; i < NBUCK; i += 256) {
    u32 c = cnt[i];
    base[i] = c ? atomicAdd(&gcur[i], c) : 0u;
    cnt[i] = 0;
  }
  __syncthreads();
#pragma unroll
  for (int k = 0; k < 32; ++k) {
    if (bk[k] != 0xFFFFFFFFu) {
      u32 p = base[bk[k]] + atomicAdd(&cnt[bk[k]], 1u);
      pairs[p] = pk[k];
    }
  }
}

// ---------- fscat2 body: per-bucket node CSR (LDS hist+scan) + place ----------
static __device__ __forceinline__ void fscat2_body(
    int b, u32* SH, const u32* __restrict__ boffs, const u32* __restrict__ pairs,
    u32* __restrict__ esrc, u32* __restrict__ offs_g, u32* __restrict__ cnt_g) {
  u32* lcnt = SH; u32* lexc = SH + 256; u32* lcur = SH + 512;
  int t = threadIdx.x;
  u32 s0 = boffs[b], e0 = boffs[b + 1];
  lcnt[t] = 0;
  __syncthreads();
  for (u32 p = s0 + t; p < e0; p += 256) atomicAdd(&lcnt[pairs[p] >> 24], 1u);
  __syncthreads();
  u32 v = lcnt[t];
  lexc[t] = v;
  __syncthreads();
  for (int d = 1; d < 256; d <<= 1) {
    u32 a = (t >= d) ? lexc[t - d] : 0u;
    __syncthreads();
    lexc[t] += a;
    __syncthreads();
  }
  u32 excl = lexc[t] - v;
  int node = (b << 8) + t;
  if (node < N_NODES) { offs_g[node] = s0 + excl; cnt_g[node] = v; }
  lcur[t] = 0;
  lexc[t] = excl;
  __syncthreads();
  for (u32 p = s0 + t; p < e0; p += 256) {
    u32 pk = pairs[p];
    u32 dl = pk >> 24;
    u32 l = atomicAdd(&lcur[dl], 1u);
    esrc[s0 + lexc[dl] + l] = pk & 0x00FFFFFFu;
  }
}

// ---------- MFMA GEMM body: [u | v] = act(X) @ [A-B | B], u/v bf16 out ----------
// One 64-row tile; 4 waves; Xl XOR-swizzled (byte^=(row&7)<<4).
static __device__ __forceinline__ void gemm_body(
    int tile, u32* Xl,
    const void* __restrict__ xin, int xbf16, const uint4* __restrict__ Wb,
    const float* ab, const float* __restrict__ bias,
    ushort* __restrict__ ub, ushort* __restrict__ vb) {
  int t = threadIdx.x;
  int l = t & 63, wv = t >> 6;
  short8 bs[2][8];
#pragma unroll
  for (int kh = 0; kh < 2; ++kh)
#pragma unroll
    for (int ct = 0; ct < 8; ++ct) {
      uint4 tmp = Wb[(kh * 8 + ct) * 64 + l];
      __builtin_memcpy(&bs[kh][ct], &tmp, 16);
    }
  int srow = t >> 2, scol = (t & 3) * 16;
  int rb = tile * 64;
  int gr = rb + srow;
  u32 xb[8];
  if (gr < N_NODES) {
    if (xbf16) {
      const uint4* xp = (const uint4*)((const ushort*)xin + (size_t)gr * 64 + scol);
      uint4 p0 = xp[0], p1 = xp[1];
      u32 raw[8] = {p0.x, p0.y, p0.z, p0.w, p1.x, p1.y, p1.z, p1.w};
#pragma unroll
      for (int q = 0; q < 8; ++q) {
        int c = scol + 2 * q;
        float lo = fmaxf(fmaf(bflo(raw[q]), ab[c], ab[64 + c]), 0.f);
        float hi = fmaxf(fmaf(bfhi(raw[q]), ab[c + 1], ab[64 + c + 1]), 0.f);
        xb[q] = (u32)f2bf(lo) | ((u32)f2bf(hi) << 16);
      }
    } else {
      const float4* xp = (const float4*)((const float*)xin + (size_t)gr * 64 + scol);
#pragma unroll
      for (int q = 0; q < 4; ++q) {
        float4 a = xp[q];
        xb[2 * q]     = (u32)f2bf(a.x) | ((u32)f2bf(a.y) << 16);
        xb[2 * q + 1] = (u32)f2bf(a.z) | ((u32)f2bf(a.w) << 16);
      }
    }
  } else {
#pragma unroll
    for (int q = 0; q < 8; ++q) xb[q] = 0u;
  }
  int byte0 = srow * 128 + ((scol * 2) ^ ((srow & 7) << 4));
  int byte1 = srow * 128 + ((scol * 2 + 16) ^ ((srow & 7) << 4));
  *(uint4*)((char*)Xl + byte0) = make_uint4(xb[0], xb[1], xb[2], xb[3]);
  *(uint4*)((char*)Xl + byte1) = make_uint4(xb[4], xb[5], xb[6], xb[7]);
  __syncthreads();
  f32x4 acc[8];
#pragma unroll
  for (int ct = 0; ct < 8; ++ct) {
    float b0 = (ct < 4) ? bias[ct * 16 + (l & 15)] : 0.f;
    acc[ct] = (f32x4){b0, b0, b0, b0};
  }
  int arow = wv * 16 + (l & 15);
#pragma unroll
  for (int kh = 0; kh < 2; ++kh) {
    int abyte = arow * 128 + ((kh * 64 + ((l >> 4) * 16)) ^ ((arow & 7) << 4));
    short8 af = *(const short8*)((const char*)Xl + abyte);
#pragma unroll
    for (int ct = 0; ct < 8; ++ct)
      acc[ct] = __builtin_amdgcn_mfma_f32_16x16x32_bf16(af, bs[kh][ct], acc[ct], 0, 0, 0);
  }
  // C layout: col = l&15, row = 4*(l>>4)+reg (m89-verified)
  int rloc = rb + wv * 16 + 4 * (l >> 4);
#pragma unroll
  for (int ct = 0; ct < 4; ++ct) {
    int col = ct * 16 + (l & 15);
#pragma unroll
    for (int r = 0; r < 4; ++r) {
      int row = rloc + r;
      if (row < N_NODES) ub[(size_t)row * 64 + col] = f2bf(acc[ct][r]);
    }
  }
#pragma unroll
  for (int ct = 4; ct < 8; ++ct) {
    int col = ct * 16 + (l & 15) - 64;
#pragma unroll
    for (int r = 0; r < 4; ++r) {
      int row = rloc + r;
      if (row < N_NODES) vb[(size_t)row * 64 + col] = f2bf(acc[ct][r]);
    }
  }
}

// ---------- fused: fscat2 (391 blocks) || layer-1 GEMM (1563 blocks) ----------
__global__ __launch_bounds__(256) void fused_fg_k(
    const u32* __restrict__ boffs, const u32* __restrict__ pairs,
    u32* __restrict__ esrc, u32* __restrict__ offs_g, u32* __restrict__ cnt_g,
    const float* __restrict__ x, const uint4* __restrict__ Wb,
    const float* __restrict__ bias, ushort* __restrict__ ub, ushort* __restrict__ vb) {
  __shared__ u32 SH[2048];  // 8KB
  int bid = blockIdx.x;
  if (bid < NBUCK) fscat2_body(bid, SH, boffs, pairs, esrc, offs_g, cnt_g);
  else gemm_body(bid - NBUCK, SH, x, 0, Wb, nullptr, bias, ub, vb);
}

// ---------- standalone GEMM (layers 2,3): BN affine computed from bnacc slices ----------
__global__ __launch_bounds__(256) void gemm_k(
    const ushort* __restrict__ xin, const uint4* __restrict__ Wb,
    const float* __restrict__ bnacc, const float* __restrict__ g,
    const float* __restrict__ be, const float* __restrict__ bias,
    ushort* __restrict__ ub, ushort* __restrict__ vb) {
  __shared__ u32 Xl[2048];
  __shared__ float ab_sh[128];
  int t = threadIdx.x;
  if (t < 64) {
    float s1 = 0.f, s2 = 0.f;
    for (int s = 0; s < 32; ++s) {
      s1 += bnacc[s * 128 + t];
      s2 += bnacc[s * 128 + 64 + t];
    }
    float mu = s1 / (float)N_NODES;
    float var = s2 / (float)N_NODES - mu * mu;
    float al = g[t] / sqrtf(var + EPS);
    ab_sh[t] = al;
    ab_sh[64 + t] = be[t] - mu * al;
  }
  __syncthreads();
  gemm_body(blockIdx.x, Xl, xin, 1, Wb, ab_sh, bias, ub, vb);
}

// ---------- segmax: 1 node/slot, 8 lanes/node, uint4 gathers, unroll-4 ----------
// h = relu(u + max) bf16; BN partials -> sliced global accumulators (float atomics)
__global__ __launch_bounds__(256) void segmax_k(
    const ushort* __restrict__ v, const u32* __restrict__ offs,
    const u32* __restrict__ cnt, const u32* __restrict__ esrc,
    const ushort* __restrict__ ub, ushort* __restrict__ hb,
    float* __restrict__ bnacc) {
  int t = threadIdx.x;
  int lane = t & 63;
  int op = lane & 7;        // uint4 index within row (8 channels)
  int sub = lane >> 3;      // node sub-group within wave
  int wv = t >> 6;
  int node = blockIdx.x * 32 + wv * 8 + sub;   // grid*32 == N_NODES exactly
  const uint4* v4 = (const uint4*)v;
  const uint4* u4 = (const uint4*)ub;
  uint4* h4 = (uint4*)hb;
  u32 off = offs[node], deg = cnt[node];
  const u32* ep = esrc + off;
  float m[8];
#pragma unroll
  for (int j = 0; j < 8; ++j) m[j] = -INFINITY;
  u32 i = 0;
  for (; i + 4 <= deg; i += 4) {
    u32 sA = ep[i], sB = ep[i + 1], sC = ep[i + 2], sD = ep[i + 3];
    uint4 wA = v4[(size_t)sA * 8 + op];
    uint4 wB = v4[(size_t)sB * 8 + op];
    uint4 wC = v4[(size_t)sC * 8 + op];
    uint4 wD = v4[(size_t)sD * 8 + op];
    float fA[8], fB[8], fC[8], fD[8];
    decode8(wA, fA); decode8(wB, fB); decode8(wC, fC); decode8(wD, fD);
#pragma unroll
    for (int j = 0; j < 8; ++j)
      m[j] = fmaxf(fmaxf(m[j], fmaxf(fA[j], fB[j])), fmaxf(fC[j], fD[j]));
  }
  for (; i < deg; ++i) {
    uint4 w = v4[(size_t)ep[i] * 8 + op];
    float f[8]; decode8(w, f);
#pragma unroll
    for (int j = 0; j < 8; ++j) m[j] = fmaxf(m[j], f[j]);
  }
  uint4 uu = u4[(size_t)node * 8 + op];
  float uf[8]; decode8(uu, uf);
  float h[8];
#pragma unroll
  for (int j = 0; j < 8; ++j) h[j] = fmaxf(uf[j] + m[j], 0.f);  // relu(-inf)=0
  uint4 hw;
  hw.x = (u32)f2bf(h[0]) | ((u32)f2bf(h[1]) << 16);
  hw.y = (u32)f2bf(h[2]) | ((u32)f2bf(h[3]) << 16);
  hw.z = (u32)f2bf(h[4]) | ((u32)f2bf(h[5]) << 16);
  hw.w = (u32)f2bf(h[6]) | ((u32)f2bf(h[7]) << 16);
  h4[(size_t)node * 8 + op] = hw;
  // BN partials: channel c = op*8 + j; reduce 32 nodes per block
  __shared__ float red[2048];
#pragma unroll
  for (int j = 0; j < 8; ++j) red[t * 8 + j] = h[j];
  __syncthreads();
  float o1 = 0.f, o2 = 0.f;
  if (t < 64) {
    int cop = t >> 3, cj = t & 7;
    for (int q = 0; q < 32; ++q) o1 += red[(q * 8 + cop) * 8 + cj];
  }
  __syncthreads();
#pragma unroll
  for (int j = 0; j < 8; ++j) red[t * 8 + j] = h[j] * h[j];
  __syncthreads();
  if (t < 64) {
    int cop = t >> 3, cj = t & 7;
    for (int q = 0; q < 32; ++q) o2 += red[(q * 8 + cop) * 8 + cj];
    int slice = blockIdx.x & 31;
    atomicAdd(&bnacc[slice * 128 + t], o1);
    atomicAdd(&bnacc[slice * 128 + 64 + t], o2);
  }
}

// ---------- pool partials + (last block) BN3 affine + head + softmax ----------
__global__ __launch_bounds__(256) void pool_head_k(
    const ushort* __restrict__ h3, const u32* __restrict__ bounds,
    float* __restrict__ sums, const float* __restrict__ bnacc3,
    const float* __restrict__ g3, const float* __restrict__ be3,
    const float* __restrict__ Wo, const float* __restrict__ bo,
    u32* __restrict__ counter, float* __restrict__ out) {
  int g = blockIdx.y;
  u32 s = bounds[g], e = bounds[g + 1];
  int t = threadIdx.x;
  int lane = t & 63, wv = t >> 6, sub = lane >> 5, cp = lane & 31;
  int slot = blockIdx.x * 8 + wv * 2 + sub;
  int nsl = gridDim.x * 8;
  const u32* hw = (const u32*)h3;
  float alo = 0.f, ahi = 0.f;
  for (u32 n = s + slot; n < e; n += nsl) {
    u32 w = hw[(size_t)n * 32 + cp];
    alo += bflo(w);
    ahi += bfhi(w);
  }
  __shared__ float2 red[256];
  red[t] = make_float2(alo, ahi);
  __syncthreads();
  if (t < 32) {
    float2 a = red[t];
#pragma unroll
    for (int j = 1; j < 8; ++j) {
      float2 b = red[t + 32 * j];
      a.x += b.x; a.y += b.y;
    }
    atomicAdd(&sums[g * 64 + 2 * t], a.x);
    atomicAdd(&sums[g * 64 + 2 * t + 1], a.y);
  }
  // last-block head
  __shared__ int lastf;
  __threadfence();
  __syncthreads();
  if (t == 0) {
    u32 tk = atomicAdd(counter, 1u);
    lastf = (tk == gridDim.x * gridDim.y - 1) ? 1 : 0;
  }
  __syncthreads();
  if (!lastf) return;
  __shared__ float ab3[128];
  if (t < 64) {
    float s1 = 0.f, s2 = 0.f;
    for (int sl = 0; sl < 32; ++sl) {
      s1 += bnacc3[sl * 128 + t];
      s2 += bnacc3[sl * 128 + 64 + t];
    }
    float mu = s1 / (float)N_NODES;
    float var = s2 / (float)N_NODES - mu * mu;
    float al = g3[t] / sqrtf(var + EPS);
    ab3[t] = al;
    ab3[64 + t] = be3[t] - mu * al;
  }
  __syncthreads();
  if (t < N_GRAPHS) {
    u32 cntn = bounds[t + 1] - bounds[t];
    float inv = (cntn > 0) ? 1.f / (float)cntn : 0.f;
    float lg[10];
#pragma unroll
    for (int j = 0; j < 10; ++j) lg[j] = bo[j];
    for (int c = 0; c < 64; ++c) {
      float sv = __hip_atomic_load(&sums[t * 64 + c], __ATOMIC_RELAXED,
                                   __HIP_MEMORY_SCOPE_AGENT);
      float p = (cntn > 0) ? (sv * inv * ab3[c] + ab3[64 + c]) : 0.f;
#pragma unroll
      for (int j = 0; j < 10; ++j) lg[j] = fmaf(p, Wo[c * 10 + j], lg[j]);
    }
    float mx = lg[0];
#pragma unroll
    for (int j = 1; j < 10; ++j) mx = fmaxf(mx, lg[j]);
    float ssum = 0.f, ex[10];
#pragma unroll
    for (int j = 0; j < 10; ++j) { ex[j] = expf(lg[j] - mx); ssum += ex[j]; }
#pragma unroll
    for (int j = 0; j < 10; ++j) out[t * 10 + j] = ex[j] / ssum;
  }
}

extern "C" void kernel_launch(void* const* d_in, const int* in_sizes, int n_in,
                              void* d_out, int out_size, void* d_ws, size_t ws_size,
                              hipStream_t stream) {
  const float* x    = (const float*)d_in[0];
  const int*   ei   = (const int*)d_in[1];
  const int*   batch= (const int*)d_in[2];
  const float* W1 = (const float*)d_in[3];  const float* b1 = (const float*)d_in[4];
  const float* W2 = (const float*)d_in[5];  const float* b2 = (const float*)d_in[6];
  const float* W3 = (const float*)d_in[7];  const float* b3 = (const float*)d_in[8];
  const float* g1 = (const float*)d_in[9];  const float* be1= (const float*)d_in[10];
  const float* g2 = (const float*)d_in[11]; const float* be2= (const float*)d_in[12];
  const float* g3 = (const float*)d_in[13]; const float* be3= (const float*)d_in[14];
  const float* Wo = (const float*)d_in[15]; const float* bo = (const float*)d_in[16];
  float* out = (float*)d_out;

  char* p = (char*)d_ws;
  auto alloc = [&](size_t bytes) { void* r = (void*)p; p += (bytes + 255) & ~(size_t)255; return r; };
  uint4* Wb     = (uint4*)alloc(3072 * sizeof(uint4));
  u32*   bounds = (u32*)alloc(65 * sizeof(u32));
  u32*   bcnt   = (u32*)alloc(NBUCK * sizeof(u32));
  u32*   boffs  = (u32*)alloc((NBUCK + 1) * sizeof(u32));
  u32*   bcur   = (u32*)alloc(NBUCK * sizeof(u32));
  u32*   cnt    = (u32*)alloc((size_t)N_NODES * sizeof(u32));
  u32*   offs   = (u32*)alloc((size_t)N_NODES * sizeof(u32));
  // contiguous zero region: sums (4096f) + bnacc (3*32*128 = 12288f) + counter
  float* sums   = (float*)alloc(4096 * sizeof(float));
  float* bnacc  = (float*)alloc(12288 * sizeof(float));
  u32*   counter= (u32*)alloc(256);
  u32*   esrc   = (u32*)alloc((size_t)N_EDGES * sizeof(u32));
  u32*   pairs  = (u32*)alloc((size_t)N_EDGES * sizeof(u32));
  ushort* ub    = (ushort*)alloc((size_t)N_NODES * 64 * sizeof(ushort));
  ushort* vb    = (ushort*)alloc((size_t)N_NODES * 64 * sizeof(ushort));
  ushort* hb    = (ushort*)alloc((size_t)N_NODES * 64 * sizeof(ushort));

  const int* src = ei;
  const int* dst = ei + N_EDGES;

  hipMemsetAsync(bcnt, 0, NBUCK * sizeof(u32), stream);
  // setup: bhist (782) + weight pack (12) + bounds (1) + zero accumulators (1)
  setup_k<<<EBLK + 14, 256, 0, stream>>>(dst, bcnt, W1, W2, W3, Wb, batch, bounds,
                                         (u32*)sums);
  bscan_k<<<1, 512, 0, stream>>>(bcnt, boffs, bcur);
  bscat_k<<<BSCAT_GRID, 256, 0, stream>>>(src, dst, bcur, pairs);

  // fscat2 || layer-1 GEMM
  fused_fg_k<<<NBUCK + GEMM_TILES, 256, 0, stream>>>(boffs, pairs, esrc, offs, cnt,
                                                     x, Wb, b1, ub, vb);
  segmax_k<<<SEG_NBLK, 256, 0, stream>>>(vb, offs, cnt, esrc, ub, hb, bnacc);

  // ---- layer 2 ----
  gemm_k<<<GEMM_TILES, 256, 0, stream>>>(hb, Wb + 1024, bnacc, g1, be1, b2, ub, vb);
  segmax_k<<<SEG_NBLK, 256, 0, stream>>>(vb, offs, cnt, esrc, ub, hb, bnacc + 4096);

  // ---- layer 3 ----
  gemm_k<<<GEMM_TILES, 256, 0, stream>>>(hb, Wb + 2048, bnacc + 4096, g2, be2, b3, ub, vb);
  segmax_k<<<SEG_NBLK, 256, 0, stream>>>(vb, offs, cnt, esrc, ub, hb, bnacc + 8192);

  // ---- pool + BN3 + head (last-block pattern) ----
  pool_head_k<<<dim3(8, N_GRAPHS), 256, 0, stream>>>(hb, bounds, sums, bnacc + 8192,
                                                     g3, be3, Wo, bo, counter, out);
}